// Round 3
// baseline (748.351 us; speedup 1.0000x reference)
//
#include <hip/hip_runtime.h>

#define N_NODES 10000
#define N_RELS  50
#define R_AUG   101
#define D       128
#define N_EDGES 320000
#define E_AUG   650000   /* 2*N_EDGES + N_NODES */
#define N_BATCH 65536

#define NCHUNK  4
#define RC      26                       /* ceil(101/4) */
#define NBINS   (NCHUNK * N_NODES)       /* 40000 */
#define NSB     ((NBINS + 255) / 256)    /* 157 scan blocks */

typedef short bf16x8 __attribute__((ext_vector_type(8)));
typedef float f32x4  __attribute__((ext_vector_type(4)));

__device__ __forceinline__ unsigned short f2bf(float f) {
    union { float f; unsigned int u; } v; v.f = f;
    unsigned int r = (v.u + 0x7FFFu + ((v.u >> 16) & 1u)) >> 16;
    return (unsigned short)r;
}
__device__ __forceinline__ float bf2f(unsigned short h) {
    union { unsigned int u; float f; } v; v.u = ((unsigned int)h) << 16;
    return v.f;
}
__device__ __forceinline__ float u2f(unsigned int u) {
    union { unsigned int u; float f; } v; v.u = u; return v.f;
}
__device__ __forceinline__ unsigned int f2u(float f) {
    union { float f; unsigned int u; } v; v.f = f; return v.u;
}

__device__ __forceinline__ void decode_edge(const int* __restrict__ g, int e,
                                            int& src, int& rel, int& dst) {
    if (e < N_EDGES)            { src = g[3*e];     rel = g[3*e+1];          dst = g[3*e+2]; }
    else if (e < 2*N_EDGES)     { int b = e - N_EDGES;
                                  src = g[3*b+2];   rel = g[3*b+1] + N_RELS; dst = g[3*b];   }
    else                        { int n = e - 2*N_EDGES; src = n; dst = n; rel = 2*N_RELS;   }
}

// ---------------- small prep kernels ----------------

__global__ __launch_bounds__(256) void convert_x(const float* __restrict__ x,
                                                 unsigned short* __restrict__ xb) {
    int i = blockIdx.x * 256 + threadIdx.x;
    xb[i] = f2bf(x[i]);
}

__global__ __launch_bounds__(256) void init_h(float* __restrict__ h1, float* __restrict__ h2,
                                              const float* __restrict__ b1,
                                              const float* __restrict__ b2) {
    int i = blockIdx.x * 256 + threadIdx.x;
    int d = i & (D - 1);
    h1[i] = b1[d];
    h2[i] = b2[d];
}

// W (r,d,o) fp32  ->  Wt (r,o,d) bf16
__global__ __launch_bounds__(256) void transpose_w(const float* __restrict__ W1,
                                                   const float* __restrict__ W2,
                                                   unsigned short* __restrict__ W1t,
                                                   unsigned short* __restrict__ W2t) {
    __shared__ float tile[64][65];
    int z = blockIdx.z;
    const float* W = (z < R_AUG) ? W1 : W2;
    unsigned short* Wt = (z < R_AUG) ? W1t : W2t;
    int r = (z < R_AUG) ? z : (z - R_AUG);
    int d0 = blockIdx.x * 64, o0 = blockIdx.y * 64;
    int tx = threadIdx.x & 63, ty = threadIdx.x >> 6;
    #pragma unroll
    for (int i = ty; i < 64; i += 4)
        tile[i][tx] = W[((size_t)r * D + (d0 + i)) * D + (o0 + tx)];
    __syncthreads();
    #pragma unroll
    for (int i = ty; i < 64; i += 4)
        Wt[((size_t)r * D + (o0 + i)) * D + (d0 + tx)] = f2bf(tile[tx][i]);
}

// degree histogram per (rel,dst) AND per (chunk,dst)
__global__ __launch_bounds__(256) void deg_hist(const int* __restrict__ g,
                                                float* __restrict__ deg,
                                                int* __restrict__ cnt) {
    int e = blockIdx.x * 256 + threadIdx.x;
    if (e >= E_AUG) return;
    int src, rel, dst;
    decode_edge(g, e, src, rel, dst);
    atomicAdd(&deg[rel * N_NODES + dst], 1.0f);
    atomicAdd(&cnt[(rel / RC) * N_NODES + dst], 1);
}

__global__ __launch_bounds__(256) void inv_kernel(float* __restrict__ norm) {
    int i = blockIdx.x * 256 + threadIdx.x;
    if (i >= R_AUG * N_NODES) return;
    norm[i] = 1.0f / fmaxf(norm[i], 1.0f);
}

// ---- 3-phase parallel exclusive scan over cnt[NBINS] ----

__global__ __launch_bounds__(256) void scan_block(const int* __restrict__ cnt,
                                                  int* __restrict__ offs,
                                                  int* __restrict__ partial) {
    __shared__ int wsum[4];
    int t = threadIdx.x, lane = t & 63, w = t >> 6;
    int i = blockIdx.x * 256 + t;
    int v = (i < NBINS) ? cnt[i] : 0;
    int incl = v;
    #pragma unroll
    for (int off = 1; off < 64; off <<= 1) {
        int u = __shfl_up(incl, off, 64);
        if (lane >= off) incl += u;
    }
    if (lane == 63) wsum[w] = incl;
    __syncthreads();
    int woff = 0;
    for (int k = 0; k < w; k++) woff += wsum[k];
    if (i < NBINS) offs[i] = woff + incl - v;
    if (t == 255) partial[blockIdx.x] = woff + incl;
}

__global__ __launch_bounds__(256) void scan_partial(int* __restrict__ partial) {
    __shared__ int wsum[4];
    int t = threadIdx.x, lane = t & 63, w = t >> 6;
    int v = (t < NSB) ? partial[t] : 0;
    int incl = v;
    #pragma unroll
    for (int off = 1; off < 64; off <<= 1) {
        int u = __shfl_up(incl, off, 64);
        if (lane >= off) incl += u;
    }
    if (lane == 63) wsum[w] = incl;
    __syncthreads();
    int woff = 0;
    for (int k = 0; k < w; k++) woff += wsum[k];
    if (t < NSB) partial[t] = woff + incl - v;
}

__global__ __launch_bounds__(256) void scan_add(int* __restrict__ offs,
                                                const int* __restrict__ partial,
                                                int* __restrict__ cursor) {
    int i = blockIdx.x * 256 + threadIdx.x;
    if (i < NBINS) {
        int v = offs[i] + partial[i >> 8];
        offs[i] = v;
        cursor[i] = v;
    }
    if (i == 0) offs[NBINS] = E_AUG;
}

// scatter edges into (chunk,dst)-sorted order; record = (rel<<16 | src, norm bits)
__global__ __launch_bounds__(256) void scatter_kernel(const int* __restrict__ g,
                                                      const float* __restrict__ norm,
                                                      int* __restrict__ cursor,
                                                      uint2* __restrict__ sorted) {
    int e = blockIdx.x * 256 + threadIdx.x;
    if (e >= E_AUG) return;
    int src, rel, dst;
    decode_edge(g, e, src, rel, dst);
    int pos = atomicAdd(&cursor[(rel / RC) * N_NODES + dst], 1);
    uint2 rec;
    rec.x = ((unsigned)rel << 16) | (unsigned)src;
    rec.y = f2u(norm[rel * N_NODES + dst]);
    sorted[pos] = rec;
}

__global__ __launch_bounds__(256) void relu_conv(const float* __restrict__ h,
                                                 unsigned short* __restrict__ hb) {
    int i = blockIdx.x * 256 + threadIdx.x;
    hb[i] = f2bf(fmaxf(h[i], 0.0f));
}

// ---------------- batched GEMM, LDS-free: Z[rc][m][o] = Xb[m][:] @ W[r0+rc][:][o] ----------------
// grid (79, rn); block 256 = 4 waves, each a 64x64 quadrant of the 128x128 tile.
// mfma(b, a): D row-index (quad*4+reg) <-> W row (output col), D col-index (lane&15) <-> X row.
// => lane holds 4 CONSECUTIVE output cols of one Z row -> packed 8B stores.

__global__ __launch_bounds__(256) void gemm_chunk(const unsigned short* __restrict__ xb,
                                                  const unsigned short* __restrict__ Wt,
                                                  unsigned short* __restrict__ Z,
                                                  int r0) {
    int mt = blockIdx.x, rc = blockIdx.y;
    int t = threadIdx.x, wave = t >> 6, lane = t & 63;
    int mo = (wave >> 1) * 64, no = (wave & 1) * 64;
    int lr = lane & 15, lq = lane >> 4;
    int m0 = mt * 128;
    const unsigned short* Wr = Wt + (size_t)(r0 + rc) * D * D;

    f32x4 acc[4][4] = {};   // [j: col tile][i: row tile]

    #pragma unroll
    for (int ks = 0; ks < 4; ks++) {
        int kb = ks * 32 + lq * 8;
        bf16x8 a[4], b[4];
        #pragma unroll
        for (int i = 0; i < 4; i++) {
            int m = m0 + mo + i * 16 + lr;
            bf16x8 zv = {};
            a[i] = (m < N_NODES) ? *(const bf16x8*)(xb + (size_t)m * D + kb) : zv;
        }
        #pragma unroll
        for (int j = 0; j < 4; j++)
            b[j] = *(const bf16x8*)(Wr + (size_t)(no + j * 16 + lr) * D + kb);
        #pragma unroll
        for (int j = 0; j < 4; j++)
            #pragma unroll
            for (int i = 0; i < 4; i++)
                acc[j][i] = __builtin_amdgcn_mfma_f32_16x16x32_bf16(b[j], a[i], acc[j][i], 0, 0, 0);
    }

    #pragma unroll
    for (int i = 0; i < 4; i++) {
        int m = m0 + mo + i * 16 + lr;
        if (m >= N_NODES) continue;
        unsigned short* zrow = Z + ((size_t)rc * N_NODES + m) * D;
        #pragma unroll
        for (int j = 0; j < 4; j++) {
            int col = no + j * 16 + lq * 4;
            ushort4 pk;
            pk.x = f2bf(acc[j][i][0]);
            pk.y = f2bf(acc[j][i][1]);
            pk.z = f2bf(acc[j][i][2]);
            pk.w = f2bf(acc[j][i][3]);
            *(ushort4*)(zrow + col) = pk;
        }
    }
}

// ---------------- aggregation: one wave per dst per chunk, no atomics ----------------

__global__ __launch_bounds__(256) void agg_pass(const uint2* __restrict__ sorted,
                                                const int* __restrict__ offs,
                                                const unsigned short* __restrict__ Z,
                                                float* __restrict__ h,
                                                int c) {
    int w = threadIdx.x >> 6, lane = threadIdx.x & 63;
    int dst = blockIdx.x * 4 + w;
    if (dst >= N_NODES) return;
    int bin = c * N_NODES + dst;
    int e0 = offs[bin], e1 = offs[bin + 1];
    if (e0 == e1) return;
    int r0 = c * RC;
    float ax = 0.0f, ay = 0.0f;

    for (int base = e0; base < e1; base += 64) {
        int n = e1 - base; if (n > 64) n = 64;
        uint2 rec = {0u, 0u};
        if (lane < n) rec = sorted[base + lane];
        #pragma unroll 4
        for (int j = 0; j < n; j++) {
            unsigned p  = (unsigned)__shfl((int)rec.x, j, 64);
            unsigned nb = (unsigned)__shfl((int)rec.y, j, 64);
            int rel = (int)(p >> 16), src = (int)(p & 0xFFFFu);
            float nrm = u2f(nb);
            unsigned z = *(const unsigned int*)(Z + (((size_t)(rel - r0) * N_NODES + src) << 7) + 2 * lane);
            ax += nrm * bf2f((unsigned short)(z & 0xFFFFu));
            ay += nrm * bf2f((unsigned short)(z >> 16));
        }
    }
    float* hp = h + ((size_t)dst << 7) + 2 * lane;
    hp[0] += ax;
    hp[1] += ay;
}

// ---------------- scoring ----------------

__global__ __launch_bounds__(256) void score_kernel(const int* __restrict__ batch,
                                                    const float* __restrict__ h2,
                                                    const float* __restrict__ rels,
                                                    float* __restrict__ out) {
    int i = blockIdx.x * 4 + (threadIdx.x >> 6);
    if (i >= N_BATCH) return;
    int lane = threadIdx.x & 63;
    int bs = batch[3*i], bp = batch[3*i+1], bo = batch[3*i+2];
    float2 s = *(const float2*)(h2   + (size_t)bs * D + lane * 2);
    float2 p = *(const float2*)(rels + (size_t)bp * D + lane * 2);
    float2 o = *(const float2*)(h2   + (size_t)bo * D + lane * 2);
    float v = s.x * p.x * o.x + s.y * p.y * o.y;
    #pragma unroll
    for (int off = 32; off > 0; off >>= 1) v += __shfl_down(v, off, 64);
    if (lane == 0) out[i] = v;
}

// ---------------- host ----------------

extern "C" void kernel_launch(void* const* d_in, const int* in_sizes, int n_in,
                              void* d_out, int out_size, void* d_ws, size_t ws_size,
                              hipStream_t stream) {
    const int*   graph = (const int*)  d_in[0];
    const int*   batch = (const int*)  d_in[1];
    const float* emb   = (const float*)d_in[2];
    const float* W1    = (const float*)d_in[3];
    const float* b1    = (const float*)d_in[4];
    const float* W2    = (const float*)d_in[5];
    const float* b2    = (const float*)d_in[6];
    const float* rels  = (const float*)d_in[7];
    float* out = (float*)d_out;

    char* base = (char*)d_ws;
    size_t off = 0;
    auto take = [&](size_t bytes) -> char* {
        char* q = base + off;
        off += (bytes + 255) & ~(size_t)255;
        return q;
    };
    float*          norm   = (float*)         take((size_t)R_AUG * N_NODES * 4);
    unsigned short* xb     = (unsigned short*)take((size_t)N_NODES * D * 2);
    float*          h1     = (float*)         take((size_t)N_NODES * D * 4);
    float*          h2     = (float*)         take((size_t)N_NODES * D * 4);
    unsigned short* h1b    = (unsigned short*)take((size_t)N_NODES * D * 2);
    unsigned short* W1t    = (unsigned short*)take((size_t)R_AUG * D * D * 2);
    unsigned short* W2t    = (unsigned short*)take((size_t)R_AUG * D * D * 2);
    int*            cnt    = (int*)           take((size_t)NBINS * 4);
    int*            offs   = (int*)           take((size_t)(NBINS + 1) * 4);
    int*            cursor = (int*)           take((size_t)NBINS * 4);
    int*            part   = (int*)           take((size_t)NSB * 4);
    uint2*          sorted = (uint2*)         take((size_t)E_AUG * 8);
    unsigned short* Z      = (unsigned short*)take((size_t)RC * N_NODES * D * 2);  // 66.6 MB chunk

    hipMemsetAsync(norm, 0, (size_t)R_AUG * N_NODES * 4, stream);
    hipMemsetAsync(cnt, 0, (size_t)NBINS * 4, stream);
    convert_x<<<dim3((N_NODES * D) / 256), 256, 0, stream>>>(emb, xb);
    init_h<<<dim3((N_NODES * D) / 256), 256, 0, stream>>>(h1, h2, b1, b2);
    transpose_w<<<dim3(2, 2, 2 * R_AUG), 256, 0, stream>>>(W1, W2, W1t, W2t);
    deg_hist<<<dim3((E_AUG + 255) / 256), 256, 0, stream>>>(graph, norm, cnt);
    inv_kernel<<<dim3((R_AUG * N_NODES + 255) / 256), 256, 0, stream>>>(norm);
    scan_block<<<dim3(NSB), 256, 0, stream>>>(cnt, offs, part);
    scan_partial<<<dim3(1), 256, 0, stream>>>(part);
    scan_add<<<dim3(NSB), 256, 0, stream>>>(offs, part, cursor);
    scatter_kernel<<<dim3((E_AUG + 255) / 256), 256, 0, stream>>>(graph, norm, cursor, sorted);

    const int nmt = (N_NODES + 127) / 128;  // 79
    for (int c = 0; c < NCHUNK; c++) {
        int r0 = c * RC;
        int rn = (R_AUG - r0 < RC) ? (R_AUG - r0) : RC;
        gemm_chunk<<<dim3(nmt, rn), 256, 0, stream>>>(xb, W1t, Z, r0);
        agg_pass<<<dim3((N_NODES + 3) / 4), 256, 0, stream>>>(sorted, offs, Z, h1, c);
    }
    relu_conv<<<dim3((N_NODES * D) / 256), 256, 0, stream>>>(h1, h1b);
    for (int c = 0; c < NCHUNK; c++) {
        int r0 = c * RC;
        int rn = (R_AUG - r0 < RC) ? (R_AUG - r0) : RC;
        gemm_chunk<<<dim3(nmt, rn), 256, 0, stream>>>(h1b, W2t, Z, r0);
        agg_pass<<<dim3((N_NODES + 3) / 4), 256, 0, stream>>>(sorted, offs, Z, h2, c);
    }
    score_kernel<<<dim3(N_BATCH / 4), 256, 0, stream>>>(batch, h2, rels, out);
}

// Round 4
// 597.457 us; speedup vs baseline: 1.2526x; 1.2526x over previous
//
#include <hip/hip_runtime.h>

#define N_NODES 10000
#define N_RELS  50
#define R_AUG   101
#define D       128
#define N_EDGES 320000
#define E_AUG   650000   /* 2*N_EDGES + N_NODES */
#define N_BATCH 65536

#define NCHUNK  2
#define RC      51                       /* chunk 0: rels 0-50, chunk 1: 51-100 */
#define NBINS   (NCHUNK * N_NODES)       /* 20000 */
#define NSB     ((NBINS + 255) / 256)    /* 79 scan blocks */

typedef short bf16x8 __attribute__((ext_vector_type(8)));
typedef float f32x4  __attribute__((ext_vector_type(4)));

__device__ __forceinline__ unsigned short f2bf(float f) {
    union { float f; unsigned int u; } v; v.f = f;
    unsigned int r = (v.u + 0x7FFFu + ((v.u >> 16) & 1u)) >> 16;
    return (unsigned short)r;
}
__device__ __forceinline__ float bf2f(unsigned short h) {
    union { unsigned int u; float f; } v; v.u = ((unsigned int)h) << 16;
    return v.f;
}
__device__ __forceinline__ float u2f(unsigned int u) {
    union { unsigned int u; float f; } v; v.u = u; return v.f;
}
__device__ __forceinline__ unsigned int f2u(float f) {
    union { float f; unsigned int u; } v; v.f = f; return v.u;
}

__device__ __forceinline__ void decode_edge(const int* __restrict__ g, int e,
                                            int& src, int& rel, int& dst) {
    if (e < N_EDGES)            { src = g[3*e];     rel = g[3*e+1];          dst = g[3*e+2]; }
    else if (e < 2*N_EDGES)     { int b = e - N_EDGES;
                                  src = g[3*b+2];   rel = g[3*b+1] + N_RELS; dst = g[3*b];   }
    else                        { int n = e - 2*N_EDGES; src = n; dst = n; rel = 2*N_RELS;   }
}

// ---------------- prep ----------------

// fused: bf16 conversion of x + bias-init of h1/h2
__global__ __launch_bounds__(256) void prep_x(const float* __restrict__ x,
                                              unsigned short* __restrict__ xb,
                                              float* __restrict__ h1, float* __restrict__ h2,
                                              const float* __restrict__ b1,
                                              const float* __restrict__ b2) {
    int i = blockIdx.x * 256 + threadIdx.x;   // grid covers N_NODES*D exactly
    xb[i] = f2bf(x[i]);
    int d = i & (D - 1);
    h1[i] = b1[d];
    h2[i] = b2[d];
}

// W (r,d,o) fp32  ->  Wt (r,o,d) bf16
__global__ __launch_bounds__(256) void transpose_w(const float* __restrict__ W1,
                                                   const float* __restrict__ W2,
                                                   unsigned short* __restrict__ W1t,
                                                   unsigned short* __restrict__ W2t) {
    __shared__ float tile[64][65];
    int z = blockIdx.z;
    const float* W = (z < R_AUG) ? W1 : W2;
    unsigned short* Wt = (z < R_AUG) ? W1t : W2t;
    int r = (z < R_AUG) ? z : (z - R_AUG);
    int d0 = blockIdx.x * 64, o0 = blockIdx.y * 64;
    int tx = threadIdx.x & 63, ty = threadIdx.x >> 6;
    #pragma unroll
    for (int i = ty; i < 64; i += 4)
        tile[i][tx] = W[((size_t)r * D + (d0 + i)) * D + (o0 + tx)];
    __syncthreads();
    #pragma unroll
    for (int i = ty; i < 64; i += 4)
        Wt[((size_t)r * D + (o0 + i)) * D + (d0 + tx)] = f2bf(tile[tx][i]);
}

// degree histogram per (rel,dst): ONE int atomic per edge
__global__ __launch_bounds__(256) void deg_hist(const int* __restrict__ g,
                                                int* __restrict__ deg) {
    int e = blockIdx.x * 256 + threadIdx.x;
    if (e >= E_AUG) return;
    int src, rel, dst;
    decode_edge(g, e, src, rel, dst);
    atomicAdd(&deg[rel * N_NODES + dst], 1);
}

// ---- 3-phase parallel exclusive scan; per-(chunk,dst) counts derived inline from deg ----

__global__ __launch_bounds__(256) void scan_block(const int* __restrict__ deg,
                                                  int* __restrict__ offs,
                                                  int* __restrict__ partial) {
    __shared__ int wsum[4];
    int t = threadIdx.x, lane = t & 63, w = t >> 6;
    int i = blockIdx.x * 256 + t;
    int v = 0;
    if (i < NBINS) {
        int c   = (i >= N_NODES) ? 1 : 0;
        int dst = i - c * N_NODES;
        int rlo = c * RC;
        int rhi = c ? R_AUG : RC;
        for (int r = rlo; r < rhi; r++) v += deg[r * N_NODES + dst];
    }
    int incl = v;
    #pragma unroll
    for (int off = 1; off < 64; off <<= 1) {
        int u = __shfl_up(incl, off, 64);
        if (lane >= off) incl += u;
    }
    if (lane == 63) wsum[w] = incl;
    __syncthreads();
    int woff = 0;
    for (int k = 0; k < w; k++) woff += wsum[k];
    if (i < NBINS) offs[i] = woff + incl - v;
    if (t == 255) partial[blockIdx.x] = woff + incl;
}

__global__ __launch_bounds__(256) void scan_partial(int* __restrict__ partial) {
    __shared__ int wsum[4];
    int t = threadIdx.x, lane = t & 63, w = t >> 6;
    int v = (t < NSB) ? partial[t] : 0;
    int incl = v;
    #pragma unroll
    for (int off = 1; off < 64; off <<= 1) {
        int u = __shfl_up(incl, off, 64);
        if (lane >= off) incl += u;
    }
    if (lane == 63) wsum[w] = incl;
    __syncthreads();
    int woff = 0;
    for (int k = 0; k < w; k++) woff += wsum[k];
    if (t < NSB) partial[t] = woff + incl - v;
}

__global__ __launch_bounds__(256) void scan_add(int* __restrict__ offs,
                                                const int* __restrict__ partial,
                                                int* __restrict__ cursor) {
    int i = blockIdx.x * 256 + threadIdx.x;
    if (i < NBINS) {
        int v = offs[i] + partial[i >> 8];
        offs[i] = v;
        cursor[i] = v;
    }
    if (i == 0) offs[NBINS] = E_AUG;
}

// scatter edges into (chunk,dst)-sorted order; record = (rel<<16 | src, norm bits)
// norm computed inline: exact fp32 1/deg
__global__ __launch_bounds__(256) void scatter_kernel(const int* __restrict__ g,
                                                      const int* __restrict__ deg,
                                                      int* __restrict__ cursor,
                                                      uint2* __restrict__ sorted) {
    int e = blockIdx.x * 256 + threadIdx.x;
    if (e >= E_AUG) return;
    int src, rel, dst;
    decode_edge(g, e, src, rel, dst);
    int c = (rel >= RC) ? 1 : 0;
    int pos = atomicAdd(&cursor[c * N_NODES + dst], 1);
    int dg = deg[rel * N_NODES + dst];          // >= 1 by construction
    float nrm = 1.0f / (float)dg;
    uint2 rec;
    rec.x = ((unsigned)rel << 16) | (unsigned)src;
    rec.y = f2u(nrm);
    sorted[pos] = rec;
}

__global__ __launch_bounds__(256) void relu_conv(const float* __restrict__ h,
                                                 unsigned short* __restrict__ hb) {
    int i = blockIdx.x * 256 + threadIdx.x;
    hb[i] = f2bf(fmaxf(h[i], 0.0f));
}

// ---------------- batched GEMM: Z[rc][m][o] = Xb[m][:] @ W[r0+rc][:][o] ----------------
// grid (79, rn); block 256 = 4 waves. W[r] staged in LDS; wave w covers
// output cols [w*32, w*32+32) (j=2 tiles) x all 128 rows (i=8 tiles):
// halves LDS read traffic per MFMA vs 64x64 quadrant tiling.
// mfma(b, a): D row (lq*4+reg) <-> W row (output col), D col (lane&15) <-> X row
// => lane holds 4 consecutive output cols of one Z row -> packed 8B stores.

__global__ __launch_bounds__(256) void gemm_chunk(const unsigned short* __restrict__ xb,
                                                  const unsigned short* __restrict__ Wt,
                                                  unsigned short* __restrict__ Z,
                                                  int r0) {
    __shared__ unsigned short Bs[128][136];
    int mt = blockIdx.x, rc = blockIdx.y;
    int t = threadIdx.x;
    const unsigned short* Wr = Wt + (size_t)(r0 + rc) * D * D;

    // stage W[r] (128x128 bf16): 2048 chunks of 16B, 256 threads x 8
    #pragma unroll
    for (int i = 0; i < 8; i++) {
        int c = t + 256 * i;
        int row = c >> 4, col = (c & 15) * 8;
        *(uint4*)&Bs[row][col] = *(const uint4*)(Wr + (size_t)row * D + col);
    }
    __syncthreads();

    int wave = t >> 6, lane = t & 63;
    int lr = lane & 15, lq = lane >> 4;
    int no = wave * 32;
    int m0 = mt * 128;

    f32x4 acc[2][8] = {};   // [j][i]

    #pragma unroll
    for (int ks = 0; ks < 4; ks++) {
        int kb = ks * 32 + lq * 8;
        bf16x8 b[2], a[8];
        #pragma unroll
        for (int j = 0; j < 2; j++)
            b[j] = *(const bf16x8*)(&Bs[no + j * 16 + lr][kb]);
        #pragma unroll
        for (int i = 0; i < 8; i++) {
            int m = m0 + i * 16 + lr;
            bf16x8 zv = {};
            a[i] = (m < N_NODES) ? *(const bf16x8*)(xb + (size_t)m * D + kb) : zv;
        }
        #pragma unroll
        for (int j = 0; j < 2; j++)
            #pragma unroll
            for (int i = 0; i < 8; i++)
                acc[j][i] = __builtin_amdgcn_mfma_f32_16x16x32_bf16(b[j], a[i], acc[j][i], 0, 0, 0);
    }

    #pragma unroll
    for (int i = 0; i < 8; i++) {
        int m = m0 + i * 16 + lr;
        if (m >= N_NODES) continue;
        unsigned short* zrow = Z + ((size_t)rc * N_NODES + m) * D;
        #pragma unroll
        for (int j = 0; j < 2; j++) {
            int col = no + j * 16 + lq * 4;
            ushort4 pk;
            pk.x = f2bf(acc[j][i][0]);
            pk.y = f2bf(acc[j][i][1]);
            pk.z = f2bf(acc[j][i][2]);
            pk.w = f2bf(acc[j][i][3]);
            *(ushort4*)(zrow + col) = pk;
        }
    }
}

// ---------------- aggregation: one wave per (chunk,dst), no atomics ----------------
// lane layout: group g = lane>>4 handles edge 4j+g, sublane s = lane&15 handles 8 dims
// (16B uint4 loads). 4 edges in flight per iteration; cross-group reduce at end.

__global__ __launch_bounds__(256) void agg_pass(const uint2* __restrict__ sorted,
                                                const int* __restrict__ offs,
                                                const unsigned short* __restrict__ Z,
                                                float* __restrict__ h,
                                                int c) {
    int w = threadIdx.x >> 6, lane = threadIdx.x & 63;
    int dst = blockIdx.x * 4 + w;
    if (dst >= N_NODES) return;
    int bin = c * N_NODES + dst;
    int e0 = offs[bin], e1 = offs[bin + 1];
    if (e0 == e1) return;
    int g = lane >> 4, s = lane & 15;
    int rlo = c * RC;
    float acc[8] = {};

    for (int base = e0; base < e1; base += 64) {
        int n = e1 - base; if (n > 64) n = 64;
        uint2 rec = {0u, 0u};
        if (lane < n) rec = sorted[base + lane];
        int iters = (n + 3) >> 2;
        #pragma unroll 4
        for (int j = 0; j < iters; j++) {
            int ej = j * 4 + g;
            int ec = (ej < n) ? ej : (n - 1);
            unsigned p  = (unsigned)__shfl((int)rec.x, ec, 64);
            unsigned nb = (unsigned)__shfl((int)rec.y, ec, 64);
            float nrm = (ej < n) ? u2f(nb) : 0.0f;
            int rel = (int)(p >> 16), src = (int)(p & 0xFFFFu);
            const unsigned short* zp = Z + (((size_t)(rel - rlo) * N_NODES + src) << 7) + s * 8;
            uint4 zv = *(const uint4*)zp;
            acc[0] += nrm * bf2f((unsigned short)(zv.x & 0xFFFFu));
            acc[1] += nrm * bf2f((unsigned short)(zv.x >> 16));
            acc[2] += nrm * bf2f((unsigned short)(zv.y & 0xFFFFu));
            acc[3] += nrm * bf2f((unsigned short)(zv.y >> 16));
            acc[4] += nrm * bf2f((unsigned short)(zv.z & 0xFFFFu));
            acc[5] += nrm * bf2f((unsigned short)(zv.z >> 16));
            acc[6] += nrm * bf2f((unsigned short)(zv.w & 0xFFFFu));
            acc[7] += nrm * bf2f((unsigned short)(zv.w >> 16));
        }
    }
    #pragma unroll
    for (int k = 0; k < 8; k++) {
        acc[k] += __shfl_down(acc[k], 16, 64);
        acc[k] += __shfl_down(acc[k], 32, 64);
    }
    if (g == 0) {
        float* hp = h + ((size_t)dst << 7) + s * 8;
        float4 h0 = *(float4*)hp, h1v = *(float4*)(hp + 4);
        h0.x += acc[0]; h0.y += acc[1]; h0.z += acc[2]; h0.w += acc[3];
        h1v.x += acc[4]; h1v.y += acc[5]; h1v.z += acc[6]; h1v.w += acc[7];
        *(float4*)hp = h0;
        *(float4*)(hp + 4) = h1v;
    }
}

// ---------------- scoring: 2 items per wave, float4 loads, width-32 reduce ----------------

__global__ __launch_bounds__(256) void score_kernel(const int* __restrict__ batch,
                                                    const float* __restrict__ h2,
                                                    const float* __restrict__ rels,
                                                    float* __restrict__ out) {
    int t = threadIdx.x;
    int wv = t >> 6, half = (t & 63) >> 5, sl = t & 31;
    int i = blockIdx.x * 8 + wv * 2 + half;    // grid 8192 covers 65536 exactly
    int bs = batch[3*i], bp = batch[3*i+1], bo = batch[3*i+2];
    float4 s = *(const float4*)(h2   + (size_t)bs * D + sl * 4);
    float4 p = *(const float4*)(rels + (size_t)bp * D + sl * 4);
    float4 o = *(const float4*)(h2   + (size_t)bo * D + sl * 4);
    float v = s.x * p.x * o.x + s.y * p.y * o.y + s.z * p.z * o.z + s.w * p.w * o.w;
    #pragma unroll
    for (int off = 16; off > 0; off >>= 1) v += __shfl_down(v, off, 32);
    if (sl == 0) out[i] = v;
}

// ---------------- host ----------------

extern "C" void kernel_launch(void* const* d_in, const int* in_sizes, int n_in,
                              void* d_out, int out_size, void* d_ws, size_t ws_size,
                              hipStream_t stream) {
    const int*   graph = (const int*)  d_in[0];
    const int*   batch = (const int*)  d_in[1];
    const float* emb   = (const float*)d_in[2];
    const float* W1    = (const float*)d_in[3];
    const float* b1    = (const float*)d_in[4];
    const float* W2    = (const float*)d_in[5];
    const float* b2    = (const float*)d_in[6];
    const float* rels  = (const float*)d_in[7];
    float* out = (float*)d_out;

    char* base = (char*)d_ws;
    size_t off = 0;
    auto take = [&](size_t bytes) -> char* {
        char* q = base + off;
        off += (bytes + 255) & ~(size_t)255;
        return q;
    };
    int*            deg    = (int*)           take((size_t)R_AUG * N_NODES * 4);
    unsigned short* xb     = (unsigned short*)take((size_t)N_NODES * D * 2);
    float*          h1     = (float*)         take((size_t)N_NODES * D * 4);
    float*          h2     = (float*)         take((size_t)N_NODES * D * 4);
    unsigned short* h1b    = (unsigned short*)take((size_t)N_NODES * D * 2);
    unsigned short* W1t    = (unsigned short*)take((size_t)R_AUG * D * D * 2);
    unsigned short* W2t    = (unsigned short*)take((size_t)R_AUG * D * D * 2);
    int*            offs   = (int*)           take((size_t)(NBINS + 1) * 4);
    int*            cursor = (int*)           take((size_t)NBINS * 4);
    int*            part   = (int*)           take((size_t)NSB * 4);
    uint2*          sorted = (uint2*)         take((size_t)E_AUG * 8);
    unsigned short* Z      = (unsigned short*)take((size_t)RC * N_NODES * D * 2);  // 130.6 MB

    hipMemsetAsync(deg, 0, (size_t)R_AUG * N_NODES * 4, stream);
    prep_x<<<dim3((N_NODES * D) / 256), 256, 0, stream>>>(emb, xb, h1, h2, b1, b2);
    transpose_w<<<dim3(2, 2, 2 * R_AUG), 256, 0, stream>>>(W1, W2, W1t, W2t);
    deg_hist<<<dim3((E_AUG + 255) / 256), 256, 0, stream>>>(graph, deg);
    scan_block<<<dim3(NSB), 256, 0, stream>>>(deg, offs, part);
    scan_partial<<<dim3(1), 256, 0, stream>>>(part);
    scan_add<<<dim3(NSB), 256, 0, stream>>>(offs, part, cursor);
    scatter_kernel<<<dim3((E_AUG + 255) / 256), 256, 0, stream>>>(graph, deg, cursor, sorted);

    const int nmt = (N_NODES + 127) / 128;  // 79
    for (int c = 0; c < NCHUNK; c++) {
        int r0 = c * RC;
        int rn = (R_AUG - r0 < RC) ? (R_AUG - r0) : RC;
        gemm_chunk<<<dim3(nmt, rn), 256, 0, stream>>>(xb, W1t, Z, r0);
        agg_pass<<<dim3((N_NODES + 3) / 4), 256, 0, stream>>>(sorted, offs, Z, h1, c);
    }
    relu_conv<<<dim3((N_NODES * D) / 256), 256, 0, stream>>>(h1, h1b);
    for (int c = 0; c < NCHUNK; c++) {
        int r0 = c * RC;
        int rn = (R_AUG - r0 < RC) ? (R_AUG - r0) : RC;
        gemm_chunk<<<dim3(nmt, rn), 256, 0, stream>>>(h1b, W2t, Z, r0);
        agg_pass<<<dim3((N_NODES + 3) / 4), 256, 0, stream>>>(sorted, offs, Z, h2, c);
    }
    score_kernel<<<dim3(N_BATCH / 8), 256, 0, stream>>>(batch, h2, rels, out);
}

// Round 6
// 550.158 us; speedup vs baseline: 1.3602x; 1.0860x over previous
//
#include <hip/hip_runtime.h>

#define N_NODES 10000
#define N_RELS  50
#define R_AUG   101
#define D       128
#define N_EDGES 320000
#define E_AUG   650000   /* 2*N_EDGES + N_NODES */
#define N_BATCH 65536

#define NCHUNK  2
#define RC      51                       /* chunk 0: rels 0-50, chunk 1: 51-100 */
#define NBINS   (NCHUNK * N_NODES)       /* 20000 */
#define NSB     ((NBINS + 255) / 256)    /* 79 scan blocks */

typedef short bf16x8 __attribute__((ext_vector_type(8)));
typedef float f32x4  __attribute__((ext_vector_type(4)));

__device__ __forceinline__ unsigned short f2bf(float f) {
    union { float f; unsigned int u; } v; v.f = f;
    unsigned int r = (v.u + 0x7FFFu + ((v.u >> 16) & 1u)) >> 16;
    return (unsigned short)r;
}
__device__ __forceinline__ float bf2f(unsigned short h) {
    union { unsigned int u; float f; } v; v.u = ((unsigned int)h) << 16;
    return v.f;
}
__device__ __forceinline__ float u2f(unsigned int u) {
    union { unsigned int u; float f; } v; v.u = u; return v.f;
}
__device__ __forceinline__ unsigned int f2u(float f) {
    union { float f; unsigned int u; } v; v.f = f; return v.u;
}

__device__ __forceinline__ void decode_edge(const int* __restrict__ g, int e,
                                            int& src, int& rel, int& dst) {
    if (e < N_EDGES)            { src = g[3*e];     rel = g[3*e+1];          dst = g[3*e+2]; }
    else if (e < 2*N_EDGES)     { int b = e - N_EDGES;
                                  src = g[3*b+2];   rel = g[3*b+1] + N_RELS; dst = g[3*b];   }
    else                        { int n = e - 2*N_EDGES; src = n; dst = n; rel = 2*N_RELS;   }
}

// ---------------- prep ----------------

__global__ __launch_bounds__(256) void prep_x(const float* __restrict__ x,
                                              unsigned short* __restrict__ xb,
                                              float* __restrict__ h1, float* __restrict__ h2,
                                              const float* __restrict__ b1,
                                              const float* __restrict__ b2) {
    int i = blockIdx.x * 256 + threadIdx.x;
    xb[i] = f2bf(x[i]);
    int d = i & (D - 1);
    h1[i] = b1[d];
    h2[i] = b2[d];
}

// W (r,d,o) fp32  ->  Wt (r,o,d) bf16
__global__ __launch_bounds__(256) void transpose_w(const float* __restrict__ W1,
                                                   const float* __restrict__ W2,
                                                   unsigned short* __restrict__ W1t,
                                                   unsigned short* __restrict__ W2t) {
    __shared__ float tile[64][65];
    int z = blockIdx.z;
    const float* W = (z < R_AUG) ? W1 : W2;
    unsigned short* Wt = (z < R_AUG) ? W1t : W2t;
    int r = (z < R_AUG) ? z : (z - R_AUG);
    int d0 = blockIdx.x * 64, o0 = blockIdx.y * 64;
    int tx = threadIdx.x & 63, ty = threadIdx.x >> 6;
    #pragma unroll
    for (int i = ty; i < 64; i += 4)
        tile[i][tx] = W[((size_t)r * D + (d0 + i)) * D + (o0 + tx)];
    __syncthreads();
    #pragma unroll
    for (int i = ty; i < 64; i += 4)
        Wt[((size_t)r * D + (o0 + i)) * D + (d0 + tx)] = f2bf(tile[tx][i]);
}

// degree histogram per (rel,dst): one int atomic per edge
__global__ __launch_bounds__(256) void deg_hist(const int* __restrict__ g,
                                                int* __restrict__ deg) {
    int e = blockIdx.x * 256 + threadIdx.x;
    if (e >= E_AUG) return;
    int src, rel, dst;
    decode_edge(g, e, src, rel, dst);
    atomicAdd(&deg[rel * N_NODES + dst], 1);
}

// ---- 3-phase parallel exclusive scan; per-(chunk,dst) counts derived from deg ----

__global__ __launch_bounds__(256) void scan_block(const int* __restrict__ deg,
                                                  int* __restrict__ offs,
                                                  int* __restrict__ partial) {
    __shared__ int wsum[4];
    int t = threadIdx.x, lane = t & 63, w = t >> 6;
    int i = blockIdx.x * 256 + t;
    int v = 0;
    if (i < NBINS) {
        int c   = (i >= N_NODES) ? 1 : 0;
        int dst = i - c * N_NODES;
        int rlo = c * RC;
        int rhi = c ? R_AUG : RC;
        for (int r = rlo; r < rhi; r++) v += deg[r * N_NODES + dst];
    }
    int incl = v;
    #pragma unroll
    for (int off = 1; off < 64; off <<= 1) {
        int u = __shfl_up(incl, off, 64);
        if (lane >= off) incl += u;
    }
    if (lane == 63) wsum[w] = incl;
    __syncthreads();
    int woff = 0;
    for (int k = 0; k < w; k++) woff += wsum[k];
    if (i < NBINS) offs[i] = woff + incl - v;
    if (t == 255) partial[blockIdx.x] = woff + incl;
}

__global__ __launch_bounds__(256) void scan_partial(int* __restrict__ partial) {
    __shared__ int wsum[4];
    int t = threadIdx.x, lane = t & 63, w = t >> 6;
    int v = (t < NSB) ? partial[t] : 0;
    int incl = v;
    #pragma unroll
    for (int off = 1; off < 64; off <<= 1) {
        int u = __shfl_up(incl, off, 64);
        if (lane >= off) incl += u;
    }
    if (lane == 63) wsum[w] = incl;
    __syncthreads();
    int woff = 0;
    for (int k = 0; k < w; k++) woff += wsum[k];
    if (t < NSB) partial[t] = woff + incl - v;
}

__global__ __launch_bounds__(256) void scan_add(int* __restrict__ offs,
                                                const int* __restrict__ partial,
                                                int* __restrict__ cursor) {
    int i = blockIdx.x * 256 + threadIdx.x;
    if (i < NBINS) {
        int v = offs[i] + partial[i >> 8];
        offs[i] = v;
        cursor[i] = v;
    }
    if (i == 0) offs[NBINS] = E_AUG;
}

// scatter edges into (chunk,dst)-sorted order; record = (rel<<16 | src, norm bits)
__global__ __launch_bounds__(256) void scatter_kernel(const int* __restrict__ g,
                                                      const int* __restrict__ deg,
                                                      int* __restrict__ cursor,
                                                      uint2* __restrict__ sorted) {
    int e = blockIdx.x * 256 + threadIdx.x;
    if (e >= E_AUG) return;
    int src, rel, dst;
    decode_edge(g, e, src, rel, dst);
    int c = (rel >= RC) ? 1 : 0;
    int pos = atomicAdd(&cursor[c * N_NODES + dst], 1);
    int dg = deg[rel * N_NODES + dst];          // >= 1 by construction
    float nrm = 1.0f / (float)dg;
    uint2 rec;
    rec.x = ((unsigned)rel << 16) | (unsigned)src;
    rec.y = f2u(nrm);
    sorted[pos] = rec;
}

__global__ __launch_bounds__(256) void relu_conv(const float* __restrict__ h,
                                                 unsigned short* __restrict__ hb) {
    int i = blockIdx.x * 256 + threadIdx.x;
    hb[i] = f2bf(fmaxf(h[i], 0.0f));
}

// ---------------- batched GEMM, register-resident W, no LDS, no barriers ----------------
// grid (20, rn); block 256 = 4 waves. Block handles rows [mg*512, mg*512+512) of
// relation r0+rc. Wave w owns output cols [w*32, w*32+32): its 8 W-fragments live
// in VGPRs for the whole block. Per 16-row tile: 4 global A-loads -> 8 MFMA ->
// 2 packed ushort4 stores. mfma(w, a): D row (lq*4+reg) <-> W row (output col),
// D col (lane&15) <-> X row  [layout verified rounds 3-4].

__global__ __launch_bounds__(256, 4) void gemm_chunk(const unsigned short* __restrict__ xb,
                                                     const unsigned short* __restrict__ Wt,
                                                     unsigned short* __restrict__ Z,
                                                     int r0) {
    int mg = blockIdx.x;        // 512-row group (20 total)
    int rc = blockIdx.y;
    int r  = r0 + rc;
    int t = threadIdx.x, wave = t >> 6, lane = t & 63;
    int lr = lane & 15, lq = lane >> 4;
    int no = wave * 32;
    const unsigned short* Wr = Wt + (size_t)r * D * D;

    bf16x8 w[2][4];
    #pragma unroll
    for (int j = 0; j < 2; j++)
        #pragma unroll
        for (int ks = 0; ks < 4; ks++)
            w[j][ks] = *(const bf16x8*)(Wr + (size_t)(no + j * 16 + lr) * D + ks * 32 + lq * 8);

    unsigned short* Zr = Z + (size_t)rc * N_NODES * D;
    int m0 = mg * 512;
    int mend = N_NODES - m0; if (mend > 512) mend = 512;   // N_NODES % 16 == 0: full tiles

    for (int mb = 0; mb < mend; mb += 16) {
        int m = m0 + mb + lr;
        const unsigned short* xrow = xb + (size_t)m * D + lq * 8;
        bf16x8 a[4];
        #pragma unroll
        for (int ks = 0; ks < 4; ks++)
            a[ks] = *(const bf16x8*)(xrow + ks * 32);
        f32x4 acc0 = {}, acc1 = {};
        #pragma unroll
        for (int ks = 0; ks < 4; ks++) {
            acc0 = __builtin_amdgcn_mfma_f32_16x16x32_bf16(w[0][ks], a[ks], acc0, 0, 0, 0);
            acc1 = __builtin_amdgcn_mfma_f32_16x16x32_bf16(w[1][ks], a[ks], acc1, 0, 0, 0);
        }
        unsigned short* zrow = Zr + (size_t)m * D + no + lq * 4;
        ushort4 p0, p1;
        p0.x = f2bf(acc0[0]); p0.y = f2bf(acc0[1]); p0.z = f2bf(acc0[2]); p0.w = f2bf(acc0[3]);
        p1.x = f2bf(acc1[0]); p1.y = f2bf(acc1[1]); p1.z = f2bf(acc1[2]); p1.w = f2bf(acc1[3]);
        *(ushort4*)zrow = p0;
        *(ushort4*)(zrow + 16) = p1;
    }
}

// ---------------- aggregation: one wave per (chunk,dst), no atomics ----------------
// group g = lane>>4 handles edge 4j+g, sublane s = lane&15 handles 8 dims (16B loads)

__global__ __launch_bounds__(256) void agg_pass(const uint2* __restrict__ sorted,
                                                const int* __restrict__ offs,
                                                const unsigned short* __restrict__ Z,
                                                float* __restrict__ h,
                                                int c) {
    int w = threadIdx.x >> 6, lane = threadIdx.x & 63;
    int dst = blockIdx.x * 4 + w;
    if (dst >= N_NODES) return;
    int bin = c * N_NODES + dst;
    int e0 = offs[bin], e1 = offs[bin + 1];
    if (e0 == e1) return;
    int g = lane >> 4, s = lane & 15;
    int rlo = c * RC;
    float acc[8] = {};

    for (int base = e0; base < e1; base += 64) {
        int n = e1 - base; if (n > 64) n = 64;
        uint2 rec = {0u, 0u};
        if (lane < n) rec = sorted[base + lane];
        int iters = (n + 3) >> 2;
        #pragma unroll 4
        for (int j = 0; j < iters; j++) {
            int ej = j * 4 + g;
            int ec = (ej < n) ? ej : (n - 1);
            unsigned p  = (unsigned)__shfl((int)rec.x, ec, 64);
            unsigned nb = (unsigned)__shfl((int)rec.y, ec, 64);
            float nrm = (ej < n) ? u2f(nb) : 0.0f;
            int rel = (int)(p >> 16), src = (int)(p & 0xFFFFu);
            const unsigned short* zp = Z + (((size_t)(rel - rlo) * N_NODES + src) << 7) + s * 8;
            uint4 zv = *(const uint4*)zp;
            acc[0] += nrm * bf2f((unsigned short)(zv.x & 0xFFFFu));
            acc[1] += nrm * bf2f((unsigned short)(zv.x >> 16));
            acc[2] += nrm * bf2f((unsigned short)(zv.y & 0xFFFFu));
            acc[3] += nrm * bf2f((unsigned short)(zv.y >> 16));
            acc[4] += nrm * bf2f((unsigned short)(zv.z & 0xFFFFu));
            acc[5] += nrm * bf2f((unsigned short)(zv.z >> 16));
            acc[6] += nrm * bf2f((unsigned short)(zv.w & 0xFFFFu));
            acc[7] += nrm * bf2f((unsigned short)(zv.w >> 16));
        }
    }
    #pragma unroll
    for (int k = 0; k < 8; k++) {
        acc[k] += __shfl_down(acc[k], 16, 64);
        acc[k] += __shfl_down(acc[k], 32, 64);
    }
    if (g == 0) {
        float* hp = h + ((size_t)dst << 7) + s * 8;
        float4 h0 = *(float4*)hp, h1v = *(float4*)(hp + 4);
        h0.x += acc[0]; h0.y += acc[1]; h0.z += acc[2]; h0.w += acc[3];
        h1v.x += acc[4]; h1v.y += acc[5]; h1v.z += acc[6]; h1v.w += acc[7];
        *(float4*)hp = h0;
        *(float4*)(hp + 4) = h1v;
    }
}

// ---------------- scoring ----------------

__global__ __launch_bounds__(256) void score_kernel(const int* __restrict__ batch,
                                                    const float* __restrict__ h2,
                                                    const float* __restrict__ rels,
                                                    float* __restrict__ out) {
    int t = threadIdx.x;
    int wv = t >> 6, half = (t & 63) >> 5, sl = t & 31;
    int i = blockIdx.x * 8 + wv * 2 + half;
    int bs = batch[3*i], bp = batch[3*i+1], bo = batch[3*i+2];
    float4 s = *(const float4*)(h2   + (size_t)bs * D + sl * 4);
    float4 p = *(const float4*)(rels + (size_t)bp * D + sl * 4);
    float4 o = *(const float4*)(h2   + (size_t)bo * D + sl * 4);
    float v = s.x * p.x * o.x + s.y * p.y * o.y + s.z * p.z * o.z + s.w * p.w * o.w;
    #pragma unroll
    for (int off = 16; off > 0; off >>= 1) v += __shfl_down(v, off, 32);
    if (sl == 0) out[i] = v;
}

// ---------------- host ----------------

extern "C" void kernel_launch(void* const* d_in, const int* in_sizes, int n_in,
                              void* d_out, int out_size, void* d_ws, size_t ws_size,
                              hipStream_t stream) {
    const int*   graph = (const int*)  d_in[0];
    const int*   batch = (const int*)  d_in[1];
    const float* emb   = (const float*)d_in[2];
    const float* W1    = (const float*)d_in[3];
    const float* b1    = (const float*)d_in[4];
    const float* W2    = (const float*)d_in[5];
    const float* b2    = (const float*)d_in[6];
    const float* rels  = (const float*)d_in[7];
    float* out = (float*)d_out;

    char* base = (char*)d_ws;
    size_t off = 0;
    auto take = [&](size_t bytes) -> char* {
        char* q = base + off;
        off += (bytes + 255) & ~(size_t)255;
        return q;
    };
    int*            deg    = (int*)           take((size_t)R_AUG * N_NODES * 4);
    unsigned short* xb     = (unsigned short*)take((size_t)N_NODES * D * 2);
    float*          h1     = (float*)         take((size_t)N_NODES * D * 4);
    float*          h2     = (float*)         take((size_t)N_NODES * D * 4);
    unsigned short* h1b    = (unsigned short*)take((size_t)N_NODES * D * 2);
    unsigned short* W1t    = (unsigned short*)take((size_t)R_AUG * D * D * 2);
    unsigned short* W2t    = (unsigned short*)take((size_t)R_AUG * D * D * 2);
    int*            offs   = (int*)           take((size_t)(NBINS + 1) * 4);
    int*            cursor = (int*)           take((size_t)NBINS * 4);
    int*            part   = (int*)           take((size_t)NSB * 4);
    uint2*          sorted = (uint2*)         take((size_t)E_AUG * 8);
    unsigned short* Z      = (unsigned short*)take((size_t)RC * N_NODES * D * 2);  // 130.6 MB

    hipMemsetAsync(deg, 0, (size_t)R_AUG * N_NODES * 4, stream);
    prep_x<<<dim3((N_NODES * D) / 256), 256, 0, stream>>>(emb, xb, h1, h2, b1, b2);
    transpose_w<<<dim3(2, 2, 2 * R_AUG), 256, 0, stream>>>(W1, W2, W1t, W2t);
    deg_hist<<<dim3((E_AUG + 255) / 256), 256, 0, stream>>>(graph, deg);
    scan_block<<<dim3(NSB), 256, 0, stream>>>(deg, offs, part);
    scan_partial<<<dim3(1), 256, 0, stream>>>(part);
    scan_add<<<dim3(NSB), 256, 0, stream>>>(offs, part, cursor);
    scatter_kernel<<<dim3((E_AUG + 255) / 256), 256, 0, stream>>>(graph, deg, cursor, sorted);

    for (int c = 0; c < NCHUNK; c++) {
        int r0 = c * RC;
        int rn = (R_AUG - r0 < RC) ? (R_AUG - r0) : RC;
        gemm_chunk<<<dim3(20, rn), 256, 0, stream>>>(xb, W1t, Z, r0);
        agg_pass<<<dim3((N_NODES + 3) / 4), 256, 0, stream>>>(sorted, offs, Z, h1, c);
    }
    relu_conv<<<dim3((N_NODES * D) / 256), 256, 0, stream>>>(h1, h1b);
    for (int c = 0; c < NCHUNK; c++) {
        int r0 = c * RC;
        int rn = (R_AUG - r0 < RC) ? (R_AUG - r0) : RC;
        gemm_chunk<<<dim3(20, rn), 256, 0, stream>>>(h1b, W2t, Z, r0);
        agg_pass<<<dim3((N_NODES + 3) / 4), 256, 0, stream>>>(sorted, offs, Z, h2, c);
    }
    score_kernel<<<dim3(N_BATCH / 8), 256, 0, stream>>>(batch, h2, rels, out);
}

// Round 7
// 541.492 us; speedup vs baseline: 1.3820x; 1.0160x over previous
//
#include <hip/hip_runtime.h>

#define N_NODES 10000
#define N_RELS  50
#define R_AUG   101
#define D       128
#define N_EDGES 320000
#define E_AUG   650000   /* 2*N_EDGES + N_NODES */
#define N_BATCH 65536

#define NCHUNK  2
#define RC      51                       /* chunk 0: rels 0-50, chunk 1: 51-100 */
#define NBINS   (NCHUNK * N_NODES)       /* 20000 */
#define NSB     ((NBINS + 255) / 256)    /* 79 scan blocks */

/* fused prep kernel block ranges */
#define PREPX_BLOCKS 5000                /* N_NODES*D/256 */
#define TW_BLOCKS    808                 /* 2*2*(2*R_AUG) */
#define HIST_BLOCKS  2540                /* ceil(E_AUG/256) */

typedef short bf16x8 __attribute__((ext_vector_type(8)));
typedef float f32x4  __attribute__((ext_vector_type(4)));

__device__ __forceinline__ unsigned short f2bf(float f) {
    union { float f; unsigned int u; } v; v.f = f;
    unsigned int r = (v.u + 0x7FFFu + ((v.u >> 16) & 1u)) >> 16;
    return (unsigned short)r;
}
__device__ __forceinline__ float bf2f(unsigned short h) {
    union { unsigned int u; float f; } v; v.u = ((unsigned int)h) << 16;
    return v.f;
}
__device__ __forceinline__ float u2f(unsigned int u) {
    union { unsigned int u; float f; } v; v.u = u; return v.f;
}
__device__ __forceinline__ unsigned int f2u(float f) {
    union { float f; unsigned int u; } v; v.f = f; return v.u;
}

__device__ __forceinline__ void decode_edge(const int* __restrict__ g, int e,
                                            int& src, int& rel, int& dst) {
    if (e < N_EDGES)            { src = g[3*e];     rel = g[3*e+1];          dst = g[3*e+2]; }
    else if (e < 2*N_EDGES)     { int b = e - N_EDGES;
                                  src = g[3*b+2];   rel = g[3*b+1] + N_RELS; dst = g[3*b];   }
    else                        { int n = e - 2*N_EDGES; src = n; dst = n; rel = 2*N_RELS;   }
}

// ---------------- fused prep: prep_x | transpose_w | deg_hist (independent work) ----------------

__global__ __launch_bounds__(256) void prep_all(const float* __restrict__ x,
                                                unsigned short* __restrict__ xb,
                                                float* __restrict__ h1, float* __restrict__ h2,
                                                const float* __restrict__ b1,
                                                const float* __restrict__ b2,
                                                const float* __restrict__ W1,
                                                const float* __restrict__ W2,
                                                unsigned short* __restrict__ W1t,
                                                unsigned short* __restrict__ W2t,
                                                const int* __restrict__ g,
                                                int* __restrict__ deg) {
    __shared__ float tile[64][65];
    int b = blockIdx.x, t = threadIdx.x;
    if (b < PREPX_BLOCKS) {
        int i = b * 256 + t;
        xb[i] = f2bf(x[i]);
        int d = i & (D - 1);
        h1[i] = b1[d];
        h2[i] = b2[d];
    } else if (b < PREPX_BLOCKS + TW_BLOCKS) {
        int q = b - PREPX_BLOCKS;
        int d0 = (q & 1) * 64, o0 = ((q >> 1) & 1) * 64;
        int z = q >> 2;                                  /* 0..201 */
        const float* W = (z < R_AUG) ? W1 : W2;
        unsigned short* Wt = (z < R_AUG) ? W1t : W2t;
        int r = (z < R_AUG) ? z : (z - R_AUG);
        int tx = t & 63, ty = t >> 6;
        #pragma unroll
        for (int i = ty; i < 64; i += 4)
            tile[i][tx] = W[((size_t)r * D + (d0 + i)) * D + (o0 + tx)];
        __syncthreads();
        #pragma unroll
        for (int i = ty; i < 64; i += 4)
            Wt[((size_t)r * D + (o0 + i)) * D + (d0 + tx)] = f2bf(tile[tx][i]);
    } else {
        int e = (b - PREPX_BLOCKS - TW_BLOCKS) * 256 + t;
        if (e < E_AUG) {
            int src, rel, dst;
            decode_edge(g, e, src, rel, dst);
            atomicAdd(&deg[rel * N_NODES + dst], 1);
        }
    }
}

// ---- 3-phase parallel exclusive scan; per-(chunk,dst) counts derived from deg ----

__global__ __launch_bounds__(256) void scan_block(const int* __restrict__ deg,
                                                  int* __restrict__ offs,
                                                  int* __restrict__ partial) {
    __shared__ int wsum[4];
    int t = threadIdx.x, lane = t & 63, w = t >> 6;
    int i = blockIdx.x * 256 + t;
    int v = 0;
    if (i < NBINS) {
        int c   = (i >= N_NODES) ? 1 : 0;
        int dst = i - c * N_NODES;
        int rlo = c * RC;
        int rhi = c ? R_AUG : RC;
        for (int r = rlo; r < rhi; r++) v += deg[r * N_NODES + dst];
    }
    int incl = v;
    #pragma unroll
    for (int off = 1; off < 64; off <<= 1) {
        int u = __shfl_up(incl, off, 64);
        if (lane >= off) incl += u;
    }
    if (lane == 63) wsum[w] = incl;
    __syncthreads();
    int woff = 0;
    for (int k = 0; k < w; k++) woff += wsum[k];
    if (i < NBINS) offs[i] = woff + incl - v;
    if (t == 255) partial[blockIdx.x] = woff + incl;
}

__global__ __launch_bounds__(256) void scan_partial(int* __restrict__ partial) {
    __shared__ int wsum[4];
    int t = threadIdx.x, lane = t & 63, w = t >> 6;
    int v = (t < NSB) ? partial[t] : 0;
    int incl = v;
    #pragma unroll
    for (int off = 1; off < 64; off <<= 1) {
        int u = __shfl_up(incl, off, 64);
        if (lane >= off) incl += u;
    }
    if (lane == 63) wsum[w] = incl;
    __syncthreads();
    int woff = 0;
    for (int k = 0; k < w; k++) woff += wsum[k];
    if (t < NSB) partial[t] = woff + incl - v;
}

__global__ __launch_bounds__(256) void scan_add(int* __restrict__ offs,
                                                const int* __restrict__ partial,
                                                int* __restrict__ cursor) {
    int i = blockIdx.x * 256 + threadIdx.x;
    if (i < NBINS) {
        int v = offs[i] + partial[i >> 8];
        offs[i] = v;
        cursor[i] = v;
    }
    if (i == 0) offs[NBINS] = E_AUG;
}

// scatter edges into (chunk,dst)-sorted order; record = (rel<<16 | src, norm bits)
__global__ __launch_bounds__(256) void scatter_kernel(const int* __restrict__ g,
                                                      const int* __restrict__ deg,
                                                      int* __restrict__ cursor,
                                                      uint2* __restrict__ sorted) {
    int e = blockIdx.x * 256 + threadIdx.x;
    if (e >= E_AUG) return;
    int src, rel, dst;
    decode_edge(g, e, src, rel, dst);
    int c = (rel >= RC) ? 1 : 0;
    int pos = atomicAdd(&cursor[c * N_NODES + dst], 1);
    int dg = deg[rel * N_NODES + dst];          // >= 1 by construction
    float nrm = 1.0f / (float)dg;
    uint2 rec;
    rec.x = ((unsigned)rel << 16) | (unsigned)src;
    rec.y = f2u(nrm);
    sorted[pos] = rec;
}

__global__ __launch_bounds__(256) void relu_conv(const float* __restrict__ h,
                                                 unsigned short* __restrict__ hb) {
    int i = blockIdx.x * 256 + threadIdx.x;
    hb[i] = f2bf(fmaxf(h[i], 0.0f));
}

// ---------------- batched GEMM, register-resident W, no LDS, A-prefetch, 16B stores ----------------
// grid (40, rn); block 256 = 4 waves, 256 rows/block. Wave w owns output cols
// [w*32, w*32+32); its 8 W-fragments live in VGPRs for the whole block, with rows
// PERMUTED (MFMA j covers W rows no + (m>>2)*8 + j*4 + (m&3)) so that lane (lr,lq)
// ends up holding output cols no+lq*8+{0..7} of row m0+mb+lr -> one 16B store/tile.
// Next tile's A-loads issue before current tile's MFMAs (vmcnt overlap).

__global__ __launch_bounds__(256, 4) void gemm_chunk(const unsigned short* __restrict__ xb,
                                                     const unsigned short* __restrict__ Wt,
                                                     unsigned short* __restrict__ Z,
                                                     int r0) {
    int mg = blockIdx.x;        // 256-row group (40 total)
    int rc = blockIdx.y;
    int t = threadIdx.x, wave = t >> 6, lane = t & 63;
    int lr = lane & 15, lq = lane >> 4;
    int no = wave * 32;
    const unsigned short* Wr = Wt + (size_t)(r0 + rc) * D * D;

    int row0 = no + ((lr >> 2) << 3) + (lr & 3);   // permuted row for MFMA j=0; j=1 is +4
    bf16x8 w0[4], w1[4];
    #pragma unroll
    for (int ks = 0; ks < 4; ks++) {
        w0[ks] = *(const bf16x8*)(Wr + (size_t)row0 * D + ks * 32 + lq * 8);
        w1[ks] = *(const bf16x8*)(Wr + (size_t)(row0 + 4) * D + ks * 32 + lq * 8);
    }

    unsigned short* Zr = Z + (size_t)rc * N_NODES * D;
    int m0 = mg * 256;
    int mend = N_NODES - m0; if (mend > 256) mend = 256;   // multiple of 16

    bf16x8 a[4];
    {
        const unsigned short* xrow = xb + (size_t)(m0 + lr) * D + lq * 8;
        #pragma unroll
        for (int ks = 0; ks < 4; ks++) a[ks] = *(const bf16x8*)(xrow + ks * 32);
    }

    for (int mb = 0; mb < mend; mb += 16) {
        int mbn = mb + 16 < mend ? mb + 16 : mb;           // clamp: redundant reload on last
        const unsigned short* xnxt = xb + (size_t)(m0 + mbn + lr) * D + lq * 8;
        bf16x8 an[4];
        #pragma unroll
        for (int ks = 0; ks < 4; ks++) an[ks] = *(const bf16x8*)(xnxt + ks * 32);

        f32x4 acc0 = {}, acc1 = {};
        #pragma unroll
        for (int ks = 0; ks < 4; ks++) {
            acc0 = __builtin_amdgcn_mfma_f32_16x16x32_bf16(w0[ks], a[ks], acc0, 0, 0, 0);
            acc1 = __builtin_amdgcn_mfma_f32_16x16x32_bf16(w1[ks], a[ks], acc1, 0, 0, 0);
        }
        uint4 pk;
        pk.x = (unsigned)f2bf(acc0[0]) | ((unsigned)f2bf(acc0[1]) << 16);
        pk.y = (unsigned)f2bf(acc0[2]) | ((unsigned)f2bf(acc0[3]) << 16);
        pk.z = (unsigned)f2bf(acc1[0]) | ((unsigned)f2bf(acc1[1]) << 16);
        pk.w = (unsigned)f2bf(acc1[2]) | ((unsigned)f2bf(acc1[3]) << 16);
        *(uint4*)(Zr + (size_t)(m0 + mb + lr) * D + no + lq * 8) = pk;

        #pragma unroll
        for (int ks = 0; ks < 4; ks++) a[ks] = an[ks];
    }
}

// ---------------- aggregation: one wave per (chunk,dst), no atomics ----------------

__global__ __launch_bounds__(256) void agg_pass(const uint2* __restrict__ sorted,
                                                const int* __restrict__ offs,
                                                const unsigned short* __restrict__ Z,
                                                float* __restrict__ h,
                                                int c) {
    int w = threadIdx.x >> 6, lane = threadIdx.x & 63;
    int dst = blockIdx.x * 4 + w;
    if (dst >= N_NODES) return;
    int bin = c * N_NODES + dst;
    int e0 = offs[bin], e1 = offs[bin + 1];
    if (e0 == e1) return;
    int g = lane >> 4, s = lane & 15;
    int rlo = c * RC;
    float acc[8] = {};

    for (int base = e0; base < e1; base += 64) {
        int n = e1 - base; if (n > 64) n = 64;
        uint2 rec = {0u, 0u};
        if (lane < n) rec = sorted[base + lane];
        int iters = (n + 3) >> 2;
        #pragma unroll 4
        for (int j = 0; j < iters; j++) {
            int ej = j * 4 + g;
            int ec = (ej < n) ? ej : (n - 1);
            unsigned p  = (unsigned)__shfl((int)rec.x, ec, 64);
            unsigned nb = (unsigned)__shfl((int)rec.y, ec, 64);
            float nrm = (ej < n) ? u2f(nb) : 0.0f;
            int rel = (int)(p >> 16), src = (int)(p & 0xFFFFu);
            const unsigned short* zp = Z + (((size_t)(rel - rlo) * N_NODES + src) << 7) + s * 8;
            uint4 zv = *(const uint4*)zp;
            acc[0] += nrm * bf2f((unsigned short)(zv.x & 0xFFFFu));
            acc[1] += nrm * bf2f((unsigned short)(zv.x >> 16));
            acc[2] += nrm * bf2f((unsigned short)(zv.y & 0xFFFFu));
            acc[3] += nrm * bf2f((unsigned short)(zv.y >> 16));
            acc[4] += nrm * bf2f((unsigned short)(zv.z & 0xFFFFu));
            acc[5] += nrm * bf2f((unsigned short)(zv.z >> 16));
            acc[6] += nrm * bf2f((unsigned short)(zv.w & 0xFFFFu));
            acc[7] += nrm * bf2f((unsigned short)(zv.w >> 16));
        }
    }
    #pragma unroll
    for (int k = 0; k < 8; k++) {
        acc[k] += __shfl_down(acc[k], 16, 64);
        acc[k] += __shfl_down(acc[k], 32, 64);
    }
    if (g == 0) {
        float* hp = h + ((size_t)dst << 7) + s * 8;
        float4 h0 = *(float4*)hp, h1v = *(float4*)(hp + 4);
        h0.x += acc[0]; h0.y += acc[1]; h0.z += acc[2]; h0.w += acc[3];
        h1v.x += acc[4]; h1v.y += acc[5]; h1v.z += acc[6]; h1v.w += acc[7];
        *(float4*)hp = h0;
        *(float4*)(hp + 4) = h1v;
    }
}

// ---------------- scoring ----------------

__global__ __launch_bounds__(256) void score_kernel(const int* __restrict__ batch,
                                                    const float* __restrict__ h2,
                                                    const float* __restrict__ rels,
                                                    float* __restrict__ out) {
    int t = threadIdx.x;
    int wv = t >> 6, half = (t & 63) >> 5, sl = t & 31;
    int i = blockIdx.x * 8 + wv * 2 + half;
    int bs = batch[3*i], bp = batch[3*i+1], bo = batch[3*i+2];
    float4 s = *(const float4*)(h2   + (size_t)bs * D + sl * 4);
    float4 p = *(const float4*)(rels + (size_t)bp * D + sl * 4);
    float4 o = *(const float4*)(h2   + (size_t)bo * D + sl * 4);
    float v = s.x * p.x * o.x + s.y * p.y * o.y + s.z * p.z * o.z + s.w * p.w * o.w;
    #pragma unroll
    for (int off = 16; off > 0; off >>= 1) v += __shfl_down(v, off, 32);
    if (sl == 0) out[i] = v;
}

// ---------------- host ----------------

extern "C" void kernel_launch(void* const* d_in, const int* in_sizes, int n_in,
                              void* d_out, int out_size, void* d_ws, size_t ws_size,
                              hipStream_t stream) {
    const int*   graph = (const int*)  d_in[0];
    const int*   batch = (const int*)  d_in[1];
    const float* emb   = (const float*)d_in[2];
    const float* W1    = (const float*)d_in[3];
    const float* b1    = (const float*)d_in[4];
    const float* W2    = (const float*)d_in[5];
    const float* b2    = (const float*)d_in[6];
    const float* rels  = (const float*)d_in[7];
    float* out = (float*)d_out;

    char* base = (char*)d_ws;
    size_t off = 0;
    auto take = [&](size_t bytes) -> char* {
        char* q = base + off;
        off += (bytes + 255) & ~(size_t)255;
        return q;
    };
    int*            deg    = (int*)           take((size_t)R_AUG * N_NODES * 4);
    unsigned short* xb     = (unsigned short*)take((size_t)N_NODES * D * 2);
    float*          h1     = (float*)         take((size_t)N_NODES * D * 4);
    float*          h2     = (float*)         take((size_t)N_NODES * D * 4);
    unsigned short* h1b    = (unsigned short*)take((size_t)N_NODES * D * 2);
    unsigned short* W1t    = (unsigned short*)take((size_t)R_AUG * D * D * 2);
    unsigned short* W2t    = (unsigned short*)take((size_t)R_AUG * D * D * 2);
    int*            offs   = (int*)           take((size_t)(NBINS + 1) * 4);
    int*            cursor = (int*)           take((size_t)NBINS * 4);
    int*            part   = (int*)           take((size_t)NSB * 4);
    uint2*          sorted = (uint2*)         take((size_t)E_AUG * 8);
    unsigned short* Z      = (unsigned short*)take((size_t)RC * N_NODES * D * 2);  // 130.6 MB

    hipMemsetAsync(deg, 0, (size_t)R_AUG * N_NODES * 4, stream);
    prep_all<<<dim3(PREPX_BLOCKS + TW_BLOCKS + HIST_BLOCKS), 256, 0, stream>>>(
        emb, xb, h1, h2, b1, b2, W1, W2, W1t, W2t, graph, deg);
    scan_block<<<dim3(NSB), 256, 0, stream>>>(deg, offs, part);
    scan_partial<<<dim3(1), 256, 0, stream>>>(part);
    scan_add<<<dim3(NSB), 256, 0, stream>>>(offs, part, cursor);
    scatter_kernel<<<dim3((E_AUG + 255) / 256), 256, 0, stream>>>(graph, deg, cursor, sorted);

    for (int c = 0; c < NCHUNK; c++) {
        int r0 = c * RC;
        int rn = (R_AUG - r0 < RC) ? (R_AUG - r0) : RC;
        gemm_chunk<<<dim3(40, rn), 256, 0, stream>>>(xb, W1t, Z, r0);
        agg_pass<<<dim3((N_NODES + 3) / 4), 256, 0, stream>>>(sorted, offs, Z, h1, c);
    }
    relu_conv<<<dim3((N_NODES * D) / 256), 256, 0, stream>>>(h1, h1b);
    for (int c = 0; c < NCHUNK; c++) {
        int r0 = c * RC;
        int rn = (R_AUG - r0 < RC) ? (R_AUG - r0) : RC;
        gemm_chunk<<<dim3(40, rn), 256, 0, stream>>>(h1b, W2t, Z, r0);
        agg_pass<<<dim3((N_NODES + 3) / 4), 256, 0, stream>>>(sorted, offs, Z, h2, c);
    }
    score_kernel<<<dim3(N_BATCH / 8), 256, 0, stream>>>(batch, h2, rels, out);
}

// Round 8
// 461.935 us; speedup vs baseline: 1.6200x; 1.1722x over previous
//
#include <hip/hip_runtime.h>

#define N_NODES 10000
#define N_RELS  50
#define R_AUG   101
#define D       128
#define N_EDGES 320000
#define E_AUG   650000   /* 2*N_EDGES + N_NODES */
#define N_BATCH 65536

#define NCHUNK  2
#define RC      51                       /* chunk 0: rels 0-50, chunk 1: 51-100 */
#define NBINS   (NCHUNK * N_NODES)       /* 20000 */
#define NSB     ((NBINS + 255) / 256)    /* 79 scan blocks */

/* fused prep kernel block ranges */
#define PREPX_BLOCKS 5000                /* N_NODES*D/256 */
#define TW_BLOCKS    808                 /* 2*2*(2*R_AUG) */
#define HIST_BLOCKS  2540                /* ceil(E_AUG/256) */

typedef short bf16x8 __attribute__((ext_vector_type(8)));
typedef float f32x4  __attribute__((ext_vector_type(4)));

__device__ __forceinline__ unsigned short f2bf(float f) {
    union { float f; unsigned int u; } v; v.f = f;
    unsigned int r = (v.u + 0x7FFFu + ((v.u >> 16) & 1u)) >> 16;
    return (unsigned short)r;
}
__device__ __forceinline__ float bf2f(unsigned short h) {
    union { unsigned int u; float f; } v; v.u = ((unsigned int)h) << 16;
    return v.f;
}
__device__ __forceinline__ float u2f(unsigned int u) {
    union { unsigned int u; float f; } v; v.u = u; return v.f;
}
__device__ __forceinline__ unsigned int f2u(float f) {
    union { float f; unsigned int u; } v; v.f = f; return v.u;
}

__device__ __forceinline__ void decode_edge(const int* __restrict__ g, int e,
                                            int& src, int& rel, int& dst) {
    if (e < N_EDGES)            { src = g[3*e];     rel = g[3*e+1];          dst = g[3*e+2]; }
    else if (e < 2*N_EDGES)     { int b = e - N_EDGES;
                                  src = g[3*b+2];   rel = g[3*b+1] + N_RELS; dst = g[3*b];   }
    else                        { int n = e - 2*N_EDGES; src = n; dst = n; rel = 2*N_RELS;   }
}

// ---------------- fused prep: prep_x | transpose_w | deg_hist (independent work) ----------------

__global__ __launch_bounds__(256) void prep_all(const float* __restrict__ x,
                                                unsigned short* __restrict__ xb,
                                                float* __restrict__ h1, float* __restrict__ h2,
                                                const float* __restrict__ b1,
                                                const float* __restrict__ b2,
                                                const float* __restrict__ W1,
                                                const float* __restrict__ W2,
                                                unsigned short* __restrict__ W1t,
                                                unsigned short* __restrict__ W2t,
                                                const int* __restrict__ g,
                                                int* __restrict__ deg) {
    __shared__ float tile[64][65];
    int b = blockIdx.x, t = threadIdx.x;
    if (b < PREPX_BLOCKS) {
        int i = b * 256 + t;
        xb[i] = f2bf(x[i]);
        int d = i & (D - 1);
        h1[i] = b1[d];
        h2[i] = b2[d];
    } else if (b < PREPX_BLOCKS + TW_BLOCKS) {
        int q = b - PREPX_BLOCKS;
        int d0 = (q & 1) * 64, o0 = ((q >> 1) & 1) * 64;
        int z = q >> 2;                                  /* 0..201 */
        const float* W = (z < R_AUG) ? W1 : W2;
        unsigned short* Wt = (z < R_AUG) ? W1t : W2t;
        int r = (z < R_AUG) ? z : (z - R_AUG);
        int tx = t & 63, ty = t >> 6;
        #pragma unroll
        for (int i = ty; i < 64; i += 4)
            tile[i][tx] = W[((size_t)r * D + (d0 + i)) * D + (o0 + tx)];
        __syncthreads();
        #pragma unroll
        for (int i = ty; i < 64; i += 4)
            Wt[((size_t)r * D + (o0 + i)) * D + (d0 + tx)] = f2bf(tile[tx][i]);
    } else {
        int e = (b - PREPX_BLOCKS - TW_BLOCKS) * 256 + t;
        if (e < E_AUG) {
            int src, rel, dst;
            decode_edge(g, e, src, rel, dst);
            atomicAdd(&deg[rel * N_NODES + dst], 1);
        }
    }
}

// ---- 3-phase parallel exclusive scan; per-(chunk,dst) counts derived from deg ----

__global__ __launch_bounds__(256) void scan_block(const int* __restrict__ deg,
                                                  int* __restrict__ offs,
                                                  int* __restrict__ partial) {
    __shared__ int wsum[4];
    int t = threadIdx.x, lane = t & 63, w = t >> 6;
    int i = blockIdx.x * 256 + t;
    int v = 0;
    if (i < NBINS) {
        int c   = (i >= N_NODES) ? 1 : 0;
        int dst = i - c * N_NODES;
        int rlo = c * RC;
        int rhi = c ? R_AUG : RC;
        for (int r = rlo; r < rhi; r++) v += deg[r * N_NODES + dst];
    }
    int incl = v;
    #pragma unroll
    for (int off = 1; off < 64; off <<= 1) {
        int u = __shfl_up(incl, off, 64);
        if (lane >= off) incl += u;
    }
    if (lane == 63) wsum[w] = incl;
    __syncthreads();
    int woff = 0;
    for (int k = 0; k < w; k++) woff += wsum[k];
    if (i < NBINS) offs[i] = woff + incl - v;
    if (t == 255) partial[blockIdx.x] = woff + incl;
}

__global__ __launch_bounds__(256) void scan_partial(int* __restrict__ partial) {
    __shared__ int wsum[4];
    int t = threadIdx.x, lane = t & 63, w = t >> 6;
    int v = (t < NSB) ? partial[t] : 0;
    int incl = v;
    #pragma unroll
    for (int off = 1; off < 64; off <<= 1) {
        int u = __shfl_up(incl, off, 64);
        if (lane >= off) incl += u;
    }
    if (lane == 63) wsum[w] = incl;
    __syncthreads();
    int woff = 0;
    for (int k = 0; k < w; k++) woff += wsum[k];
    if (t < NSB) partial[t] = woff + incl - v;
}

__global__ __launch_bounds__(256) void scan_add(int* __restrict__ offs,
                                                const int* __restrict__ partial,
                                                int* __restrict__ cursor) {
    int i = blockIdx.x * 256 + threadIdx.x;
    if (i < NBINS) {
        int v = offs[i] + partial[i >> 8];
        offs[i] = v;
        cursor[i] = v;
    }
    if (i == 0) offs[NBINS] = E_AUG;
}

// scatter edges into (chunk,dst)-sorted order; record = (rel<<16 | src, norm bits)
__global__ __launch_bounds__(256) void scatter_kernel(const int* __restrict__ g,
                                                      const int* __restrict__ deg,
                                                      int* __restrict__ cursor,
                                                      uint2* __restrict__ sorted) {
    int e = blockIdx.x * 256 + threadIdx.x;
    if (e >= E_AUG) return;
    int src, rel, dst;
    decode_edge(g, e, src, rel, dst);
    int c = (rel >= RC) ? 1 : 0;
    int pos = atomicAdd(&cursor[c * N_NODES + dst], 1);
    int dg = deg[rel * N_NODES + dst];          // >= 1 by construction
    float nrm = 1.0f / (float)dg;
    uint2 rec;
    rec.x = ((unsigned)rel << 16) | (unsigned)src;
    rec.y = f2u(nrm);
    sorted[pos] = rec;
}

__global__ __launch_bounds__(256) void relu_conv(const float* __restrict__ h,
                                                 unsigned short* __restrict__ hb) {
    int i = blockIdx.x * 256 + threadIdx.x;
    hb[i] = f2bf(fmaxf(h[i], 0.0f));
}

// ---------------- batched GEMM: TWO relations per block, register-resident W ----------------
// grid (79, ceil(rn/2)); block 256 = 4 waves, 128 rows/block. Wave w owns output
// cols [w*32, w*32+32) for BOTH relations ra=2*rp and rb=ra+1; all W fragments
// (2 rels x 8 frags = 64 VGPRs) live in registers for the whole block. Per 16-row
// tile: 4 global A-loads feed 16 MFMAs (load:MFMA ratio 0.25 = R2's, the best
// measured point of the load-ratio law) -> 2 packed 16B stores.
// W rows PERMUTED at load (MFMA j covers rows no+(m>>2)*8+j*4+(m&3)) so lane
// (lr,lq) holds output cols no+lq*8+{0..7} of row m0+mb+lr -> one uint4 per rel.

__global__ __launch_bounds__(256, 4) void gemm_chunk(const unsigned short* __restrict__ xb,
                                                     const unsigned short* __restrict__ Wt,
                                                     unsigned short* __restrict__ Z,
                                                     int r0, int rn) {
    int mg = blockIdx.x;        // 128-row group (79 total)
    int rp = blockIdx.y;        // relation pair
    int t = threadIdx.x, wave = t >> 6, lane = t & 63;
    int lr = lane & 15, lq = lane >> 4;
    int no = wave * 32;

    int ra = rp * 2;
    int hasB = (ra + 1 < rn) ? 1 : 0;
    int rb = hasB ? ra + 1 : ra;
    const unsigned short* WA = Wt + (size_t)(r0 + ra) * D * D;
    const unsigned short* WB = Wt + (size_t)(r0 + rb) * D * D;

    int row0 = no + ((lr >> 2) << 3) + (lr & 3);   // permuted row for MFMA j=0; j=1 is +4
    bf16x8 wa0[4], wa1[4], wb0[4], wb1[4];
    #pragma unroll
    for (int ks = 0; ks < 4; ks++) {
        size_t o0 = (size_t)row0 * D + ks * 32 + lq * 8;
        size_t o1 = (size_t)(row0 + 4) * D + ks * 32 + lq * 8;
        wa0[ks] = *(const bf16x8*)(WA + o0);
        wa1[ks] = *(const bf16x8*)(WA + o1);
        wb0[ks] = *(const bf16x8*)(WB + o0);
        wb1[ks] = *(const bf16x8*)(WB + o1);
    }

    unsigned short* Za = Z + (size_t)ra * N_NODES * D;
    unsigned short* Zb = Z + (size_t)rb * N_NODES * D;
    int m0 = mg * 128;
    int mend = N_NODES - m0; if (mend > 128) mend = 128;   // multiple of 16

    for (int mb = 0; mb < mend; mb += 16) {
        int m = m0 + mb + lr;
        const unsigned short* xrow = xb + (size_t)m * D + lq * 8;
        bf16x8 a[4];
        #pragma unroll
        for (int ks = 0; ks < 4; ks++)
            a[ks] = *(const bf16x8*)(xrow + ks * 32);

        f32x4 aa0 = {}, aa1 = {}, ab0 = {}, ab1 = {};
        #pragma unroll
        for (int ks = 0; ks < 4; ks++) {
            aa0 = __builtin_amdgcn_mfma_f32_16x16x32_bf16(wa0[ks], a[ks], aa0, 0, 0, 0);
            aa1 = __builtin_amdgcn_mfma_f32_16x16x32_bf16(wa1[ks], a[ks], aa1, 0, 0, 0);
            ab0 = __builtin_amdgcn_mfma_f32_16x16x32_bf16(wb0[ks], a[ks], ab0, 0, 0, 0);
            ab1 = __builtin_amdgcn_mfma_f32_16x16x32_bf16(wb1[ks], a[ks], ab1, 0, 0, 0);
        }

        size_t zoff = (size_t)m * D + no + lq * 8;
        uint4 pa;
        pa.x = (unsigned)f2bf(aa0[0]) | ((unsigned)f2bf(aa0[1]) << 16);
        pa.y = (unsigned)f2bf(aa0[2]) | ((unsigned)f2bf(aa0[3]) << 16);
        pa.z = (unsigned)f2bf(aa1[0]) | ((unsigned)f2bf(aa1[1]) << 16);
        pa.w = (unsigned)f2bf(aa1[2]) | ((unsigned)f2bf(aa1[3]) << 16);
        *(uint4*)(Za + zoff) = pa;
        if (hasB) {
            uint4 pb;
            pb.x = (unsigned)f2bf(ab0[0]) | ((unsigned)f2bf(ab0[1]) << 16);
            pb.y = (unsigned)f2bf(ab0[2]) | ((unsigned)f2bf(ab0[3]) << 16);
            pb.z = (unsigned)f2bf(ab1[0]) | ((unsigned)f2bf(ab1[1]) << 16);
            pb.w = (unsigned)f2bf(ab1[2]) | ((unsigned)f2bf(ab1[3]) << 16);
            *(uint4*)(Zb + zoff) = pb;
        }
    }
}

// ---------------- aggregation: one wave per (chunk,dst), no atomics ----------------

__global__ __launch_bounds__(256) void agg_pass(const uint2* __restrict__ sorted,
                                                const int* __restrict__ offs,
                                                const unsigned short* __restrict__ Z,
                                                float* __restrict__ h,
                                                int c) {
    int w = threadIdx.x >> 6, lane = threadIdx.x & 63;
    int dst = blockIdx.x * 4 + w;
    if (dst >= N_NODES) return;
    int bin = c * N_NODES + dst;
    int e0 = offs[bin], e1 = offs[bin + 1];
    if (e0 == e1) return;
    int g = lane >> 4, s = lane & 15;
    int rlo = c * RC;
    float acc[8] = {};

    for (int base = e0; base < e1; base += 64) {
        int n = e1 - base; if (n > 64) n = 64;
        uint2 rec = {0u, 0u};
        if (lane < n) rec = sorted[base + lane];
        int iters = (n + 3) >> 2;
        #pragma unroll 4
        for (int j = 0; j < iters; j++) {
            int ej = j * 4 + g;
            int ec = (ej < n) ? ej : (n - 1);
            unsigned p  = (unsigned)__shfl((int)rec.x, ec, 64);
            unsigned nb = (unsigned)__shfl((int)rec.y, ec, 64);
            float nrm = (ej < n) ? u2f(nb) : 0.0f;
            int rel = (int)(p >> 16), src = (int)(p & 0xFFFFu);
            const unsigned short* zp = Z + (((size_t)(rel - rlo) * N_NODES + src) << 7) + s * 8;
            uint4 zv = *(const uint4*)zp;
            acc[0] += nrm * bf2f((unsigned short)(zv.x & 0xFFFFu));
            acc[1] += nrm * bf2f((unsigned short)(zv.x >> 16));
            acc[2] += nrm * bf2f((unsigned short)(zv.y & 0xFFFFu));
            acc[3] += nrm * bf2f((unsigned short)(zv.y >> 16));
            acc[4] += nrm * bf2f((unsigned short)(zv.z & 0xFFFFu));
            acc[5] += nrm * bf2f((unsigned short)(zv.z >> 16));
            acc[6] += nrm * bf2f((unsigned short)(zv.w & 0xFFFFu));
            acc[7] += nrm * bf2f((unsigned short)(zv.w >> 16));
        }
    }
    #pragma unroll
    for (int k = 0; k < 8; k++) {
        acc[k] += __shfl_down(acc[k], 16, 64);
        acc[k] += __shfl_down(acc[k], 32, 64);
    }
    if (g == 0) {
        float* hp = h + ((size_t)dst << 7) + s * 8;
        float4 h0 = *(float4*)hp, h1v = *(float4*)(hp + 4);
        h0.x += acc[0]; h0.y += acc[1]; h0.z += acc[2]; h0.w += acc[3];
        h1v.x += acc[4]; h1v.y += acc[5]; h1v.z += acc[6]; h1v.w += acc[7];
        *(float4*)hp = h0;
        *(float4*)(hp + 4) = h1v;
    }
}

// ---------------- scoring ----------------

__global__ __launch_bounds__(256) void score_kernel(const int* __restrict__ batch,
                                                    const float* __restrict__ h2,
                                                    const float* __restrict__ rels,
                                                    float* __restrict__ out) {
    int t = threadIdx.x;
    int wv = t >> 6, half = (t & 63) >> 5, sl = t & 31;
    int i = blockIdx.x * 8 + wv * 2 + half;
    int bs = batch[3*i], bp = batch[3*i+1], bo = batch[3*i+2];
    float4 s = *(const float4*)(h2   + (size_t)bs * D + sl * 4);
    float4 p = *(const float4*)(rels + (size_t)bp * D + sl * 4);
    float4 o = *(const float4*)(h2   + (size_t)bo * D + sl * 4);
    float v = s.x * p.x * o.x + s.y * p.y * o.y + s.z * p.z * o.z + s.w * p.w * o.w;
    #pragma unroll
    for (int off = 16; off > 0; off >>= 1) v += __shfl_down(v, off, 32);
    if (sl == 0) out[i] = v;
}

// ---------------- host ----------------

extern "C" void kernel_launch(void* const* d_in, const int* in_sizes, int n_in,
                              void* d_out, int out_size, void* d_ws, size_t ws_size,
                              hipStream_t stream) {
    const int*   graph = (const int*)  d_in[0];
    const int*   batch = (const int*)  d_in[1];
    const float* emb   = (const float*)d_in[2];
    const float* W1    = (const float*)d_in[3];
    const float* b1    = (const float*)d_in[4];
    const float* W2    = (const float*)d_in[5];
    const float* b2    = (const float*)d_in[6];
    const float* rels  = (const float*)d_in[7];
    float* out = (float*)d_out;

    char* base = (char*)d_ws;
    size_t off = 0;
    auto take = [&](size_t bytes) -> char* {
        char* q = base + off;
        off += (bytes + 255) & ~(size_t)255;
        return q;
    };
    int*            deg    = (int*)           take((size_t)R_AUG * N_NODES * 4);
    unsigned short* xb     = (unsigned short*)take((size_t)N_NODES * D * 2);
    float*          h1     = (float*)         take((size_t)N_NODES * D * 4);
    float*          h2     = (float*)         take((size_t)N_NODES * D * 4);
    unsigned short* h1b    = (unsigned short*)take((size_t)N_NODES * D * 2);
    unsigned short* W1t    = (unsigned short*)take((size_t)R_AUG * D * D * 2);
    unsigned short* W2t    = (unsigned short*)take((size_t)R_AUG * D * D * 2);
    int*            offs   = (int*)           take((size_t)(NBINS + 1) * 4);
    int*            cursor = (int*)           take((size_t)NBINS * 4);
    int*            part   = (int*)           take((size_t)NSB * 4);
    uint2*          sorted = (uint2*)         take((size_t)E_AUG * 8);
    unsigned short* Z      = (unsigned short*)take((size_t)RC * N_NODES * D * 2);  // 130.6 MB

    hipMemsetAsync(deg, 0, (size_t)R_AUG * N_NODES * 4, stream);
    prep_all<<<dim3(PREPX_BLOCKS + TW_BLOCKS + HIST_BLOCKS), 256, 0, stream>>>(
        emb, xb, h1, h2, b1, b2, W1, W2, W1t, W2t, graph, deg);
    scan_block<<<dim3(NSB), 256, 0, stream>>>(deg, offs, part);
    scan_partial<<<dim3(1), 256, 0, stream>>>(part);
    scan_add<<<dim3(NSB), 256, 0, stream>>>(offs, part, cursor);
    scatter_kernel<<<dim3((E_AUG + 255) / 256), 256, 0, stream>>>(graph, deg, cursor, sorted);

    for (int c = 0; c < NCHUNK; c++) {
        int r0 = c * RC;
        int rn = (R_AUG - r0 < RC) ? (R_AUG - r0) : RC;
        gemm_chunk<<<dim3(79, (rn + 1) / 2), 256, 0, stream>>>(xb, W1t, Z, r0, rn);
        agg_pass<<<dim3((N_NODES + 3) / 4), 256, 0, stream>>>(sorted, offs, Z, h1, c);
    }
    relu_conv<<<dim3((N_NODES * D) / 256), 256, 0, stream>>>(h1, h1b);
    for (int c = 0; c < NCHUNK; c++) {
        int r0 = c * RC;
        int rn = (R_AUG - r0 < RC) ? (R_AUG - r0) : RC;
        gemm_chunk<<<dim3(79, (rn + 1) / 2), 256, 0, stream>>>(h1b, W2t, Z, r0, rn);
        agg_pass<<<dim3((N_NODES + 3) / 4), 256, 0, stream>>>(sorted, offs, Z, h2, c);
    }
    score_kernel<<<dim3(N_BATCH / 8), 256, 0, stream>>>(batch, h2, rels, out);
}

// Round 9
// 395.312 us; speedup vs baseline: 1.8931x; 1.1685x over previous
//
#include <hip/hip_runtime.h>

#define N_NODES 10000
#define N_RELS  50
#define R_AUG   101
#define D       128
#define N_EDGES 320000
#define E_AUG   650000   /* 2*N_EDGES + N_NODES */
#define N_BATCH 65536

#define NBINS   N_NODES
#define NSB     ((NBINS + 255) / 256)        /* 40 dst-bin scan blocks */
#define NP      (R_AUG * N_NODES)            /* 1,010,000 (rel,src) pairs */
#define NSB2    ((NP + 255) / 256)           /* 3946 pair-scan blocks */
#define GEMM_NBLK (101 + (E_AUG + 127) / 128)/* 5180: worst-case compact blocks */

/* fused prep kernel block ranges */
#define PREPX_BLOCKS 5000                    /* N_NODES*D/256 */
#define TW_BLOCKS    808                     /* 2*2*(2*R_AUG) */
#define HIST_BLOCKS  2540                    /* ceil(E_AUG/256) */

typedef short bf16x8 __attribute__((ext_vector_type(8)));
typedef float f32x4  __attribute__((ext_vector_type(4)));

__device__ __forceinline__ unsigned short f2bf(float f) {
    union { float f; unsigned int u; } v; v.f = f;
    unsigned int r = (v.u + 0x7FFFu + ((v.u >> 16) & 1u)) >> 16;
    return (unsigned short)r;
}
__device__ __forceinline__ float bf2f(unsigned short h) {
    union { unsigned int u; float f; } v; v.u = ((unsigned int)h) << 16;
    return v.f;
}
__device__ __forceinline__ float u2f(unsigned int u) {
    union { unsigned int u; float f; } v; v.u = u; return v.f;
}
__device__ __forceinline__ unsigned int f2u(float f) {
    union { float f; unsigned int u; } v; v.f = f; return v.u;
}

__device__ __forceinline__ void decode_edge(const int* __restrict__ g, int e,
                                            int& src, int& rel, int& dst) {
    if (e < N_EDGES)            { src = g[3*e];     rel = g[3*e+1];          dst = g[3*e+2]; }
    else if (e < 2*N_EDGES)     { int b = e - N_EDGES;
                                  src = g[3*b+2];   rel = g[3*b+1] + N_RELS; dst = g[3*b];   }
    else                        { int n = e - 2*N_EDGES; src = n; dst = n; rel = 2*N_RELS;   }
}

// ---------------- fused prep: prep_x | transpose_w | deg_hist+flags ----------------

__global__ __launch_bounds__(256) void prep_all(const float* __restrict__ x,
                                                unsigned short* __restrict__ xb,
                                                float* __restrict__ h1, float* __restrict__ h2,
                                                const float* __restrict__ b1,
                                                const float* __restrict__ b2,
                                                const float* __restrict__ W1,
                                                const float* __restrict__ W2,
                                                unsigned short* __restrict__ W1t,
                                                unsigned short* __restrict__ W2t,
                                                const int* __restrict__ g,
                                                int* __restrict__ deg,
                                                int* __restrict__ flags) {
    __shared__ float tile[64][65];
    int b = blockIdx.x, t = threadIdx.x;
    if (b < PREPX_BLOCKS) {
        int i = b * 256 + t;
        xb[i] = f2bf(x[i]);
        int d = i & (D - 1);
        h1[i] = b1[d];
        h2[i] = b2[d];
    } else if (b < PREPX_BLOCKS + TW_BLOCKS) {
        int q = b - PREPX_BLOCKS;
        int d0 = (q & 1) * 64, o0 = ((q >> 1) & 1) * 64;
        int z = q >> 2;                                  /* 0..201 */
        const float* W = (z < R_AUG) ? W1 : W2;
        unsigned short* Wt = (z < R_AUG) ? W1t : W2t;
        int r = (z < R_AUG) ? z : (z - R_AUG);
        int tx = t & 63, ty = t >> 6;
        #pragma unroll
        for (int i = ty; i < 64; i += 4)
            tile[i][tx] = W[((size_t)r * D + (d0 + i)) * D + (o0 + tx)];
        __syncthreads();
        #pragma unroll
        for (int i = ty; i < 64; i += 4)
            Wt[((size_t)r * D + (o0 + i)) * D + (d0 + tx)] = f2bf(tile[tx][i]);
    } else {
        int e = (b - PREPX_BLOCKS - TW_BLOCKS) * 256 + t;
        if (e < E_AUG) {
            int src, rel, dst;
            decode_edge(g, e, src, rel, dst);
            atomicAdd(&deg[rel * N_NODES + dst], 1);
            flags[rel * N_NODES + src] = 1;      /* benign race: same value */
        }
    }
}

// ---- dst-bin exclusive scan (counts = sum of deg over all rels per dst) ----

__global__ __launch_bounds__(256) void scan_block(const int* __restrict__ deg,
                                                  int* __restrict__ offs,
                                                  int* __restrict__ partial) {
    __shared__ int wsum[4];
    int t = threadIdx.x, lane = t & 63, w = t >> 6;
    int i = blockIdx.x * 256 + t;
    int v = 0;
    if (i < NBINS) {
        for (int r = 0; r < R_AUG; r++) v += deg[r * N_NODES + i];
    }
    int incl = v;
    #pragma unroll
    for (int off = 1; off < 64; off <<= 1) {
        int u = __shfl_up(incl, off, 64);
        if (lane >= off) incl += u;
    }
    if (lane == 63) wsum[w] = incl;
    __syncthreads();
    int woff = 0;
    for (int k = 0; k < w; k++) woff += wsum[k];
    if (i < NBINS) offs[i] = woff + incl - v;
    if (t == 255) partial[blockIdx.x] = woff + incl;
}

__global__ __launch_bounds__(256) void scan_partial(int* __restrict__ partial) {
    __shared__ int wsum[4];
    int t = threadIdx.x, lane = t & 63, w = t >> 6;
    int v = (t < NSB) ? partial[t] : 0;
    int incl = v;
    #pragma unroll
    for (int off = 1; off < 64; off <<= 1) {
        int u = __shfl_up(incl, off, 64);
        if (lane >= off) incl += u;
    }
    if (lane == 63) wsum[w] = incl;
    __syncthreads();
    int woff = 0;
    for (int k = 0; k < w; k++) woff += wsum[k];
    if (t < NSB) partial[t] = woff + incl - v;
}

__global__ __launch_bounds__(256) void scan_add(int* __restrict__ offs,
                                                const int* __restrict__ partial,
                                                int* __restrict__ cursor) {
    int i = blockIdx.x * 256 + threadIdx.x;
    if (i < NBINS) {
        int v = offs[i] + partial[i >> 8];
        offs[i] = v;
        cursor[i] = v;
    }
    if (i == 0) offs[NBINS] = E_AUG;
}

// ---- pair-compaction scan over flags[NP] -> S (exclusive), pair_src ----

__global__ __launch_bounds__(256) void pscan1(const int* __restrict__ flags,
                                              int* __restrict__ S,
                                              int* __restrict__ ppart) {
    __shared__ int wsum[4];
    int t = threadIdx.x, lane = t & 63, w = t >> 6;
    int i = blockIdx.x * 256 + t;
    int v = (i < NP) ? flags[i] : 0;
    int incl = v;
    #pragma unroll
    for (int off = 1; off < 64; off <<= 1) {
        int u = __shfl_up(incl, off, 64);
        if (lane >= off) incl += u;
    }
    if (lane == 63) wsum[w] = incl;
    __syncthreads();
    int woff = 0;
    for (int k = 0; k < w; k++) woff += wsum[k];
    if (i < NP) S[i] = woff + incl - v;
    if (t == 255) ppart[blockIdx.x] = woff + incl;
}

// serial-carry scan over ppart[NSB2] (single block), writes total to S[NP]
__global__ __launch_bounds__(256) void pscan2(int* __restrict__ ppart,
                                              int* __restrict__ S) {
    __shared__ int wsum[4];
    int t = threadIdx.x, lane = t & 63, w = t >> 6;
    int carry = 0;
    for (int base = 0; base < NSB2; base += 256) {
        int i = base + t;
        int v = (i < NSB2) ? ppart[i] : 0;
        int incl = v;
        #pragma unroll
        for (int off = 1; off < 64; off <<= 1) {
            int u = __shfl_up(incl, off, 64);
            if (lane >= off) incl += u;
        }
        if (lane == 63) wsum[w] = incl;
        __syncthreads();
        int woff = 0;
        for (int k = 0; k < w; k++) woff += wsum[k];
        if (i < NSB2) ppart[i] = carry + woff + incl - v;
        carry += wsum[0] + wsum[1] + wsum[2] + wsum[3];
        __syncthreads();
    }
    if (t == 0) S[NP] = carry;
}

__global__ __launch_bounds__(256) void pscan3(const int* __restrict__ flags,
                                              int* __restrict__ S,
                                              const int* __restrict__ ppart,
                                              int* __restrict__ pair_src) {
    int i = blockIdx.x * 256 + threadIdx.x;
    if (i >= NP) return;
    int s = S[i] + ppart[i >> 8];
    S[i] = s;
    if (flags[i]) pair_src[s] = i % N_NODES;
}

// per-rel row base/count + block table for the fixed-grid compact GEMM
__global__ __launch_bounds__(256) void blk_kernel(const int* __restrict__ S,
                                                  int* __restrict__ rowbase,
                                                  int* __restrict__ rowcnt,
                                                  int* __restrict__ blkoffs) {
    __shared__ int wsum[4];
    int t = threadIdx.x, lane = t & 63, w = t >> 6;
    int nb = 0;
    if (t < R_AUG) {
        int base = S[t * N_NODES];
        int nxt  = S[(t + 1) * N_NODES];     /* t==100 -> S[NP] = total */
        rowbase[t] = base;
        rowcnt[t]  = nxt - base;
        nb = (nxt - base + 127) >> 7;
    }
    int incl = nb;
    #pragma unroll
    for (int off = 1; off < 64; off <<= 1) {
        int u = __shfl_up(incl, off, 64);
        if (lane >= off) incl += u;
    }
    if (lane == 63) wsum[w] = incl;
    __syncthreads();
    int woff = 0;
    for (int k = 0; k < w; k++) woff += wsum[k];
    if (t < R_AUG) blkoffs[t] = woff + incl - nb;
    if (t == R_AUG) blkoffs[R_AUG] = woff + incl;   /* t=101: total blocks */
}

// scatter edges into dst-sorted order; record = (compact z-row index, norm bits)
__global__ __launch_bounds__(256) void scatter_kernel(const int* __restrict__ g,
                                                      const int* __restrict__ deg,
                                                      const int* __restrict__ S,
                                                      int* __restrict__ cursor,
                                                      uint2* __restrict__ sorted) {
    int e = blockIdx.x * 256 + threadIdx.x;
    if (e >= E_AUG) return;
    int src, rel, dst;
    decode_edge(g, e, src, rel, dst);
    int pos = atomicAdd(&cursor[dst], 1);
    int dg = deg[rel * N_NODES + dst];          // >= 1 by construction
    uint2 rec;
    rec.x = (unsigned)S[rel * N_NODES + src];   // compact Z row
    rec.y = f2u(1.0f / (float)dg);
    sorted[pos] = rec;
}

__global__ __launch_bounds__(256) void relu_conv(const float* __restrict__ h,
                                                 unsigned short* __restrict__ hb) {
    int i = blockIdx.x * 256 + threadIdx.x;
    hb[i] = f2bf(fmaxf(h[i], 0.0f));
}

// ---------------- compact GEMM: Zc[row][o] = xb[pair_src[row]][:] @ W[rel(row)][:][o] ----------------
// Fixed grid GEMM_NBLK; block -> (rel, 128-row span) via binary search in blkoffs.
// 4 waves: wave w = (colhalf = w&1 -> cols colhalf*64..+64, tile parity w>>1).
// Per 16-row tile: 4 gathered A-loads feed 16 MFMAs (ratio 0.25) -> 2 packed 16B stores.
// W rows permuted at load so lane (lr,lq) holds cols no+lq*8+{0..7} of its row.

__global__ __launch_bounds__(256, 4) void gemm_compact(const unsigned short* __restrict__ xb,
                                                       const unsigned short* __restrict__ Wt,
                                                       const int* __restrict__ pair_src,
                                                       const int* __restrict__ rowbase,
                                                       const int* __restrict__ rowcnt,
                                                       const int* __restrict__ blkoffs,
                                                       unsigned short* __restrict__ Zc) {
    int b = blockIdx.x;
    if (b >= blkoffs[R_AUG]) return;
    int lo = 0, hi = R_AUG;
    while (hi - lo > 1) {
        int mid = (lo + hi) >> 1;
        if (blkoffs[mid] <= b) lo = mid; else hi = mid;
    }
    int r = lo;
    int lb = b - blkoffs[r];
    int rbase = rowbase[r] + lb * 128;
    int nrows = rowcnt[r] - lb * 128; if (nrows > 128) nrows = 128;

    int t = threadIdx.x, wave = t >> 6, lane = t & 63;
    int lr = lane & 15, lq = lane >> 4;
    int no = (wave & 1) * 64;
    int tp = wave >> 1;
    const unsigned short* Wr = Wt + (size_t)r * D * D;

    int prow = ((lr >> 2) << 3) + (lr & 3);
    bf16x8 w0[4], w1[4], w2[4], w3[4];
    #pragma unroll
    for (int ks = 0; ks < 4; ks++) {
        size_t kb = ks * 32 + lq * 8;
        w0[ks] = *(const bf16x8*)(Wr + (size_t)(no + prow) * D + kb);
        w1[ks] = *(const bf16x8*)(Wr + (size_t)(no + prow + 4) * D + kb);
        w2[ks] = *(const bf16x8*)(Wr + (size_t)(no + 32 + prow) * D + kb);
        w3[ks] = *(const bf16x8*)(Wr + (size_t)(no + 32 + prow + 4) * D + kb);
    }

    for (int tile = tp; tile * 16 < nrows; tile += 2) {
        int row = tile * 16 + lr;                       // local row in block span
        int rc = (row < nrows) ? row : 0;               // clamp for load
        int srcr = pair_src[rbase + rc];
        const unsigned short* xrow = xb + (size_t)srcr * D + lq * 8;
        bf16x8 a[4];
        #pragma unroll
        for (int ks = 0; ks < 4; ks++)
            a[ks] = *(const bf16x8*)(xrow + ks * 32);

        f32x4 c0 = {}, c1 = {}, c2 = {}, c3 = {};
        #pragma unroll
        for (int ks = 0; ks < 4; ks++) {
            c0 = __builtin_amdgcn_mfma_f32_16x16x32_bf16(w0[ks], a[ks], c0, 0, 0, 0);
            c1 = __builtin_amdgcn_mfma_f32_16x16x32_bf16(w1[ks], a[ks], c1, 0, 0, 0);
            c2 = __builtin_amdgcn_mfma_f32_16x16x32_bf16(w2[ks], a[ks], c2, 0, 0, 0);
            c3 = __builtin_amdgcn_mfma_f32_16x16x32_bf16(w3[ks], a[ks], c3, 0, 0, 0);
        }
        if (row < nrows) {
            unsigned short* zrow = Zc + ((size_t)(rbase + row) << 7);
            uint4 p0, p1;
            p0.x = (unsigned)f2bf(c0[0]) | ((unsigned)f2bf(c0[1]) << 16);
            p0.y = (unsigned)f2bf(c0[2]) | ((unsigned)f2bf(c0[3]) << 16);
            p0.z = (unsigned)f2bf(c1[0]) | ((unsigned)f2bf(c1[1]) << 16);
            p0.w = (unsigned)f2bf(c1[2]) | ((unsigned)f2bf(c1[3]) << 16);
            p1.x = (unsigned)f2bf(c2[0]) | ((unsigned)f2bf(c2[1]) << 16);
            p1.y = (unsigned)f2bf(c2[2]) | ((unsigned)f2bf(c2[3]) << 16);
            p1.z = (unsigned)f2bf(c3[0]) | ((unsigned)f2bf(c3[1]) << 16);
            p1.w = (unsigned)f2bf(c3[2]) | ((unsigned)f2bf(c3[3]) << 16);
            *(uint4*)(zrow + no + lq * 8) = p0;
            *(uint4*)(zrow + no + 32 + lq * 8) = p1;
        }
    }
}

// ---------------- aggregation: one wave per dst, compact Z rows, no atomics ----------------

__global__ __launch_bounds__(256) void agg_pass(const uint2* __restrict__ sorted,
                                                const int* __restrict__ offs,
                                                const unsigned short* __restrict__ Zc,
                                                float* __restrict__ h) {
    int w = threadIdx.x >> 6, lane = threadIdx.x & 63;
    int dst = blockIdx.x * 4 + w;
    if (dst >= N_NODES) return;
    int e0 = offs[dst], e1 = offs[dst + 1];
    if (e0 == e1) return;
    int g = lane >> 4, s = lane & 15;
    float acc[8] = {};

    for (int base = e0; base < e1; base += 64) {
        int n = e1 - base; if (n > 64) n = 64;
        uint2 rec = {0u, 0u};
        if (lane < n) rec = sorted[base + lane];
        int iters = (n + 3) >> 2;
        #pragma unroll 4
        for (int j = 0; j < iters; j++) {
            int ej = j * 4 + g;
            int ec = (ej < n) ? ej : (n - 1);
            unsigned zi = (unsigned)__shfl((int)rec.x, ec, 64);
            unsigned nb = (unsigned)__shfl((int)rec.y, ec, 64);
            float nrm = (ej < n) ? u2f(nb) : 0.0f;
            const unsigned short* zp = Zc + ((size_t)zi << 7) + s * 8;
            uint4 zv = *(const uint4*)zp;
            acc[0] += nrm * bf2f((unsigned short)(zv.x & 0xFFFFu));
            acc[1] += nrm * bf2f((unsigned short)(zv.x >> 16));
            acc[2] += nrm * bf2f((unsigned short)(zv.y & 0xFFFFu));
            acc[3] += nrm * bf2f((unsigned short)(zv.y >> 16));
            acc[4] += nrm * bf2f((unsigned short)(zv.z & 0xFFFFu));
            acc[5] += nrm * bf2f((unsigned short)(zv.z >> 16));
            acc[6] += nrm * bf2f((unsigned short)(zv.w & 0xFFFFu));
            acc[7] += nrm * bf2f((unsigned short)(zv.w >> 16));
        }
    }
    #pragma unroll
    for (int k = 0; k < 8; k++) {
        acc[k] += __shfl_down(acc[k], 16, 64);
        acc[k] += __shfl_down(acc[k], 32, 64);
    }
    if (g == 0) {
        float* hp = h + ((size_t)dst << 7) + s * 8;
        float4 h0 = *(float4*)hp, h1v = *(float4*)(hp + 4);
        h0.x += acc[0]; h0.y += acc[1]; h0.z += acc[2]; h0.w += acc[3];
        h1v.x += acc[4]; h1v.y += acc[5]; h1v.z += acc[6]; h1v.w += acc[7];
        *(float4*)hp = h0;
        *(float4*)(hp + 4) = h1v;
    }
}

// ---------------- scoring ----------------

__global__ __launch_bounds__(256) void score_kernel(const int* __restrict__ batch,
                                                    const float* __restrict__ h2,
                                                    const float* __restrict__ rels,
                                                    float* __restrict__ out) {
    int t = threadIdx.x;
    int wv = t >> 6, half = (t & 63) >> 5, sl = t & 31;
    int i = blockIdx.x * 8 + wv * 2 + half;
    int bs = batch[3*i], bp = batch[3*i+1], bo = batch[3*i+2];
    float4 s = *(const float4*)(h2   + (size_t)bs * D + sl * 4);
    float4 p = *(const float4*)(rels + (size_t)bp * D + sl * 4);
    float4 o = *(const float4*)(h2   + (size_t)bo * D + sl * 4);
    float v = s.x * p.x * o.x + s.y * p.y * o.y + s.z * p.z * o.z + s.w * p.w * o.w;
    #pragma unroll
    for (int off = 16; off > 0; off >>= 1) v += __shfl_down(v, off, 32);
    if (sl == 0) out[i] = v;
}

// ---------------- host ----------------

extern "C" void kernel_launch(void* const* d_in, const int* in_sizes, int n_in,
                              void* d_out, int out_size, void* d_ws, size_t ws_size,
                              hipStream_t stream) {
    const int*   graph = (const int*)  d_in[0];
    const int*   batch = (const int*)  d_in[1];
    const float* emb   = (const float*)d_in[2];
    const float* W1    = (const float*)d_in[3];
    const float* b1    = (const float*)d_in[4];
    const float* W2    = (const float*)d_in[5];
    const float* b2    = (const float*)d_in[6];
    const float* rels  = (const float*)d_in[7];
    float* out = (float*)d_out;

    char* base = (char*)d_ws;
    size_t off = 0;
    auto take = [&](size_t bytes) -> char* {
        char* q = base + off;
        off += (bytes + 255) & ~(size_t)255;
        return q;
    };
    int*            deg     = (int*)           take((size_t)NP * 4);
    int*            flags   = (int*)           take((size_t)NP * 4);
    int*            S       = (int*)           take((size_t)(NP + 1) * 4);
    int*            pair_src= (int*)           take((size_t)E_AUG * 4);
    int*            ppart   = (int*)           take((size_t)NSB2 * 4);
    int*            rowbase = (int*)           take((size_t)(R_AUG + 1) * 4);
    int*            rowcnt  = (int*)           take((size_t)(R_AUG + 1) * 4);
    int*            blkoffs = (int*)           take((size_t)(R_AUG + 2) * 4);
    unsigned short* xb      = (unsigned short*)take((size_t)N_NODES * D * 2);
    float*          h1      = (float*)         take((size_t)N_NODES * D * 4);
    float*          h2      = (float*)         take((size_t)N_NODES * D * 4);
    unsigned short* h1b     = (unsigned short*)take((size_t)N_NODES * D * 2);
    unsigned short* W1t     = (unsigned short*)take((size_t)R_AUG * D * D * 2);
    unsigned short* W2t     = (unsigned short*)take((size_t)R_AUG * D * D * 2);
    int*            offs    = (int*)           take((size_t)(NBINS + 1) * 4);
    int*            cursor  = (int*)           take((size_t)NBINS * 4);
    int*            part    = (int*)           take((size_t)NSB * 4);
    uint2*          sorted  = (uint2*)         take((size_t)E_AUG * 8);
    unsigned short* Zc      = (unsigned short*)take((size_t)E_AUG * D * 2);  // worst-case 166 MB

    hipMemsetAsync(deg, 0, (size_t)NP * 4, stream);
    hipMemsetAsync(flags, 0, (size_t)NP * 4, stream);
    prep_all<<<dim3(PREPX_BLOCKS + TW_BLOCKS + HIST_BLOCKS), 256, 0, stream>>>(
        emb, xb, h1, h2, b1, b2, W1, W2, W1t, W2t, graph, deg, flags);
    scan_block<<<dim3(NSB), 256, 0, stream>>>(deg, offs, part);
    scan_partial<<<dim3(1), 256, 0, stream>>>(part);
    scan_add<<<dim3(NSB), 256, 0, stream>>>(offs, part, cursor);
    pscan1<<<dim3(NSB2), 256, 0, stream>>>(flags, S, ppart);
    pscan2<<<dim3(1), 256, 0, stream>>>(ppart, S);
    pscan3<<<dim3(NSB2), 256, 0, stream>>>(flags, S, ppart, pair_src);
    blk_kernel<<<dim3(1), 256, 0, stream>>>(S, rowbase, rowcnt, blkoffs);
    scatter_kernel<<<dim3((E_AUG + 255) / 256), 256, 0, stream>>>(graph, deg, S, cursor, sorted);

    gemm_compact<<<dim3(GEMM_NBLK), 256, 0, stream>>>(xb, W1t, pair_src, rowbase, rowcnt, blkoffs, Zc);
    agg_pass<<<dim3((N_NODES + 3) / 4), 256, 0, stream>>>(sorted, offs, Zc, h1);
    relu_conv<<<dim3((N_NODES * D) / 256), 256, 0, stream>>>(h1, h1b);
    gemm_compact<<<dim3(GEMM_NBLK), 256, 0, stream>>>(h1b, W2t, pair_src, rowbase, rowcnt, blkoffs, Zc);
    agg_pass<<<dim3((N_NODES + 3) / 4), 256, 0, stream>>>(sorted, offs, Zc, h2);
    score_kernel<<<dim3(N_BATCH / 8), 256, 0, stream>>>(batch, h2, rels, out);
}

// Round 10
// 359.978 us; speedup vs baseline: 2.0789x; 1.0982x over previous
//
#include <hip/hip_runtime.h>

#define N_NODES 10000
#define N_RELS  50
#define R_AUG   101
#define D       128
#define N_EDGES 320000
#define E_AUG   650000   /* 2*N_EDGES + N_NODES */
#define N_BATCH 65536

#define NBINS   N_NODES
#define NSB     ((NBINS + 255) / 256)        /* 40 dst-bin scan blocks */
#define NP      (R_AUG * N_NODES)            /* 1,010,000 (rel,src) pairs */
#define NSB2    ((NP + 255) / 256)           /* 3946 pair-scan blocks */
#define BSPAN   256                          /* rows per gemm block */
#define GEMM_NBLK (101 + (E_AUG + BSPAN - 1) / BSPAN)  /* 2641 worst-case */

/* fused prep kernel block ranges */
#define PREPX_BLOCKS 5000                    /* N_NODES*D/256 */
#define TW_BLOCKS    808                     /* 2*2*(2*R_AUG) */
#define HIST_BLOCKS  2540                    /* ceil(E_AUG/256) */

typedef short bf16x8 __attribute__((ext_vector_type(8)));
typedef float f32x4  __attribute__((ext_vector_type(4)));

__device__ __forceinline__ unsigned short f2bf(float f) {
    union { float f; unsigned int u; } v; v.f = f;
    unsigned int r = (v.u + 0x7FFFu + ((v.u >> 16) & 1u)) >> 16;
    return (unsigned short)r;
}
__device__ __forceinline__ float bf2f(unsigned short h) {
    union { unsigned int u; float f; } v; v.u = ((unsigned int)h) << 16;
    return v.f;
}
__device__ __forceinline__ float u2f(unsigned int u) {
    union { unsigned int u; float f; } v; v.u = u; return v.f;
}
__device__ __forceinline__ unsigned int f2u(float f) {
    union { float f; unsigned int u; } v; v.f = f; return v.u;
}

__device__ __forceinline__ void decode_edge(const int* __restrict__ g, int e,
                                            int& src, int& rel, int& dst) {
    if (e < N_EDGES)            { src = g[3*e];     rel = g[3*e+1];          dst = g[3*e+2]; }
    else if (e < 2*N_EDGES)     { int b = e - N_EDGES;
                                  src = g[3*b+2];   rel = g[3*b+1] + N_RELS; dst = g[3*b];   }
    else                        { int n = e - 2*N_EDGES; src = n; dst = n; rel = 2*N_RELS;   }
}

// ---------------- fused prep: x->bf16 | transpose_w | deg_hist+flags ----------------

__global__ __launch_bounds__(256) void prep_all(const float* __restrict__ x,
                                                unsigned short* __restrict__ xb,
                                                const float* __restrict__ W1,
                                                const float* __restrict__ W2,
                                                unsigned short* __restrict__ W1t,
                                                unsigned short* __restrict__ W2t,
                                                const int* __restrict__ g,
                                                int* __restrict__ deg,
                                                int* __restrict__ flags) {
    __shared__ float tile[64][65];
    int b = blockIdx.x, t = threadIdx.x;
    if (b < PREPX_BLOCKS) {
        int i = b * 256 + t;
        xb[i] = f2bf(x[i]);
    } else if (b < PREPX_BLOCKS + TW_BLOCKS) {
        int q = b - PREPX_BLOCKS;
        int d0 = (q & 1) * 64, o0 = ((q >> 1) & 1) * 64;
        int z = q >> 2;                                  /* 0..201 */
        const float* W = (z < R_AUG) ? W1 : W2;
        unsigned short* Wt = (z < R_AUG) ? W1t : W2t;
        int r = (z < R_AUG) ? z : (z - R_AUG);
        int tx = t & 63, ty = t >> 6;
        #pragma unroll
        for (int i = ty; i < 64; i += 4)
            tile[i][tx] = W[((size_t)r * D + (d0 + i)) * D + (o0 + tx)];
        __syncthreads();
        #pragma unroll
        for (int i = ty; i < 64; i += 4)
            Wt[((size_t)r * D + (o0 + i)) * D + (d0 + tx)] = f2bf(tile[tx][i]);
    } else {
        int e = (b - PREPX_BLOCKS - TW_BLOCKS) * 256 + t;
        if (e < E_AUG) {
            int src, rel, dst;
            decode_edge(g, e, src, rel, dst);
            atomicAdd(&deg[rel * N_NODES + dst], 1);
            flags[rel * N_NODES + src] = 1;      /* benign race: same value */
        }
    }
}

// ---- scan stage A: dst-bin block scan | pair-flag block scan ----

__global__ __launch_bounds__(256) void scan_a(const int* __restrict__ deg,
                                              int* __restrict__ offs,
                                              int* __restrict__ part,
                                              const int* __restrict__ flags,
                                              int* __restrict__ S,
                                              int* __restrict__ ppart) {
    __shared__ int wsum[4];
    int t = threadIdx.x, lane = t & 63, w = t >> 6;
    int b = blockIdx.x;
    if (b < NSB) {
        int i = b * 256 + t;
        int v = 0;
        if (i < NBINS) {
            for (int r = 0; r < R_AUG; r++) v += deg[r * N_NODES + i];
        }
        int incl = v;
        #pragma unroll
        for (int off = 1; off < 64; off <<= 1) {
            int u = __shfl_up(incl, off, 64);
            if (lane >= off) incl += u;
        }
        if (lane == 63) wsum[w] = incl;
        __syncthreads();
        int woff = 0;
        for (int k = 0; k < w; k++) woff += wsum[k];
        if (i < NBINS) offs[i] = woff + incl - v;
        if (t == 255) part[b] = woff + incl;
    } else {
        int pb = b - NSB;
        int i = pb * 256 + t;
        int v = (i < NP) ? flags[i] : 0;
        int incl = v;
        #pragma unroll
        for (int off = 1; off < 64; off <<= 1) {
            int u = __shfl_up(incl, off, 64);
            if (lane >= off) incl += u;
        }
        if (lane == 63) wsum[w] = incl;
        __syncthreads();
        int woff = 0;
        for (int k = 0; k < w; k++) woff += wsum[k];
        if (i < NP) S[i] = woff + incl - v;
        if (t == 255) ppart[pb] = woff + incl;
    }
}

// ---- scan stage B: block 0 scans part[NSB]; block 1 serial-carry scans ppart[NSB2] ----

__global__ __launch_bounds__(256) void scan_b(int* __restrict__ part,
                                              int* __restrict__ ppart,
                                              int* __restrict__ S) {
    __shared__ int wsum[4];
    int t = threadIdx.x, lane = t & 63, w = t >> 6;
    if (blockIdx.x == 0) {
        int v = (t < NSB) ? part[t] : 0;
        int incl = v;
        #pragma unroll
        for (int off = 1; off < 64; off <<= 1) {
            int u = __shfl_up(incl, off, 64);
            if (lane >= off) incl += u;
        }
        if (lane == 63) wsum[w] = incl;
        __syncthreads();
        int woff = 0;
        for (int k = 0; k < w; k++) woff += wsum[k];
        if (t < NSB) part[t] = woff + incl - v;
    } else {
        int carry = 0;
        for (int base = 0; base < NSB2; base += 256) {
            int i = base + t;
            int v = (i < NSB2) ? ppart[i] : 0;
            int incl = v;
            #pragma unroll
            for (int off = 1; off < 64; off <<= 1) {
                int u = __shfl_up(incl, off, 64);
                if (lane >= off) incl += u;
            }
            if (lane == 63) wsum[w] = incl;
            __syncthreads();
            int woff = 0;
            for (int k = 0; k < w; k++) woff += wsum[k];
            if (i < NSB2) ppart[i] = carry + woff + incl - v;
            carry += wsum[0] + wsum[1] + wsum[2] + wsum[3];
            __syncthreads();
        }
        if (t == 0) S[NP] = carry;
    }
}

// ---- scan stage C: dst-bin add+cursor | pair add+compact ----

__global__ __launch_bounds__(256) void scan_c(int* __restrict__ offs,
                                              const int* __restrict__ part,
                                              int* __restrict__ cursor,
                                              const int* __restrict__ flags,
                                              int* __restrict__ S,
                                              const int* __restrict__ ppart,
                                              int* __restrict__ pair_src) {
    int b = blockIdx.x, t = threadIdx.x;
    if (b < NSB) {
        int i = b * 256 + t;
        if (i < NBINS) {
            int v = offs[i] + part[i >> 8];
            offs[i] = v;
            cursor[i] = v;
        }
        if (i == 0) offs[NBINS] = E_AUG;
    } else {
        int i = (b - NSB) * 256 + t;
        if (i >= NP) return;
        int s = S[i] + ppart[(b - NSB)];
        S[i] = s;
        if (flags[i]) pair_src[s] = i % N_NODES;
    }
}

// per-rel row base/count + block table for the fixed-grid compact GEMM
__global__ __launch_bounds__(256) void blk_kernel(const int* __restrict__ S,
                                                  int* __restrict__ rowbase,
                                                  int* __restrict__ rowcnt,
                                                  int* __restrict__ blkoffs) {
    __shared__ int wsum[4];
    int t = threadIdx.x, lane = t & 63, w = t >> 6;
    int nb = 0;
    if (t < R_AUG) {
        int base = S[t * N_NODES];
        int nxt  = S[(t + 1) * N_NODES];     /* t==100 -> S[NP] = total */
        rowbase[t] = base;
        rowcnt[t]  = nxt - base;
        nb = (nxt - base + BSPAN - 1) / BSPAN;
    }
    int incl = nb;
    #pragma unroll
    for (int off = 1; off < 64; off <<= 1) {
        int u = __shfl_up(incl, off, 64);
        if (lane >= off) incl += u;
    }
    if (lane == 63) wsum[w] = incl;
    __syncthreads();
    int woff = 0;
    for (int k = 0; k < w; k++) woff += wsum[k];
    if (t < R_AUG) blkoffs[t] = woff + incl - nb;
    if (t == R_AUG) blkoffs[R_AUG] = woff + incl;   /* total blocks */
}

// scatter edges into dst-sorted order; record = (compact z-row index, norm bits)
__global__ __launch_bounds__(256) void scatter_kernel(const int* __restrict__ g,
                                                      const int* __restrict__ deg,
                                                      const int* __restrict__ S,
                                                      int* __restrict__ cursor,
                                                      uint2* __restrict__ sorted) {
    int e = blockIdx.x * 256 + threadIdx.x;
    if (e >= E_AUG) return;
    int src, rel, dst;
    decode_edge(g, e, src, rel, dst);
    int pos = atomicAdd(&cursor[dst], 1);
    int dg = deg[rel * N_NODES + dst];          // >= 1 by construction
    uint2 rec;
    rec.x = (unsigned)S[rel * N_NODES + src];   // compact Z row
    rec.y = f2u(1.0f / (float)dg);
    sorted[pos] = rec;
}

// ---------------- compact GEMM: Zc[row][o] = xb[pair_src[row]][:] @ W[rel(row)][:][o] ----------------
// Fixed grid; block -> (rel, 256-row span) via binary search in blkoffs.
// Wave w: cols (w&1)*64..+64, tile parity w>>1 (8 tiles of 16 rows each).
// All 8 tile indices preloaded up-front (independent loads — no per-tile index
// chain); next tile's A prefetched before current MFMAs. 4 A-loads : 16 MFMA.
// W rows permuted at load so lane (lr,lq) holds cols no+lq*8+{0..7} of its row.

__global__ __launch_bounds__(256, 3) void gemm_compact(const unsigned short* __restrict__ xb,
                                                       const unsigned short* __restrict__ Wt,
                                                       const int* __restrict__ pair_src,
                                                       const int* __restrict__ rowbase,
                                                       const int* __restrict__ rowcnt,
                                                       const int* __restrict__ blkoffs,
                                                       unsigned short* __restrict__ Zc) {
    int b = blockIdx.x;
    if (b >= blkoffs[R_AUG]) return;
    int lo = 0, hi = R_AUG;
    while (hi - lo > 1) {
        int mid = (lo + hi) >> 1;
        if (blkoffs[mid] <= b) lo = mid; else hi = mid;
    }
    int r = lo;
    int lb = b - blkoffs[r];
    int rbase = rowbase[r] + lb * BSPAN;
    int nrows = rowcnt[r] - lb * BSPAN; if (nrows > BSPAN) nrows = BSPAN;

    int t = threadIdx.x, wave = t >> 6, lane = t & 63;
    int lr = lane & 15, lq = lane >> 4;
    int no = (wave & 1) * 64;
    int tp = wave >> 1;
    const unsigned short* Wr = Wt + (size_t)r * D * D;

    // preload all 8 tile indices (independent loads)
    int srcs[8];
    #pragma unroll
    for (int i = 0; i < 8; i++) {
        int row = (tp + 2 * i) * 16 + lr;
        srcs[i] = pair_src[rbase + (row < nrows ? row : 0)];
    }

    int prow = ((lr >> 2) << 3) + (lr & 3);
    bf16x8 w0[4], w1[4], w2[4], w3[4];
    #pragma unroll
    for (int ks = 0; ks < 4; ks++) {
        size_t kb = ks * 32 + lq * 8;
        w0[ks] = *(const bf16x8*)(Wr + (size_t)(no + prow) * D + kb);
        w1[ks] = *(const bf16x8*)(Wr + (size_t)(no + prow + 4) * D + kb);
        w2[ks] = *(const bf16x8*)(Wr + (size_t)(no + 32 + prow) * D + kb);
        w3[ks] = *(const bf16x8*)(Wr + (size_t)(no + 32 + prow + 4) * D + kb);
    }

    bf16x8 a[4];
    {
        const unsigned short* x0 = xb + (size_t)srcs[0] * D + lq * 8;
        #pragma unroll
        for (int ks = 0; ks < 4; ks++) a[ks] = *(const bf16x8*)(x0 + ks * 32);
    }

    #pragma unroll
    for (int i = 0; i < 8; i++) {
        int tile = tp + 2 * i;
        if (tile * 16 >= nrows) break;                  // wave-uniform

        bf16x8 an[4];                                   // prefetch next tile's A
        {
            int ni = (i < 7) ? i + 1 : 7;
            const unsigned short* xn = xb + (size_t)srcs[ni] * D + lq * 8;
            #pragma unroll
            for (int ks = 0; ks < 4; ks++) an[ks] = *(const bf16x8*)(xn + ks * 32);
        }

        f32x4 c0 = {}, c1 = {}, c2 = {}, c3 = {};
        #pragma unroll
        for (int ks = 0; ks < 4; ks++) {
            c0 = __builtin_amdgcn_mfma_f32_16x16x32_bf16(w0[ks], a[ks], c0, 0, 0, 0);
            c1 = __builtin_amdgcn_mfma_f32_16x16x32_bf16(w1[ks], a[ks], c1, 0, 0, 0);
            c2 = __builtin_amdgcn_mfma_f32_16x16x32_bf16(w2[ks], a[ks], c2, 0, 0, 0);
            c3 = __builtin_amdgcn_mfma_f32_16x16x32_bf16(w3[ks], a[ks], c3, 0, 0, 0);
        }
        int row = tile * 16 + lr;
        if (row < nrows) {
            unsigned short* zrow = Zc + ((size_t)(rbase + row) << 7);
            uint4 p0, p1;
            p0.x = (unsigned)f2bf(c0[0]) | ((unsigned)f2bf(c0[1]) << 16);
            p0.y = (unsigned)f2bf(c0[2]) | ((unsigned)f2bf(c0[3]) << 16);
            p0.z = (unsigned)f2bf(c1[0]) | ((unsigned)f2bf(c1[1]) << 16);
            p0.w = (unsigned)f2bf(c1[2]) | ((unsigned)f2bf(c1[3]) << 16);
            p1.x = (unsigned)f2bf(c2[0]) | ((unsigned)f2bf(c2[1]) << 16);
            p1.y = (unsigned)f2bf(c2[2]) | ((unsigned)f2bf(c2[3]) << 16);
            p1.z = (unsigned)f2bf(c3[0]) | ((unsigned)f2bf(c3[1]) << 16);
            p1.w = (unsigned)f2bf(c3[2]) | ((unsigned)f2bf(c3[3]) << 16);
            *(uint4*)(zrow + no + lq * 8) = p0;
            *(uint4*)(zrow + no + 32 + lq * 8) = p1;
        }
        #pragma unroll
        for (int ks = 0; ks < 4; ks++) a[ks] = an[ks];
    }
}

// ---------------- aggregation: one wave per dst, fused bias + (relu->bf16 | fp32) epilogue ----------------

__global__ __launch_bounds__(256) void agg_pass(const uint2* __restrict__ sorted,
                                                const int* __restrict__ offs,
                                                const unsigned short* __restrict__ Zc,
                                                const float* __restrict__ bias,
                                                float* __restrict__ hf,
                                                unsigned short* __restrict__ hb,
                                                int dorelu) {
    int w = threadIdx.x >> 6, lane = threadIdx.x & 63;
    int dst = blockIdx.x * 4 + w;
    if (dst >= N_NODES) return;
    int e0 = offs[dst], e1 = offs[dst + 1];
    int g = lane >> 4, s = lane & 15;
    float acc[8] = {};

    for (int base = e0; base < e1; base += 64) {
        int n = e1 - base; if (n > 64) n = 64;
        uint2 rec = {0u, 0u};
        if (lane < n) rec = sorted[base + lane];
        int iters = (n + 3) >> 2;
        #pragma unroll 4
        for (int j = 0; j < iters; j++) {
            int ej = j * 4 + g;
            int ec = (ej < n) ? ej : (n - 1);
            unsigned zi = (unsigned)__shfl((int)rec.x, ec, 64);
            unsigned nb = (unsigned)__shfl((int)rec.y, ec, 64);
            float nrm = (ej < n) ? u2f(nb) : 0.0f;
            const unsigned short* zp = Zc + ((size_t)zi << 7) + s * 8;
            uint4 zv = *(const uint4*)zp;
            acc[0] += nrm * bf2f((unsigned short)(zv.x & 0xFFFFu));
            acc[1] += nrm * bf2f((unsigned short)(zv.x >> 16));
            acc[2] += nrm * bf2f((unsigned short)(zv.y & 0xFFFFu));
            acc[3] += nrm * bf2f((unsigned short)(zv.y >> 16));
            acc[4] += nrm * bf2f((unsigned short)(zv.z & 0xFFFFu));
            acc[5] += nrm * bf2f((unsigned short)(zv.z >> 16));
            acc[6] += nrm * bf2f((unsigned short)(zv.w & 0xFFFFu));
            acc[7] += nrm * bf2f((unsigned short)(zv.w >> 16));
        }
    }
    #pragma unroll
    for (int k = 0; k < 8; k++) {
        acc[k] += __shfl_down(acc[k], 16, 64);
        acc[k] += __shfl_down(acc[k], 32, 64);
    }
    if (g == 0) {
        float4 b0 = *(const float4*)(bias + s * 8);
        float4 b1v = *(const float4*)(bias + s * 8 + 4);
        float v0 = b0.x + acc[0], v1 = b0.y + acc[1], v2 = b0.z + acc[2], v3 = b0.w + acc[3];
        float v4 = b1v.x + acc[4], v5 = b1v.y + acc[5], v6 = b1v.z + acc[6], v7 = b1v.w + acc[7];
        if (dorelu) {
            uint4 pk;
            pk.x = (unsigned)f2bf(fmaxf(v0, 0.0f)) | ((unsigned)f2bf(fmaxf(v1, 0.0f)) << 16);
            pk.y = (unsigned)f2bf(fmaxf(v2, 0.0f)) | ((unsigned)f2bf(fmaxf(v3, 0.0f)) << 16);
            pk.z = (unsigned)f2bf(fmaxf(v4, 0.0f)) | ((unsigned)f2bf(fmaxf(v5, 0.0f)) << 16);
            pk.w = (unsigned)f2bf(fmaxf(v6, 0.0f)) | ((unsigned)f2bf(fmaxf(v7, 0.0f)) << 16);
            *(uint4*)(hb + ((size_t)dst << 7) + s * 8) = pk;
        } else {
            float* hp = hf + ((size_t)dst << 7) + s * 8;
            float4 o0 = {v0, v1, v2, v3};
            float4 o1 = {v4, v5, v6, v7};
            *(float4*)hp = o0;
            *(float4*)(hp + 4) = o1;
        }
    }
}

// ---------------- scoring ----------------

__global__ __launch_bounds__(256) void score_kernel(const int* __restrict__ batch,
                                                    const float* __restrict__ h2,
                                                    const float* __restrict__ rels,
                                                    float* __restrict__ out) {
    int t = threadIdx.x;
    int wv = t >> 6, half = (t & 63) >> 5, sl = t & 31;
    int i = blockIdx.x * 8 + wv * 2 + half;
    int bs = batch[3*i], bp = batch[3*i+1], bo = batch[3*i+2];
    float4 s = *(const float4*)(h2   + (size_t)bs * D + sl * 4);
    float4 p = *(const float4*)(rels + (size_t)bp * D + sl * 4);
    float4 o = *(const float4*)(h2   + (size_t)bo * D + sl * 4);
    float v = s.x * p.x * o.x + s.y * p.y * o.y + s.z * p.z * o.z + s.w * p.w * o.w;
    #pragma unroll
    for (int off = 16; off > 0; off >>= 1) v += __shfl_down(v, off, 32);
    if (sl == 0) out[i] = v;
}

// ---------------- host ----------------

extern "C" void kernel_launch(void* const* d_in, const int* in_sizes, int n_in,
                              void* d_out, int out_size, void* d_ws, size_t ws_size,
                              hipStream_t stream) {
    const int*   graph = (const int*)  d_in[0];
    const int*   batch = (const int*)  d_in[1];
    const float* emb   = (const float*)d_in[2];
    const float* W1    = (const float*)d_in[3];
    const float* b1    = (const float*)d_in[4];
    const float* W2    = (const float*)d_in[5];
    const float* b2    = (const float*)d_in[6];
    const float* rels  = (const float*)d_in[7];
    float* out = (float*)d_out;

    char* base = (char*)d_ws;
    size_t off = 0;
    auto take = [&](size_t bytes) -> char* {
        char* q = base + off;
        off += (bytes + 255) & ~(size_t)255;
        return q;
    };
    int*            deg     = (int*)           take((size_t)NP * 4);
    int*            flags   = (int*)           take((size_t)NP * 4);
    int*            S       = (int*)           take((size_t)(NP + 1) * 4);
    int*            pair_src= (int*)           take((size_t)E_AUG * 4);
    int*            ppart   = (int*)           take((size_t)NSB2 * 4);
    int*            rowbase = (int*)           take((size_t)(R_AUG + 1) * 4);
    int*            rowcnt  = (int*)           take((size_t)(R_AUG + 1) * 4);
    int*            blkoffs = (int*)           take((size_t)(R_AUG + 2) * 4);
    unsigned short* xb      = (unsigned short*)take((size_t)N_NODES * D * 2);
    float*          h2      = (float*)         take((size_t)N_NODES * D * 4);
    unsigned short* h1b     = (unsigned short*)take((size_t)N_NODES * D * 2);
    unsigned short* W1t     = (unsigned short*)take((size_t)R_AUG * D * D * 2);
    unsigned short* W2t     = (unsigned short*)take((size_t)R_AUG * D * D * 2);
    int*            offs    = (int*)           take((size_t)(NBINS + 1) * 4);
    int*            cursor  = (int*)           take((size_t)NBINS * 4);
    int*            part    = (int*)           take((size_t)NSB * 4);
    uint2*          sorted  = (uint2*)         take((size_t)E_AUG * 8);
    unsigned short* Zc      = (unsigned short*)take((size_t)E_AUG * D * 2);  // worst-case 166 MB

    // deg and flags are adjacent: one memset covers both
    hipMemsetAsync(deg, 0, (size_t)((char*)S - (char*)deg), stream);
    prep_all<<<dim3(PREPX_BLOCKS + TW_BLOCKS + HIST_BLOCKS), 256, 0, stream>>>(
        emb, xb, W1, W2, W1t, W2t, graph, deg, flags);
    scan_a<<<dim3(NSB + NSB2), 256, 0, stream>>>(deg, offs, part, flags, S, ppart);
    scan_b<<<dim3(2), 256, 0, stream>>>(part, ppart, S);
    scan_c<<<dim3(NSB + NSB2), 256, 0, stream>>>(offs, part, cursor, flags, S, ppart, pair_src);
    blk_kernel<<<dim3(1), 256, 0, stream>>>(S, rowbase, rowcnt, blkoffs);
    scatter_kernel<<<dim3((E_AUG + 255) / 256), 256, 0, stream>>>(graph, deg, S, cursor, sorted);

    gemm_compact<<<dim3(GEMM_NBLK), 256, 0, stream>>>(xb, W1t, pair_src, rowbase, rowcnt, blkoffs, Zc);
    agg_pass<<<dim3((N_NODES + 3) / 4), 256, 0, stream>>>(sorted, offs, Zc, b1, (float*)0, h1b, 1);
    gemm_compact<<<dim3(GEMM_NBLK), 256, 0, stream>>>(h1b, W2t, pair_src, rowbase, rowcnt, blkoffs, Zc);
    agg_pass<<<dim3((N_NODES + 3) / 4), 256, 0, stream>>>(sorted, offs, Zc, b2, h2, (unsigned short*)0, 0);
    score_kernel<<<dim3(N_BATCH / 8), 256, 0, stream>>>(batch, h2, rels, out);
}

// Round 11
// 342.933 us; speedup vs baseline: 2.1822x; 1.0497x over previous
//
#include <hip/hip_runtime.h>

#define N_NODES 10000
#define N_RELS  50
#define R_AUG   101
#define D       128
#define N_EDGES 320000
#define E_AUG   650000   /* 2*N_EDGES + N_NODES */
#define N_BATCH 65536

#define NBINS   N_NODES
#define NSB     ((NBINS + 255) / 256)        /* 40 dst-bin scan blocks */
#define NP      (R_AUG * N_NODES)            /* 1,010,000 (rel,src) pairs */
#define NPB4    ((NP + 1023) / 1024)         /* 987 pair-scan blocks (4 elem/thread) */
#define BSPAN   256                          /* rows per gemm block */
#define GEMM_NBLK (101 + (E_AUG + BSPAN - 1) / BSPAN)  /* 2641 worst-case */
#define SCAT_BLOCKS ((E_AUG + 255) / 256)    /* 2540 */

/* fused prep kernel block ranges */
#define PREPX_BLOCKS 5000                    /* N_NODES*D/256 */
#define TW_BLOCKS    808                     /* 2*2*(2*R_AUG) */
#define HIST_BLOCKS  2540                    /* ceil(E_AUG/256) */

typedef short bf16x8 __attribute__((ext_vector_type(8)));
typedef float f32x4  __attribute__((ext_vector_type(4)));

__device__ __forceinline__ unsigned short f2bf(float f) {
    union { float f; unsigned int u; } v; v.f = f;
    unsigned int r = (v.u + 0x7FFFu + ((v.u >> 16) & 1u)) >> 16;
    return (unsigned short)r;
}
__device__ __forceinline__ float bf2f(unsigned short h) {
    union { unsigned int u; float f; } v; v.u = ((unsigned int)h) << 16;
    return v.f;
}
__device__ __forceinline__ float u2f(unsigned int u) {
    union { unsigned int u; float f; } v; v.u = u; return v.f;
}
__device__ __forceinline__ unsigned int f2u(float f) {
    union { float f; unsigned int u; } v; v.f = f; return v.u;
}

__device__ __forceinline__ void decode_edge(const int* __restrict__ g, int e,
                                            int& src, int& rel, int& dst) {
    if (e < N_EDGES)            { src = g[3*e];     rel = g[3*e+1];          dst = g[3*e+2]; }
    else if (e < 2*N_EDGES)     { int b = e - N_EDGES;
                                  src = g[3*b+2];   rel = g[3*b+1] + N_RELS; dst = g[3*b];   }
    else                        { int n = e - 2*N_EDGES; src = n; dst = n; rel = 2*N_RELS;   }
}

// ---------------- fused prep: x->bf16 | transpose_w | deg_hist+flags ----------------

__global__ __launch_bounds__(256) void prep_all(const float* __restrict__ x,
                                                unsigned short* __restrict__ xb,
                                                const float* __restrict__ W1,
                                                const float* __restrict__ W2,
                                                unsigned short* __restrict__ W1t,
                                                unsigned short* __restrict__ W2t,
                                                const int* __restrict__ g,
                                                int* __restrict__ deg,
                                                int* __restrict__ flags) {
    __shared__ float tile[64][65];
    int b = blockIdx.x, t = threadIdx.x;
    if (b < PREPX_BLOCKS) {
        int i = b * 256 + t;
        xb[i] = f2bf(x[i]);
    } else if (b < PREPX_BLOCKS + TW_BLOCKS) {
        int q = b - PREPX_BLOCKS;
        int d0 = (q & 1) * 64, o0 = ((q >> 1) & 1) * 64;
        int z = q >> 2;                                  /* 0..201 */
        const float* W = (z < R_AUG) ? W1 : W2;
        unsigned short* Wt = (z < R_AUG) ? W1t : W2t;
        int r = (z < R_AUG) ? z : (z - R_AUG);
        int tx = t & 63, ty = t >> 6;
        #pragma unroll
        for (int i = ty; i < 64; i += 4)
            tile[i][tx] = W[((size_t)r * D + (d0 + i)) * D + (o0 + tx)];
        __syncthreads();
        #pragma unroll
        for (int i = ty; i < 64; i += 4)
            Wt[((size_t)r * D + (o0 + i)) * D + (d0 + tx)] = f2bf(tile[tx][i]);
    } else {
        int e = (b - PREPX_BLOCKS - TW_BLOCKS) * 256 + t;
        if (e < E_AUG) {
            int src, rel, dst;
            decode_edge(g, e, src, rel, dst);
            atomicAdd(&deg[rel * N_NODES + dst], 1);
            flags[rel * N_NODES + src] = 1;      /* benign race: same value */
        }
    }
}

// ---- scan stage A: dst-bin block scan | pair-flag block scan (4 elem/thread) ----

__global__ __launch_bounds__(256) void scan_a(const int* __restrict__ deg,
                                              int* __restrict__ offs,
                                              int* __restrict__ part,
                                              const int* __restrict__ flags,
                                              int* __restrict__ S,
                                              int* __restrict__ ppart) {
    __shared__ int wsum[4];
    int t = threadIdx.x, lane = t & 63, w = t >> 6;
    int b = blockIdx.x;
    if (b < NSB) {
        int i = b * 256 + t;
        int v = 0;
        if (i < NBINS) {
            for (int r = 0; r < R_AUG; r++) v += deg[r * N_NODES + i];
        }
        int incl = v;
        #pragma unroll
        for (int off = 1; off < 64; off <<= 1) {
            int u = __shfl_up(incl, off, 64);
            if (lane >= off) incl += u;
        }
        if (lane == 63) wsum[w] = incl;
        __syncthreads();
        int woff = 0;
        for (int k = 0; k < w; k++) woff += wsum[k];
        if (i < NBINS) offs[i] = woff + incl - v;
        if (t == 255) part[b] = woff + incl;
    } else {
        int pb = b - NSB;
        int i0 = pb * 1024 + t * 4;
        int4 f = {0, 0, 0, 0};
        if (i0 + 3 < NP) {
            f = *(const int4*)(flags + i0);
        } else if (i0 < NP) {
            f.x = flags[i0];
            if (i0 + 1 < NP) f.y = flags[i0 + 1];
            if (i0 + 2 < NP) f.z = flags[i0 + 2];
        }
        int e1 = f.x, e2 = f.x + f.y, e3 = e2 + f.z, v = e3 + f.w;
        int incl = v;
        #pragma unroll
        for (int off = 1; off < 64; off <<= 1) {
            int u = __shfl_up(incl, off, 64);
            if (lane >= off) incl += u;
        }
        if (lane == 63) wsum[w] = incl;
        __syncthreads();
        int woff = 0;
        for (int k = 0; k < w; k++) woff += wsum[k];
        int texcl = woff + incl - v;
        if (i0 + 3 < NP) {
            int4 o = {texcl, texcl + e1, texcl + e2, texcl + e3};
            *(int4*)(S + i0) = o;
        } else if (i0 < NP) {
            S[i0] = texcl;
            if (i0 + 1 < NP) S[i0 + 1] = texcl + e1;
            if (i0 + 2 < NP) S[i0 + 2] = texcl + e2;
        }
        if (t == 255) ppart[pb] = woff + incl;
    }
}

// ---- scan stage B: block 0 scans part[NSB]; block 1 serial-carry scans ppart[NPB4] ----

__global__ __launch_bounds__(256) void scan_b(int* __restrict__ part,
                                              int* __restrict__ ppart,
                                              int* __restrict__ S) {
    __shared__ int wsum[4];
    int t = threadIdx.x, lane = t & 63, w = t >> 6;
    if (blockIdx.x == 0) {
        int v = (t < NSB) ? part[t] : 0;
        int incl = v;
        #pragma unroll
        for (int off = 1; off < 64; off <<= 1) {
            int u = __shfl_up(incl, off, 64);
            if (lane >= off) incl += u;
        }
        if (lane == 63) wsum[w] = incl;
        __syncthreads();
        int woff = 0;
        for (int k = 0; k < w; k++) woff += wsum[k];
        if (t < NSB) part[t] = woff + incl - v;
    } else {
        int carry = 0;
        for (int base = 0; base < NPB4; base += 256) {
            int i = base + t;
            int v = (i < NPB4) ? ppart[i] : 0;
            int incl = v;
            #pragma unroll
            for (int off = 1; off < 64; off <<= 1) {
                int u = __shfl_up(incl, off, 64);
                if (lane >= off) incl += u;
            }
            if (lane == 63) wsum[w] = incl;
            __syncthreads();
            int woff = 0;
            for (int k = 0; k < w; k++) woff += wsum[k];
            if (i < NPB4) ppart[i] = carry + woff + incl - v;
            carry += wsum[0] + wsum[1] + wsum[2] + wsum[3];
            __syncthreads();
        }
        if (t == 0) S[NP] = carry;
    }
}

// ---- scan stage C: dst-bin add+cursor | pair add+compact (4 elem/thread) ----

__global__ __launch_bounds__(256) void scan_c(int* __restrict__ offs,
                                              const int* __restrict__ part,
                                              int* __restrict__ cursor,
                                              const int* __restrict__ flags,
                                              int* __restrict__ S,
                                              const int* __restrict__ ppart,
                                              int* __restrict__ pair_src) {
    int b = blockIdx.x, t = threadIdx.x;
    if (b < NSB) {
        int i = b * 256 + t;
        if (i < NBINS) {
            int v = offs[i] + part[i >> 8];
            offs[i] = v;
            cursor[i] = v;
        }
        if (i == 0) offs[NBINS] = E_AUG;
    } else {
        int pb = b - NSB;
        int i0 = pb * 1024 + t * 4;
        if (i0 >= NP) return;
        int pp = ppart[pb];
        if (i0 + 3 < NP) {
            int4 sv = *(int4*)(S + i0);
            sv.x += pp; sv.y += pp; sv.z += pp; sv.w += pp;
            *(int4*)(S + i0) = sv;
            int4 f = *(const int4*)(flags + i0);
            if (f.x) pair_src[sv.x] = i0 % N_NODES;
            if (f.y) pair_src[sv.y] = (i0 + 1) % N_NODES;
            if (f.z) pair_src[sv.z] = (i0 + 2) % N_NODES;
            if (f.w) pair_src[sv.w] = (i0 + 3) % N_NODES;
        } else {
            for (int k = 0; k < 4; k++) {
                int i = i0 + k;
                if (i >= NP) break;
                int s = S[i] + pp;
                S[i] = s;
                if (flags[i]) pair_src[s] = i % N_NODES;
            }
        }
    }
}

// per-rel row base/count + block table for the fixed-grid compact GEMM
__global__ __launch_bounds__(256) void blk_kernel(const int* __restrict__ S,
                                                  int* __restrict__ rowbase,
                                                  int* __restrict__ rowcnt,
                                                  int* __restrict__ blkoffs) {
    __shared__ int wsum[4];
    int t = threadIdx.x, lane = t & 63, w = t >> 6;
    int nb = 0;
    if (t < R_AUG) {
        int base = S[t * N_NODES];
        int nxt  = S[(t + 1) * N_NODES];     /* t==100 -> S[NP] = total */
        rowbase[t] = base;
        rowcnt[t]  = nxt - base;
        nb = (nxt - base + BSPAN - 1) / BSPAN;
    }
    int incl = nb;
    #pragma unroll
    for (int off = 1; off < 64; off <<= 1) {
        int u = __shfl_up(incl, off, 64);
        if (lane >= off) incl += u;
    }
    if (lane == 63) wsum[w] = incl;
    __syncthreads();
    int woff = 0;
    for (int k = 0; k < w; k++) woff += wsum[k];
    if (t < R_AUG) blkoffs[t] = woff + incl - nb;
    if (t == R_AUG) blkoffs[R_AUG] = woff + incl;   /* total blocks */
}

// ---------------- fused [edge scatter | compact GEMM] ----------------
// First scatBlocks blocks: scatter edges into dst-sorted order
//   record = (compact z-row index, norm bits). Latency-bound atomics — hide
//   under the write-bound gemm blocks that follow in the same grid.
// Remaining blocks: Zc[row][o] = xb[pair_src[row]][:] @ W[rel(row)][:][o].
//   block -> (rel, 256-row span) via binary search in blkoffs; wave w: cols
//   (w&1)*64..+64, tile parity w>>1. 8 tile indices preloaded; next-tile A
//   prefetch; 4 A-loads : 16 MFMA; permuted-W 16B stores.

__global__ __launch_bounds__(256, 3) void gemm_fused(const unsigned short* __restrict__ xb,
                                                     const unsigned short* __restrict__ Wt,
                                                     const int* __restrict__ pair_src,
                                                     const int* __restrict__ rowbase,
                                                     const int* __restrict__ rowcnt,
                                                     const int* __restrict__ blkoffs,
                                                     unsigned short* __restrict__ Zc,
                                                     const int* __restrict__ g,
                                                     const int* __restrict__ deg,
                                                     const int* __restrict__ S,
                                                     int* __restrict__ cursor,
                                                     uint2* __restrict__ sorted,
                                                     int scatBlocks) {
    int b = blockIdx.x;
    int t = threadIdx.x;
    if (b < scatBlocks) {
        int e = b * 256 + t;
        if (e < E_AUG) {
            int src, rel, dst;
            decode_edge(g, e, src, rel, dst);
            int pos = atomicAdd(&cursor[dst], 1);
            int dg = deg[rel * N_NODES + dst];      // >= 1 by construction
            uint2 rec;
            rec.x = (unsigned)S[rel * N_NODES + src];
            rec.y = f2u(1.0f / (float)dg);
            sorted[pos] = rec;
        }
        return;
    }
    b -= scatBlocks;
    if (b >= blkoffs[R_AUG]) return;
    int lo = 0, hi = R_AUG;
    while (hi - lo > 1) {
        int mid = (lo + hi) >> 1;
        if (blkoffs[mid] <= b) lo = mid; else hi = mid;
    }
    int r = lo;
    int lb = b - blkoffs[r];
    int rbase = rowbase[r] + lb * BSPAN;
    int nrows = rowcnt[r] - lb * BSPAN; if (nrows > BSPAN) nrows = BSPAN;

    int wave = t >> 6, lane = t & 63;
    int lr = lane & 15, lq = lane >> 4;
    int no = (wave & 1) * 64;
    int tp = wave >> 1;
    const unsigned short* Wr = Wt + (size_t)r * D * D;

    // preload all 8 tile indices (independent loads)
    int srcs[8];
    #pragma unroll
    for (int i = 0; i < 8; i++) {
        int row = (tp + 2 * i) * 16 + lr;
        srcs[i] = pair_src[rbase + (row < nrows ? row : 0)];
    }

    int prow = ((lr >> 2) << 3) + (lr & 3);
    bf16x8 w0[4], w1[4], w2[4], w3[4];
    #pragma unroll
    for (int ks = 0; ks < 4; ks++) {
        size_t kb = ks * 32 + lq * 8;
        w0[ks] = *(const bf16x8*)(Wr + (size_t)(no + prow) * D + kb);
        w1[ks] = *(const bf16x8*)(Wr + (size_t)(no + prow + 4) * D + kb);
        w2[ks] = *(const bf16x8*)(Wr + (size_t)(no + 32 + prow) * D + kb);
        w3[ks] = *(const bf16x8*)(Wr + (size_t)(no + 32 + prow + 4) * D + kb);
    }

    bf16x8 a[4];
    {
        const unsigned short* x0 = xb + (size_t)srcs[0] * D + lq * 8;
        #pragma unroll
        for (int ks = 0; ks < 4; ks++) a[ks] = *(const bf16x8*)(x0 + ks * 32);
    }

    #pragma unroll
    for (int i = 0; i < 8; i++) {
        int tile = tp + 2 * i;
        if (tile * 16 >= nrows) break;                  // wave-uniform

        bf16x8 an[4];                                   // prefetch next tile's A
        {
            int ni = (i < 7) ? i + 1 : 7;
            const unsigned short* xn = xb + (size_t)srcs[ni] * D + lq * 8;
            #pragma unroll
            for (int ks = 0; ks < 4; ks++) an[ks] = *(const bf16x8*)(xn + ks * 32);
        }

        f32x4 c0 = {}, c1 = {}, c2 = {}, c3 = {};
        #pragma unroll
        for (int ks = 0; ks < 4; ks++) {
            c0 = __builtin_amdgcn_mfma_f32_16x16x32_bf16(w0[ks], a[ks], c0, 0, 0, 0);
            c1 = __builtin_amdgcn_mfma_f32_16x16x32_bf16(w1[ks], a[ks], c1, 0, 0, 0);
            c2 = __builtin_amdgcn_mfma_f32_16x16x32_bf16(w2[ks], a[ks], c2, 0, 0, 0);
            c3 = __builtin_amdgcn_mfma_f32_16x16x32_bf16(w3[ks], a[ks], c3, 0, 0, 0);
        }
        int row = tile * 16 + lr;
        if (row < nrows) {
            unsigned short* zrow = Zc + ((size_t)(rbase + row) << 7);
            uint4 p0, p1;
            p0.x = (unsigned)f2bf(c0[0]) | ((unsigned)f2bf(c0[1]) << 16);
            p0.y = (unsigned)f2bf(c0[2]) | ((unsigned)f2bf(c0[3]) << 16);
            p0.z = (unsigned)f2bf(c1[0]) | ((unsigned)f2bf(c1[1]) << 16);
            p0.w = (unsigned)f2bf(c1[2]) | ((unsigned)f2bf(c1[3]) << 16);
            p1.x = (unsigned)f2bf(c2[0]) | ((unsigned)f2bf(c2[1]) << 16);
            p1.y = (unsigned)f2bf(c2[2]) | ((unsigned)f2bf(c2[3]) << 16);
            p1.z = (unsigned)f2bf(c3[0]) | ((unsigned)f2bf(c3[1]) << 16);
            p1.w = (unsigned)f2bf(c3[2]) | ((unsigned)f2bf(c3[3]) << 16);
            *(uint4*)(zrow + no + lq * 8) = p0;
            *(uint4*)(zrow + no + 32 + lq * 8) = p1;
        }
        #pragma unroll
        for (int ks = 0; ks < 4; ks++) a[ks] = an[ks];
    }
}

// ---------------- aggregation: one wave per dst, 8 edges in flight ----------------
// lane = 8 edge-slots (g=lane>>3) x 8 dim-groups (s=lane&7, 16 dims = 32B/lane).
// Fused bias + (relu->bf16 | fp32) epilogue.

__global__ __launch_bounds__(256) void agg_pass(const uint2* __restrict__ sorted,
                                                const int* __restrict__ offs,
                                                const unsigned short* __restrict__ Zc,
                                                const float* __restrict__ bias,
                                                float* __restrict__ hf,
                                                unsigned short* __restrict__ hb,
                                                int dorelu) {
    int w = threadIdx.x >> 6, lane = threadIdx.x & 63;
    int dst = blockIdx.x * 4 + w;
    if (dst >= N_NODES) return;
    int e0 = offs[dst], e1 = offs[dst + 1];
    int g = lane >> 3, s = lane & 7;
    float acc[16] = {};

    for (int base = e0; base < e1; base += 64) {
        int n = e1 - base; if (n > 64) n = 64;
        uint2 rec = {0u, 0u};
        if (lane < n) rec = sorted[base + lane];
        int iters = (n + 7) >> 3;
        #pragma unroll 2
        for (int j = 0; j < iters; j++) {
            int ej = j * 8 + g;
            int ec = (ej < n) ? ej : (n - 1);
            unsigned zi = (unsigned)__shfl((int)rec.x, ec, 64);
            unsigned nb = (unsigned)__shfl((int)rec.y, ec, 64);
            float nrm = (ej < n) ? u2f(nb) : 0.0f;
            const unsigned short* zp = Zc + ((size_t)zi << 7) + s * 16;
            uint4 z0 = *(const uint4*)zp;
            uint4 z1 = *(const uint4*)(zp + 8);
            acc[0]  += nrm * bf2f((unsigned short)(z0.x & 0xFFFFu));
            acc[1]  += nrm * bf2f((unsigned short)(z0.x >> 16));
            acc[2]  += nrm * bf2f((unsigned short)(z0.y & 0xFFFFu));
            acc[3]  += nrm * bf2f((unsigned short)(z0.y >> 16));
            acc[4]  += nrm * bf2f((unsigned short)(z0.z & 0xFFFFu));
            acc[5]  += nrm * bf2f((unsigned short)(z0.z >> 16));
            acc[6]  += nrm * bf2f((unsigned short)(z0.w & 0xFFFFu));
            acc[7]  += nrm * bf2f((unsigned short)(z0.w >> 16));
            acc[8]  += nrm * bf2f((unsigned short)(z1.x & 0xFFFFu));
            acc[9]  += nrm * bf2f((unsigned short)(z1.x >> 16));
            acc[10] += nrm * bf2f((unsigned short)(z1.y & 0xFFFFu));
            acc[11] += nrm * bf2f((unsigned short)(z1.y >> 16));
            acc[12] += nrm * bf2f((unsigned short)(z1.z & 0xFFFFu));
            acc[13] += nrm * bf2f((unsigned short)(z1.z >> 16));
            acc[14] += nrm * bf2f((unsigned short)(z1.w & 0xFFFFu));
            acc[15] += nrm * bf2f((unsigned short)(z1.w >> 16));
        }
    }
    #pragma unroll
    for (int k = 0; k < 16; k++) {
        acc[k] += __shfl_down(acc[k], 8, 64);
        acc[k] += __shfl_down(acc[k], 16, 64);
        acc[k] += __shfl_down(acc[k], 32, 64);
    }
    if (g == 0) {
        const float* bp = bias + s * 16;
        float vv[16];
        #pragma unroll
        for (int k = 0; k < 16; k++) vv[k] = bp[k] + acc[k];
        if (dorelu) {
            unsigned short* hp = hb + ((size_t)dst << 7) + s * 16;
            uint4 p0, p1;
            p0.x = (unsigned)f2bf(fmaxf(vv[0], 0.0f))  | ((unsigned)f2bf(fmaxf(vv[1], 0.0f))  << 16);
            p0.y = (unsigned)f2bf(fmaxf(vv[2], 0.0f))  | ((unsigned)f2bf(fmaxf(vv[3], 0.0f))  << 16);
            p0.z = (unsigned)f2bf(fmaxf(vv[4], 0.0f))  | ((unsigned)f2bf(fmaxf(vv[5], 0.0f))  << 16);
            p0.w = (unsigned)f2bf(fmaxf(vv[6], 0.0f))  | ((unsigned)f2bf(fmaxf(vv[7], 0.0f))  << 16);
            p1.x = (unsigned)f2bf(fmaxf(vv[8], 0.0f))  | ((unsigned)f2bf(fmaxf(vv[9], 0.0f))  << 16);
            p1.y = (unsigned)f2bf(fmaxf(vv[10], 0.0f)) | ((unsigned)f2bf(fmaxf(vv[11], 0.0f)) << 16);
            p1.z = (unsigned)f2bf(fmaxf(vv[12], 0.0f)) | ((unsigned)f2bf(fmaxf(vv[13], 0.0f)) << 16);
            p1.w = (unsigned)f2bf(fmaxf(vv[14], 0.0f)) | ((unsigned)f2bf(fmaxf(vv[15], 0.0f)) << 16);
            *(uint4*)hp = p0;
            *(uint4*)(hp + 8) = p1;
        } else {
            float* hp = hf + ((size_t)dst << 7) + s * 16;
            #pragma unroll
            for (int q = 0; q < 4; q++) {
                float4 o = {vv[q * 4], vv[q * 4 + 1], vv[q * 4 + 2], vv[q * 4 + 3]};
                *(float4*)(hp + q * 4) = o;
            }
        }
    }
}

// ---------------- scoring ----------------

__global__ __launch_bounds__(256) void score_kernel(const int* __restrict__ batch,
                                                    const float* __restrict__ h2,
                                                    const float* __restrict__ rels,
                                                    float* __restrict__ out) {
    int t = threadIdx.x;
    int wv = t >> 6, half = (t & 63) >> 5, sl = t & 31;
    int i = blockIdx.x * 8 + wv * 2 + half;
    int bs = batch[3*i], bp = batch[3*i+1], bo = batch[3*i+2];
    float4 s = *(const float4*)(h2   + (size_t)bs * D + sl * 4);
    float4 p = *(const float4*)(rels + (size_t)bp * D + sl * 4);
    float4 o = *(const float4*)(h2   + (size_t)bo * D + sl * 4);
    float v = s.x * p.x * o.x + s.y * p.y * o.y + s.z * p.z * o.z + s.w * p.w * o.w;
    #pragma unroll
    for (int off = 16; off > 0; off >>= 1) v += __shfl_down(v, off, 32);
    if (sl == 0) out[i] = v;
}

// ---------------- host ----------------

extern "C" void kernel_launch(void* const* d_in, const int* in_sizes, int n_in,
                              void* d_out, int out_size, void* d_ws, size_t ws_size,
                              hipStream_t stream) {
    const int*   graph = (const int*)  d_in[0];
    const int*   batch = (const int*)  d_in[1];
    const float* emb   = (const float*)d_in[2];
    const float* W1    = (const float*)d_in[3];
    const float* b1    = (const float*)d_in[4];
    const float* W2    = (const float*)d_in[5];
    const float* b2    = (const float*)d_in[6];
    const float* rels  = (const float*)d_in[7];
    float* out = (float*)d_out;

    char* base = (char*)d_ws;
    size_t off = 0;
    auto take = [&](size_t bytes) -> char* {
        char* q = base + off;
        off += (bytes + 255) & ~(size_t)255;
        return q;
    };
    int*            deg     = (int*)           take((size_t)NP * 4);
    int*            flags   = (int*)           take((size_t)NP * 4);
    int*            S       = (int*)           take((size_t)(NP + 1) * 4);
    int*            pair_src= (int*)           take((size_t)E_AUG * 4);
    int*            ppart   = (int*)           take((size_t)NPB4 * 4);
    int*            rowbase = (int*)           take((size_t)(R_AUG + 1) * 4);
    int*            rowcnt  = (int*)           take((size_t)(R_AUG + 1) * 4);
    int*            blkoffs = (int*)           take((size_t)(R_AUG + 2) * 4);
    unsigned short* xb      = (unsigned short*)take((size_t)N_NODES * D * 2);
    float*          h2      = (float*)         take((size_t)N_NODES * D * 4);
    unsigned short* h1b     = (unsigned short*)take((size_t)N_NODES * D * 2);
    unsigned short* W1t     = (unsigned short*)take((size_t)R_AUG * D * D * 2);
    unsigned short* W2t     = (unsigned short*)take((size_t)R_AUG * D * D * 2);
    int*            offs    = (int*)           take((size_t)(NBINS + 1) * 4);
    int*            cursor  = (int*)           take((size_t)NBINS * 4);
    int*            part    = (int*)           take((size_t)NSB * 4);
    uint2*          sorted  = (uint2*)         take((size_t)E_AUG * 8);
    unsigned short* Zc      = (unsigned short*)take((size_t)E_AUG * D * 2);  // worst-case 166 MB

    // deg and flags are adjacent: one memset covers both
    hipMemsetAsync(deg, 0, (size_t)((char*)S - (char*)deg), stream);
    prep_all<<<dim3(PREPX_BLOCKS + TW_BLOCKS + HIST_BLOCKS), 256, 0, stream>>>(
        emb, xb, W1, W2, W1t, W2t, graph, deg, flags);
    scan_a<<<dim3(NSB + NPB4), 256, 0, stream>>>(deg, offs, part, flags, S, ppart);
    scan_b<<<dim3(2), 256, 0, stream>>>(part, ppart, S);
    scan_c<<<dim3(NSB + NPB4), 256, 0, stream>>>(offs, part, cursor, flags, S, ppart, pair_src);
    blk_kernel<<<dim3(1), 256, 0, stream>>>(S, rowbase, rowcnt, blkoffs);

    gemm_fused<<<dim3(SCAT_BLOCKS + GEMM_NBLK), 256, 0, stream>>>(
        xb, W1t, pair_src, rowbase, rowcnt, blkoffs, Zc,
        graph, deg, S, cursor, sorted, SCAT_BLOCKS);
    agg_pass<<<dim3((N_NODES + 3) / 4), 256, 0, stream>>>(sorted, offs, Zc, b1, (float*)0, h1b, 1);
    gemm_fused<<<dim3(GEMM_NBLK), 256, 0, stream>>>(
        h1b, W2t, pair_src, rowbase, rowcnt, blkoffs, Zc,
        graph, deg, S, cursor, sorted, 0);
    agg_pass<<<dim3((N_NODES + 3) / 4), 256, 0, stream>>>(sorted, offs, Zc, b2, h2, (unsigned short*)0, 0);
    score_kernel<<<dim3(N_BATCH / 8), 256, 0, stream>>>(batch, h2, rels, out);
}

// Round 12
// 342.808 us; speedup vs baseline: 2.1830x; 1.0004x over previous
//
#include <hip/hip_runtime.h>

#define N_NODES 10000
#define N_RELS  50
#define R_AUG   101
#define D       128
#define N_EDGES 320000
#define E_AUG   650000   /* 2*N_EDGES + N_NODES */
#define N_BATCH 65536

#define NBINS   N_NODES
#define NSB     ((NBINS + 255) / 256)        /* 40 dst-bin scan blocks */
#define NP      (R_AUG * N_NODES)            /* 1,010,000 (rel,src) pairs */
#define NPB4    ((NP + 1023) / 1024)         /* 987 pair-scan blocks (4 elem/thread) */
#define BSPAN   256                          /* rows per gemm block */
#define GEMM_NBLK (101 + (E_AUG + BSPAN - 1) / BSPAN)  /* 2641 worst-case */
#define SCAT_BLOCKS ((E_AUG + 255) / 256)    /* 2540 */

/* fused prep kernel block ranges */
#define PREPX_BLOCKS 5000                    /* N_NODES*D/256 */
#define TW_BLOCKS    808                     /* 2*2*(2*R_AUG) */
#define HIST_BLOCKS  2540                    /* ceil(E_AUG/256) */

typedef short bf16x8 __attribute__((ext_vector_type(8)));
typedef float f32x4  __attribute__((ext_vector_type(4)));

__device__ __forceinline__ unsigned short f2bf(float f) {
    union { float f; unsigned int u; } v; v.f = f;
    unsigned int r = (v.u + 0x7FFFu + ((v.u >> 16) & 1u)) >> 16;
    return (unsigned short)r;
}
__device__ __forceinline__ float bf2f(unsigned short h) {
    union { unsigned int u; float f; } v; v.u = ((unsigned int)h) << 16;
    return v.f;
}
__device__ __forceinline__ float u2f(unsigned int u) {
    union { unsigned int u; float f; } v; v.u = u; return v.f;
}
__device__ __forceinline__ unsigned int f2u(float f) {
    union { float f; unsigned int u; } v; v.f = f; return v.u;
}

__device__ __forceinline__ void decode_edge(const int* __restrict__ g, int e,
                                            int& src, int& rel, int& dst) {
    if (e < N_EDGES)            { src = g[3*e];     rel = g[3*e+1];          dst = g[3*e+2]; }
    else if (e < 2*N_EDGES)     { int b = e - N_EDGES;
                                  src = g[3*b+2];   rel = g[3*b+1] + N_RELS; dst = g[3*b];   }
    else                        { int n = e - 2*N_EDGES; src = n; dst = n; rel = 2*N_RELS;   }
}

// paired relation: edge with rel=r,src=x exists  <=>  deg[pair(r)][x] > 0
__device__ __forceinline__ int pair_rel(int r) {
    return (r < N_RELS) ? r + N_RELS : (r < 2 * N_RELS ? r - N_RELS : r);
}

// ---------------- fused prep: x->bf16 | transpose_w | deg_hist ----------------

__global__ __launch_bounds__(256) void prep_all(const float* __restrict__ x,
                                                unsigned short* __restrict__ xb,
                                                const float* __restrict__ W1,
                                                const float* __restrict__ W2,
                                                unsigned short* __restrict__ W1t,
                                                unsigned short* __restrict__ W2t,
                                                const int* __restrict__ g,
                                                int* __restrict__ deg) {
    __shared__ float tile[64][65];
    int b = blockIdx.x, t = threadIdx.x;
    if (b < PREPX_BLOCKS) {
        int i = b * 256 + t;
        xb[i] = f2bf(x[i]);
    } else if (b < PREPX_BLOCKS + TW_BLOCKS) {
        int q = b - PREPX_BLOCKS;
        int d0 = (q & 1) * 64, o0 = ((q >> 1) & 1) * 64;
        int z = q >> 2;                                  /* 0..201 */
        const float* W = (z < R_AUG) ? W1 : W2;
        unsigned short* Wt = (z < R_AUG) ? W1t : W2t;
        int r = (z < R_AUG) ? z : (z - R_AUG);
        int tx = t & 63, ty = t >> 6;
        #pragma unroll
        for (int i = ty; i < 64; i += 4)
            tile[i][tx] = W[((size_t)r * D + (d0 + i)) * D + (o0 + tx)];
        __syncthreads();
        #pragma unroll
        for (int i = ty; i < 64; i += 4)
            Wt[((size_t)r * D + (o0 + i)) * D + (d0 + tx)] = f2bf(tile[tx][i]);
    } else {
        int e = (b - PREPX_BLOCKS - TW_BLOCKS) * 256 + t;
        if (e < E_AUG) {
            int src, rel, dst;
            decode_edge(g, e, src, rel, dst);
            atomicAdd(&deg[rel * N_NODES + dst], 1);
        }
    }
}

// ---- scan stage A: dst-bin block scan | pair block scan (flag = deg[pair]>0, 4/thread) ----

__global__ __launch_bounds__(256) void scan_a(const int* __restrict__ deg,
                                              int* __restrict__ offs,
                                              int* __restrict__ part,
                                              int* __restrict__ S,
                                              int* __restrict__ ppart) {
    __shared__ int wsum[4];
    int t = threadIdx.x, lane = t & 63, w = t >> 6;
    int b = blockIdx.x;
    if (b < NSB) {
        int i = b * 256 + t;
        int v = 0;
        if (i < NBINS) {
            for (int r = 0; r < R_AUG; r++) v += deg[r * N_NODES + i];
        }
        int incl = v;
        #pragma unroll
        for (int off = 1; off < 64; off <<= 1) {
            int u = __shfl_up(incl, off, 64);
            if (lane >= off) incl += u;
        }
        if (lane == 63) wsum[w] = incl;
        __syncthreads();
        int woff = 0;
        for (int k = 0; k < w; k++) woff += wsum[k];
        if (i < NBINS) offs[i] = woff + incl - v;
        if (t == 255) part[b] = woff + incl;
    } else {
        int pb = b - NSB;
        int i0 = pb * 1024 + t * 4;
        int4 f = {0, 0, 0, 0};
        if (i0 < NP) {
            int r = i0 / N_NODES;
            int xx = i0 - r * N_NODES;                  // 4-pack never crosses r (10000%4==0)
            const int* dp = deg + pair_rel(r) * N_NODES + xx;
            if (i0 + 3 < NP) {
                int4 d = *(const int4*)dp;
                f.x = d.x > 0; f.y = d.y > 0; f.z = d.z > 0; f.w = d.w > 0;
            } else {
                f.x = dp[0] > 0;
                if (i0 + 1 < NP) f.y = dp[1] > 0;
                if (i0 + 2 < NP) f.z = dp[2] > 0;
            }
        }
        int e1 = f.x, e2 = f.x + f.y, e3 = e2 + f.z, v = e3 + f.w;
        int incl = v;
        #pragma unroll
        for (int off = 1; off < 64; off <<= 1) {
            int u = __shfl_up(incl, off, 64);
            if (lane >= off) incl += u;
        }
        if (lane == 63) wsum[w] = incl;
        __syncthreads();
        int woff = 0;
        for (int k = 0; k < w; k++) woff += wsum[k];
        int texcl = woff + incl - v;
        if (i0 + 3 < NP) {
            int4 o = {texcl, texcl + e1, texcl + e2, texcl + e3};
            *(int4*)(S + i0) = o;
        } else if (i0 < NP) {
            S[i0] = texcl;
            if (i0 + 1 < NP) S[i0 + 1] = texcl + e1;
            if (i0 + 2 < NP) S[i0 + 2] = texcl + e2;
        }
        if (t == 255) ppart[pb] = woff + incl;
    }
}

// ---- scan stage B: block 0 scans part[NSB]; block 1 serial-carry scans ppart[NPB4] ----

__global__ __launch_bounds__(256) void scan_b(int* __restrict__ part,
                                              int* __restrict__ ppart,
                                              int* __restrict__ S) {
    __shared__ int wsum[4];
    int t = threadIdx.x, lane = t & 63, w = t >> 6;
    if (blockIdx.x == 0) {
        int v = (t < NSB) ? part[t] : 0;
        int incl = v;
        #pragma unroll
        for (int off = 1; off < 64; off <<= 1) {
            int u = __shfl_up(incl, off, 64);
            if (lane >= off) incl += u;
        }
        if (lane == 63) wsum[w] = incl;
        __syncthreads();
        int woff = 0;
        for (int k = 0; k < w; k++) woff += wsum[k];
        if (t < NSB) part[t] = woff + incl - v;
    } else {
        int carry = 0;
        for (int base = 0; base < NPB4; base += 256) {
            int i = base + t;
            int v = (i < NPB4) ? ppart[i] : 0;
            int incl = v;
            #pragma unroll
            for (int off = 1; off < 64; off <<= 1) {
                int u = __shfl_up(incl, off, 64);
                if (lane >= off) incl += u;
            }
            if (lane == 63) wsum[w] = incl;
            __syncthreads();
            int woff = 0;
            for (int k = 0; k < w; k++) woff += wsum[k];
            if (i < NPB4) ppart[i] = carry + woff + incl - v;
            carry += wsum[0] + wsum[1] + wsum[2] + wsum[3];
            __syncthreads();
        }
        if (t == 0) S[NP] = carry;
    }
}

// ---- scan stage C: dst-bin add+cursor | pair add+compact (4 elem/thread) ----

__global__ __launch_bounds__(256) void scan_c(int* __restrict__ offs,
                                              const int* __restrict__ part,
                                              int* __restrict__ cursor,
                                              const int* __restrict__ deg,
                                              int* __restrict__ S,
                                              const int* __restrict__ ppart,
                                              int* __restrict__ pair_src) {
    int b = blockIdx.x, t = threadIdx.x;
    if (b < NSB) {
        int i = b * 256 + t;
        if (i < NBINS) {
            int v = offs[i] + part[i >> 8];
            offs[i] = v;
            cursor[i] = v;
        }
        if (i == 0) offs[NBINS] = E_AUG;
    } else {
        int pb = b - NSB;
        int i0 = pb * 1024 + t * 4;
        if (i0 >= NP) return;
        int pp = ppart[pb];
        int r = i0 / N_NODES;
        int xx = i0 - r * N_NODES;
        const int* dp = deg + pair_rel(r) * N_NODES + xx;
        if (i0 + 3 < NP) {
            int4 sv = *(int4*)(S + i0);
            sv.x += pp; sv.y += pp; sv.z += pp; sv.w += pp;
            *(int4*)(S + i0) = sv;
            int4 d = *(const int4*)dp;
            if (d.x > 0) pair_src[sv.x] = xx;
            if (d.y > 0) pair_src[sv.y] = xx + 1;
            if (d.z > 0) pair_src[sv.z] = xx + 2;
            if (d.w > 0) pair_src[sv.w] = xx + 3;
        } else {
            for (int k = 0; k < 4; k++) {
                int i = i0 + k;
                if (i >= NP) break;
                int s = S[i] + pp;
                S[i] = s;
                if (dp[k] > 0) pair_src[s] = xx + k;
            }
        }
    }
}

// ---------------- fused [block-table | edge scatter] ----------------
// Block 0: per-rel row base/count + gemm block table (from final S).
// Blocks 1..: scatter edges into dst-sorted order; record = (compact z-row, norm).

__global__ __launch_bounds__(256) void scatter_blk(const int* __restrict__ g,
                                                   const int* __restrict__ deg,
                                                   const int* __restrict__ S,
                                                   int* __restrict__ cursor,
                                                   uint2* __restrict__ sorted,
                                                   int* __restrict__ rowbase,
                                                   int* __restrict__ rowcnt,
                                                   int* __restrict__ blkoffs) {
    int b = blockIdx.x, t = threadIdx.x;
    if (b == 0) {
        __shared__ int wsum[4];
        int lane = t & 63, w = t >> 6;
        int nb = 0;
        if (t < R_AUG) {
            int base = S[t * N_NODES];
            int nxt  = S[(t + 1) * N_NODES];     /* t==100 -> S[NP] = total */
            rowbase[t] = base;
            rowcnt[t]  = nxt - base;
            nb = (nxt - base + BSPAN - 1) / BSPAN;
        }
        int incl = nb;
        #pragma unroll
        for (int off = 1; off < 64; off <<= 1) {
            int u = __shfl_up(incl, off, 64);
            if (lane >= off) incl += u;
        }
        if (lane == 63) wsum[w] = incl;
        __syncthreads();
        int woff = 0;
        for (int k = 0; k < w; k++) woff += wsum[k];
        if (t < R_AUG) blkoffs[t] = woff + incl - nb;
        if (t == R_AUG) blkoffs[R_AUG] = woff + incl;   /* total blocks */
        return;
    }
    int e = (b - 1) * 256 + t;
    if (e >= E_AUG) return;
    int src, rel, dst;
    decode_edge(g, e, src, rel, dst);
    int pos = atomicAdd(&cursor[dst], 1);
    int dg = deg[rel * N_NODES + dst];          // >= 1 by construction
    uint2 rec;
    rec.x = (unsigned)S[rel * N_NODES + src];   // compact Z row
    rec.y = f2u(1.0f / (float)dg);
    sorted[pos] = rec;
}

// ---------------- compact GEMM: Zc[row][o] = xb[pair_src[row]][:] @ W[rel(row)][:][o] ----------------
// Fixed grid; block -> (rel, 256-row span) via binary search in blkoffs.
// Wave w: cols (w&1)*64..+64, tile parity w>>1 (8 tiles of 16 rows each).
// 8 tile indices preloaded; next-tile A prefetch; 4 A-loads : 16 MFMA.
// W rows permuted at load so lane (lr,lq) holds cols no+lq*8+{0..7} of its row.

__global__ __launch_bounds__(256, 3) void gemm_compact(const unsigned short* __restrict__ xb,
                                                       const unsigned short* __restrict__ Wt,
                                                       const int* __restrict__ pair_src,
                                                       const int* __restrict__ rowbase,
                                                       const int* __restrict__ rowcnt,
                                                       const int* __restrict__ blkoffs,
                                                       unsigned short* __restrict__ Zc) {
    int b = blockIdx.x;
    if (b >= blkoffs[R_AUG]) return;
    int lo = 0, hi = R_AUG;
    while (hi - lo > 1) {
        int mid = (lo + hi) >> 1;
        if (blkoffs[mid] <= b) lo = mid; else hi = mid;
    }
    int r = lo;
    int lb = b - blkoffs[r];
    int rbase = rowbase[r] + lb * BSPAN;
    int nrows = rowcnt[r] - lb * BSPAN; if (nrows > BSPAN) nrows = BSPAN;

    int t = threadIdx.x, wave = t >> 6, lane = t & 63;
    int lr = lane & 15, lq = lane >> 4;
    int no = (wave & 1) * 64;
    int tp = wave >> 1;
    const unsigned short* Wr = Wt + (size_t)r * D * D;

    // preload all 8 tile indices (independent loads)
    int srcs[8];
    #pragma unroll
    for (int i = 0; i < 8; i++) {
        int row = (tp + 2 * i) * 16 + lr;
        srcs[i] = pair_src[rbase + (row < nrows ? row : 0)];
    }

    int prow = ((lr >> 2) << 3) + (lr & 3);
    bf16x8 w0[4], w1[4], w2[4], w3[4];
    #pragma unroll
    for (int ks = 0; ks < 4; ks++) {
        size_t kb = ks * 32 + lq * 8;
        w0[ks] = *(const bf16x8*)(Wr + (size_t)(no + prow) * D + kb);
        w1[ks] = *(const bf16x8*)(Wr + (size_t)(no + prow + 4) * D + kb);
        w2[ks] = *(const bf16x8*)(Wr + (size_t)(no + 32 + prow) * D + kb);
        w3[ks] = *(const bf16x8*)(Wr + (size_t)(no + 32 + prow + 4) * D + kb);
    }

    bf16x8 a[4];
    {
        const unsigned short* x0 = xb + (size_t)srcs[0] * D + lq * 8;
        #pragma unroll
        for (int ks = 0; ks < 4; ks++) a[ks] = *(const bf16x8*)(x0 + ks * 32);
    }

    #pragma unroll
    for (int i = 0; i < 8; i++) {
        int tile = tp + 2 * i;
        if (tile * 16 >= nrows) break;                  // wave-uniform

        bf16x8 an[4];                                   // prefetch next tile's A
        {
            int ni = (i < 7) ? i + 1 : 7;
            const unsigned short* xn = xb + (size_t)srcs[ni] * D + lq * 8;
            #pragma unroll
            for (int ks = 0; ks < 4; ks++) an[ks] = *(const bf16x8*)(xn + ks * 32);
        }

        f32x4 c0 = {}, c1 = {}, c2 = {}, c3 = {};
        #pragma unroll
        for (int ks = 0; ks < 4; ks++) {
            c0 = __builtin_amdgcn_mfma_f32_16x16x32_bf16(w0[ks], a[ks], c0, 0, 0, 0);
            c1 = __builtin_amdgcn_mfma_f32_16x16x32_bf16(w1[ks], a[ks], c1, 0, 0, 0);
            c2 = __builtin_amdgcn_mfma_f32_16x16x32_bf16(w2[ks], a[ks], c2, 0, 0, 0);
            c3 = __builtin_amdgcn_mfma_f32_16x16x32_bf16(w3[ks], a[ks], c3, 0, 0, 0);
        }
        int row = tile * 16 + lr;
        if (row < nrows) {
            unsigned short* zrow = Zc + ((size_t)(rbase + row) << 7);
            uint4 p0, p1;
            p0.x = (unsigned)f2bf(c0[0]) | ((unsigned)f2bf(c0[1]) << 16);
            p0.y = (unsigned)f2bf(c0[2]) | ((unsigned)f2bf(c0[3]) << 16);
            p0.z = (unsigned)f2bf(c1[0]) | ((unsigned)f2bf(c1[1]) << 16);
            p0.w = (unsigned)f2bf(c1[2]) | ((unsigned)f2bf(c1[3]) << 16);
            p1.x = (unsigned)f2bf(c2[0]) | ((unsigned)f2bf(c2[1]) << 16);
            p1.y = (unsigned)f2bf(c2[2]) | ((unsigned)f2bf(c2[3]) << 16);
            p1.z = (unsigned)f2bf(c3[0]) | ((unsigned)f2bf(c3[1]) << 16);
            p1.w = (unsigned)f2bf(c3[2]) | ((unsigned)f2bf(c3[3]) << 16);
            *(uint4*)(zrow + no + lq * 8) = p0;
            *(uint4*)(zrow + no + 32 + lq * 8) = p1;
        }
        #pragma unroll
        for (int ks = 0; ks < 4; ks++) a[ks] = an[ks];
    }
}

// ---------------- aggregation: one wave per dst, 8 edges in flight ----------------
// lane = 8 edge-slots (g=lane>>3) x 8 dim-groups (s=lane&7, 16 dims = 32B/lane).
// Fused bias + (relu->bf16 | fp32) epilogue.

__global__ __launch_bounds__(256) void agg_pass(const uint2* __restrict__ sorted,
                                                const int* __restrict__ offs,
                                                const unsigned short* __restrict__ Zc,
                                                const float* __restrict__ bias,
                                                float* __restrict__ hf,
                                                unsigned short* __restrict__ hb,
                                                int dorelu) {
    int w = threadIdx.x >> 6, lane = threadIdx.x & 63;
    int dst = blockIdx.x * 4 + w;
    if (dst >= N_NODES) return;
    int e0 = offs[dst], e1 = offs[dst + 1];
    int g = lane >> 3, s = lane & 7;
    float acc[16] = {};

    for (int base = e0; base < e1; base += 64) {
        int n = e1 - base; if (n > 64) n = 64;
        uint2 rec = {0u, 0u};
        if (lane < n) rec = sorted[base + lane];
        int iters = (n + 7) >> 3;
        #pragma unroll 2
        for (int j = 0; j < iters; j++) {
            int ej = j * 8 + g;
            int ec = (ej < n) ? ej : (n - 1);
            unsigned zi = (unsigned)__shfl((int)rec.x, ec, 64);
            unsigned nb = (unsigned)__shfl((int)rec.y, ec, 64);
            float nrm = (ej < n) ? u2f(nb) : 0.0f;
            const unsigned short* zp = Zc + ((size_t)zi << 7) + s * 16;
            uint4 z0 = *(const uint4*)zp;
            uint4 z1 = *(const uint4*)(zp + 8);
            acc[0]  += nrm * bf2f((unsigned short)(z0.x & 0xFFFFu));
            acc[1]  += nrm * bf2f((unsigned short)(z0.x >> 16));
            acc[2]  += nrm * bf2f((unsigned short)(z0.y & 0xFFFFu));
            acc[3]  += nrm * bf2f((unsigned short)(z0.y >> 16));
            acc[4]  += nrm * bf2f((unsigned short)(z0.z & 0xFFFFu));
            acc[5]  += nrm * bf2f((unsigned short)(z0.z >> 16));
            acc[6]  += nrm * bf2f((unsigned short)(z0.w & 0xFFFFu));
            acc[7]  += nrm * bf2f((unsigned short)(z0.w >> 16));
            acc[8]  += nrm * bf2f((unsigned short)(z1.x & 0xFFFFu));
            acc[9]  += nrm * bf2f((unsigned short)(z1.x >> 16));
            acc[10] += nrm * bf2f((unsigned short)(z1.y & 0xFFFFu));
            acc[11] += nrm * bf2f((unsigned short)(z1.y >> 16));
            acc[12] += nrm * bf2f((unsigned short)(z1.z & 0xFFFFu));
            acc[13] += nrm * bf2f((unsigned short)(z1.z >> 16));
            acc[14] += nrm * bf2f((unsigned short)(z1.w & 0xFFFFu));
            acc[15] += nrm * bf2f((unsigned short)(z1.w >> 16));
        }
    }
    #pragma unroll
    for (int k = 0; k < 16; k++) {
        acc[k] += __shfl_down(acc[k], 8, 64);
        acc[k] += __shfl_down(acc[k], 16, 64);
        acc[k] += __shfl_down(acc[k], 32, 64);
    }
    if (g == 0) {
        const float* bp = bias + s * 16;
        float vv[16];
        #pragma unroll
        for (int k = 0; k < 16; k++) vv[k] = bp[k] + acc[k];
        if (dorelu) {
            unsigned short* hp = hb + ((size_t)dst << 7) + s * 16;
            uint4 p0, p1;
            p0.x = (unsigned)f2bf(fmaxf(vv[0], 0.0f))  | ((unsigned)f2bf(fmaxf(vv[1], 0.0f))  << 16);
            p0.y = (unsigned)f2bf(fmaxf(vv[2], 0.0f))  | ((unsigned)f2bf(fmaxf(vv[3], 0.0f))  << 16);
            p0.z = (unsigned)f2bf(fmaxf(vv[4], 0.0f))  | ((unsigned)f2bf(fmaxf(vv[5], 0.0f))  << 16);
            p0.w = (unsigned)f2bf(fmaxf(vv[6], 0.0f))  | ((unsigned)f2bf(fmaxf(vv[7], 0.0f))  << 16);
            p1.x = (unsigned)f2bf(fmaxf(vv[8], 0.0f))  | ((unsigned)f2bf(fmaxf(vv[9], 0.0f))  << 16);
            p1.y = (unsigned)f2bf(fmaxf(vv[10], 0.0f)) | ((unsigned)f2bf(fmaxf(vv[11], 0.0f)) << 16);
            p1.z = (unsigned)f2bf(fmaxf(vv[12], 0.0f)) | ((unsigned)f2bf(fmaxf(vv[13], 0.0f)) << 16);
            p1.w = (unsigned)f2bf(fmaxf(vv[14], 0.0f)) | ((unsigned)f2bf(fmaxf(vv[15], 0.0f)) << 16);
            *(uint4*)hp = p0;
            *(uint4*)(hp + 8) = p1;
        } else {
            float* hp = hf + ((size_t)dst << 7) + s * 16;
            #pragma unroll
            for (int q = 0; q < 4; q++) {
                float4 o = {vv[q * 4], vv[q * 4 + 1], vv[q * 4 + 2], vv[q * 4 + 3]};
                *(float4*)(hp + q * 4) = o;
            }
        }
    }
}

// ---------------- scoring ----------------

__global__ __launch_bounds__(256) void score_kernel(const int* __restrict__ batch,
                                                    const float* __restrict__ h2,
                                                    const float* __restrict__ rels,
                                                    float* __restrict__ out) {
    int t = threadIdx.x;
    int wv = t >> 6, half = (t & 63) >> 5, sl = t & 31;
    int i = blockIdx.x * 8 + wv * 2 + half;
    int bs = batch[3*i], bp = batch[3*i+1], bo = batch[3*i+2];
    float4 s = *(const float4*)(h2   + (size_t)bs * D + sl * 4);
    float4 p = *(const float4*)(rels + (size_t)bp * D + sl * 4);
    float4 o = *(const float4*)(h2   + (size_t)bo * D + sl * 4);
    float v = s.x * p.x * o.x + s.y * p.y * o.y + s.z * p.z * o.z + s.w * p.w * o.w;
    #pragma unroll
    for (int off = 16; off > 0; off >>= 1) v += __shfl_down(v, off, 32);
    if (sl == 0) out[i] = v;
}

// ---------------- host ----------------

extern "C" void kernel_launch(void* const* d_in, const int* in_sizes, int n_in,
                              void* d_out, int out_size, void* d_ws, size_t ws_size,
                              hipStream_t stream) {
    const int*   graph = (const int*)  d_in[0];
    const int*   batch = (const int*)  d_in[1];
    const float* emb   = (const float*)d_in[2];
    const float* W1    = (const float*)d_in[3];
    const float* b1    = (const float*)d_in[4];
    const float* W2    = (const float*)d_in[5];
    const float* b2    = (const float*)d_in[6];
    const float* rels  = (const float*)d_in[7];
    float* out = (float*)d_out;

    char* base = (char*)d_ws;
    size_t off = 0;
    auto take = [&](size_t bytes) -> char* {
        char* q = base + off;
        off += (bytes + 255) & ~(size_t)255;
        return q;
    };
    int*            deg     = (int*)           take((size_t)NP * 4);
    int*            S       = (int*)           take((size_t)(NP + 1) * 4);
    int*            pair_src= (int*)           take((size_t)E_AUG * 4);
    int*            ppart   = (int*)           take((size_t)NPB4 * 4);
    int*            rowbase = (int*)           take((size_t)(R_AUG + 1) * 4);
    int*            rowcnt  = (int*)           take((size_t)(R_AUG + 1) * 4);
    int*            blkoffs = (int*)           take((size_t)(R_AUG + 2) * 4);
    unsigned short* xb      = (unsigned short*)take((size_t)N_NODES * D * 2);
    float*          h2      = (float*)         take((size_t)N_NODES * D * 4);
    unsigned short* h1b     = (unsigned short*)take((size_t)N_NODES * D * 2);
    unsigned short* W1t     = (unsigned short*)take((size_t)R_AUG * D * D * 2);
    unsigned short* W2t     = (unsigned short*)take((size_t)R_AUG * D * D * 2);
    int*            offs    = (int*)           take((size_t)(NBINS + 1) * 4);
    int*            cursor  = (int*)           take((size_t)NBINS * 4);
    int*            part    = (int*)           take((size_t)NSB * 4);
    uint2*          sorted  = (uint2*)         take((size_t)E_AUG * 8);
    unsigned short* Zc      = (unsigned short*)take((size_t)E_AUG * D * 2);  // worst-case 166 MB

    hipMemsetAsync(deg, 0, (size_t)NP * 4, stream);
    prep_all<<<dim3(PREPX_BLOCKS + TW_BLOCKS + HIST_BLOCKS), 256, 0, stream>>>(
        emb, xb, W1, W2, W1t, W2t, graph, deg);
    scan_a<<<dim3(NSB + NPB4), 256, 0, stream>>>(deg, offs, part, S, ppart);
    scan_b<<<dim3(2), 256, 0, stream>>>(part, ppart, S);
    scan_c<<<dim3(NSB + NPB4), 256, 0, stream>>>(offs, part, cursor, deg, S, ppart, pair_src);
    scatter_blk<<<dim3(1 + SCAT_BLOCKS), 256, 0, stream>>>(
        graph, deg, S, cursor, sorted, rowbase, rowcnt, blkoffs);

    gemm_compact<<<dim3(GEMM_NBLK), 256, 0, stream>>>(xb, W1t, pair_src, rowbase, rowcnt, blkoffs, Zc);
    agg_pass<<<dim3((N_NODES + 3) / 4), 256, 0, stream>>>(sorted, offs, Zc, b1, (float*)0, h1b, 1);
    gemm_compact<<<dim3(GEMM_NBLK), 256, 0, stream>>>(h1b, W2t, pair_src, rowbase, rowcnt, blkoffs, Zc);
    agg_pass<<<dim3((N_NODES + 3) / 4), 256, 0, stream>>>(sorted, offs, Zc, b2, h2, (unsigned short*)0, 0);
    score_kernel<<<dim3(N_BATCH / 8), 256, 0, stream>>>(batch, h2, rels, out);
}

// Round 13
// 335.277 us; speedup vs baseline: 2.2320x; 1.0225x over previous
//
#include <hip/hip_runtime.h>

#define N_NODES 10000
#define N_RELS  50
#define R_AUG   101
#define D       128
#define N_EDGES 320000
#define E_AUG   650000   /* 2*N_EDGES + N_NODES */
#define N_BATCH 65536

#define NBINS   N_NODES
#define NSB     ((NBINS + 255) / 256)        /* 40 dst-bin scan blocks */
#define NP      (R_AUG * N_NODES)            /* 1,010,000 (rel,src) pairs */
#define NPB4    ((NP + 1023) / 1024)         /* 987 pair-scan blocks (4 elem/thread) */
#define BSPAN   512                          /* rows per gemm block */
#define GEMM_NBLK (101 + (E_AUG + BSPAN - 1) / BSPAN)  /* 1371 worst-case */
#define SCAT_BLOCKS ((E_AUG + 255) / 256)    /* 2540 */

/* fused prep kernel block ranges */
#define PREPX_BLOCKS 5000                    /* N_NODES*D/256 */
#define TW_BLOCKS    808                     /* 2*2*(2*R_AUG) */
#define HIST_BLOCKS  2540                    /* ceil(E_AUG/256) */

typedef short bf16x8 __attribute__((ext_vector_type(8)));
typedef float f32x4  __attribute__((ext_vector_type(4)));

__device__ __forceinline__ unsigned short f2bf(float f) {
    union { float f; unsigned int u; } v; v.f = f;
    unsigned int r = (v.u + 0x7FFFu + ((v.u >> 16) & 1u)) >> 16;
    return (unsigned short)r;
}
__device__ __forceinline__ float bf2f(unsigned short h) {
    union { unsigned int u; float f; } v; v.u = ((unsigned int)h) << 16;
    return v.f;
}
__device__ __forceinline__ float u2f(unsigned int u) {
    union { unsigned int u; float f; } v; v.u = u; return v.f;
}
__device__ __forceinline__ unsigned int f2u(float f) {
    union { float f; unsigned int u; } v; v.f = f; return v.u;
}

__device__ __forceinline__ void decode_edge(const int* __restrict__ g, int e,
                                            int& src, int& rel, int& dst) {
    if (e < N_EDGES)            { src = g[3*e];     rel = g[3*e+1];          dst = g[3*e+2]; }
    else if (e < 2*N_EDGES)     { int b = e - N_EDGES;
                                  src = g[3*b+2];   rel = g[3*b+1] + N_RELS; dst = g[3*b];   }
    else                        { int n = e - 2*N_EDGES; src = n; dst = n; rel = 2*N_RELS;   }
}

// paired relation: edge with rel=r,src=x exists  <=>  deg[pair(r)][x] > 0
__device__ __forceinline__ int pair_rel(int r) {
    return (r < N_RELS) ? r + N_RELS : (r < 2 * N_RELS ? r - N_RELS : r);
}

// ---------------- fused prep: x->bf16 | transpose_w | deg_hist ----------------

__global__ __launch_bounds__(256) void prep_all(const float* __restrict__ x,
                                                unsigned short* __restrict__ xb,
                                                const float* __restrict__ W1,
                                                const float* __restrict__ W2,
                                                unsigned short* __restrict__ W1t,
                                                unsigned short* __restrict__ W2t,
                                                const int* __restrict__ g,
                                                int* __restrict__ deg) {
    __shared__ float tile[64][65];
    int b = blockIdx.x, t = threadIdx.x;
    if (b < PREPX_BLOCKS) {
        int i = b * 256 + t;
        xb[i] = f2bf(x[i]);
    } else if (b < PREPX_BLOCKS + TW_BLOCKS) {
        int q = b - PREPX_BLOCKS;
        int d0 = (q & 1) * 64, o0 = ((q >> 1) & 1) * 64;
        int z = q >> 2;                                  /* 0..201 */
        const float* W = (z < R_AUG) ? W1 : W2;
        unsigned short* Wt = (z < R_AUG) ? W1t : W2t;
        int r = (z < R_AUG) ? z : (z - R_AUG);
        int tx = t & 63, ty = t >> 6;
        #pragma unroll
        for (int i = ty; i < 64; i += 4)
            tile[i][tx] = W[((size_t)r * D + (d0 + i)) * D + (o0 + tx)];
        __syncthreads();
        #pragma unroll
        for (int i = ty; i < 64; i += 4)
            Wt[((size_t)r * D + (o0 + i)) * D + (d0 + tx)] = f2bf(tile[tx][i]);
    } else {
        int e = (b - PREPX_BLOCKS - TW_BLOCKS) * 256 + t;
        if (e < E_AUG) {
            int src, rel, dst;
            decode_edge(g, e, src, rel, dst);
            atomicAdd(&deg[rel * N_NODES + dst], 1);
        }
    }
}

// ---- scan stage A: dst-bin block scan | pair block scan (flag = deg[pair]>0, 4/thread) ----

__global__ __launch_bounds__(256) void scan_a(const int* __restrict__ deg,
                                              int* __restrict__ offs,
                                              int* __restrict__ part,
                                              int* __restrict__ S,
                                              int* __restrict__ ppart) {
    __shared__ int wsum[4];
    int t = threadIdx.x, lane = t & 63, w = t >> 6;
    int b = blockIdx.x;
    if (b < NSB) {
        int i = b * 256 + t;
        int v = 0;
        if (i < NBINS) {
            for (int r = 0; r < R_AUG; r++) v += deg[r * N_NODES + i];
        }
        int incl = v;
        #pragma unroll
        for (int off = 1; off < 64; off <<= 1) {
            int u = __shfl_up(incl, off, 64);
            if (lane >= off) incl += u;
        }
        if (lane == 63) wsum[w] = incl;
        __syncthreads();
        int woff = 0;
        for (int k = 0; k < w; k++) woff += wsum[k];
        if (i < NBINS) offs[i] = woff + incl - v;
        if (t == 255) part[b] = woff + incl;
    } else {
        int pb = b - NSB;
        int i0 = pb * 1024 + t * 4;
        int4 f = {0, 0, 0, 0};
        if (i0 < NP) {
            int r = i0 / N_NODES;
            int xx = i0 - r * N_NODES;                  // 4-pack never crosses r (10000%4==0)
            const int* dp = deg + pair_rel(r) * N_NODES + xx;
            if (i0 + 3 < NP) {
                int4 d = *(const int4*)dp;
                f.x = d.x > 0; f.y = d.y > 0; f.z = d.z > 0; f.w = d.w > 0;
            } else {
                f.x = dp[0] > 0;
                if (i0 + 1 < NP) f.y = dp[1] > 0;
                if (i0 + 2 < NP) f.z = dp[2] > 0;
            }
        }
        int e1 = f.x, e2 = f.x + f.y, e3 = e2 + f.z, v = e3 + f.w;
        int incl = v;
        #pragma unroll
        for (int off = 1; off < 64; off <<= 1) {
            int u = __shfl_up(incl, off, 64);
            if (lane >= off) incl += u;
        }
        if (lane == 63) wsum[w] = incl;
        __syncthreads();
        int woff = 0;
        for (int k = 0; k < w; k++) woff += wsum[k];
        int texcl = woff + incl - v;
        if (i0 + 3 < NP) {
            int4 o = {texcl, texcl + e1, texcl + e2, texcl + e3};
            *(int4*)(S + i0) = o;
        } else if (i0 < NP) {
            S[i0] = texcl;
            if (i0 + 1 < NP) S[i0 + 1] = texcl + e1;
            if (i0 + 2 < NP) S[i0 + 2] = texcl + e2;
        }
        if (t == 255) ppart[pb] = woff + incl;
    }
}

// ---- scan stage B: block 0 scans part[NSB]; block 1 serial-carry scans ppart[NPB4] ----

__global__ __launch_bounds__(256) void scan_b(int* __restrict__ part,
                                              int* __restrict__ ppart,
                                              int* __restrict__ S) {
    __shared__ int wsum[4];
    int t = threadIdx.x, lane = t & 63, w = t >> 6;
    if (blockIdx.x == 0) {
        int v = (t < NSB) ? part[t] : 0;
        int incl = v;
        #pragma unroll
        for (int off = 1; off < 64; off <<= 1) {
            int u = __shfl_up(incl, off, 64);
            if (lane >= off) incl += u;
        }
        if (lane == 63) wsum[w] = incl;
        __syncthreads();
        int woff = 0;
        for (int k = 0; k < w; k++) woff += wsum[k];
        if (t < NSB) part[t] = woff + incl - v;
    } else {
        int carry = 0;
        for (int base = 0; base < NPB4; base += 256) {
            int i = base + t;
            int v = (i < NPB4) ? ppart[i] : 0;
            int incl = v;
            #pragma unroll
            for (int off = 1; off < 64; off <<= 1) {
                int u = __shfl_up(incl, off, 64);
                if (lane >= off) incl += u;
            }
            if (lane == 63) wsum[w] = incl;
            __syncthreads();
            int woff = 0;
            for (int k = 0; k < w; k++) woff += wsum[k];
            if (i < NPB4) ppart[i] = carry + woff + incl - v;
            carry += wsum[0] + wsum[1] + wsum[2] + wsum[3];
            __syncthreads();
        }
        if (t == 0) S[NP] = carry;
    }
}

// ---- scan stage C: dst-bin add+cursor | pair add+compact (4 elem/thread) ----

__global__ __launch_bounds__(256) void scan_c(int* __restrict__ offs,
                                              const int* __restrict__ part,
                                              int* __restrict__ cursor,
                                              const int* __restrict__ deg,
                                              int* __restrict__ S,
                                              const int* __restrict__ ppart,
                                              int* __restrict__ pair_src) {
    int b = blockIdx.x, t = threadIdx.x;
    if (b < NSB) {
        int i = b * 256 + t;
        if (i < NBINS) {
            int v = offs[i] + part[i >> 8];
            offs[i] = v;
            cursor[i] = v;
        }
        if (i == 0) offs[NBINS] = E_AUG;
    } else {
        int pb = b - NSB;
        int i0 = pb * 1024 + t * 4;
        if (i0 >= NP) return;
        int pp = ppart[pb];
        int r = i0 / N_NODES;
        int xx = i0 - r * N_NODES;
        const int* dp = deg + pair_rel(r) * N_NODES + xx;
        if (i0 + 3 < NP) {
            int4 sv = *(int4*)(S + i0);
            sv.x += pp; sv.y += pp; sv.z += pp; sv.w += pp;
            *(int4*)(S + i0) = sv;
            int4 d = *(const int4*)dp;
            if (d.x > 0) pair_src[sv.x] = xx;
            if (d.y > 0) pair_src[sv.y] = xx + 1;
            if (d.z > 0) pair_src[sv.z] = xx + 2;
            if (d.w > 0) pair_src[sv.w] = xx + 3;
        } else {
            for (int k = 0; k < 4; k++) {
                int i = i0 + k;
                if (i >= NP) break;
                int s = S[i] + pp;
                S[i] = s;
                if (dp[k] > 0) pair_src[s] = xx + k;
            }
        }
    }
}

// ---------------- fused [block-table | edge scatter] ----------------

__global__ __launch_bounds__(256) void scatter_blk(const int* __restrict__ g,
                                                   const int* __restrict__ deg,
                                                   const int* __restrict__ S,
                                                   int* __restrict__ cursor,
                                                   uint2* __restrict__ sorted,
                                                   int* __restrict__ rowbase,
                                                   int* __restrict__ rowcnt,
                                                   int* __restrict__ blkoffs) {
    int b = blockIdx.x, t = threadIdx.x;
    if (b == 0) {
        __shared__ int wsum[4];
        int lane = t & 63, w = t >> 6;
        int nb = 0;
        if (t < R_AUG) {
            int base = S[t * N_NODES];
            int nxt  = S[(t + 1) * N_NODES];     /* t==100 -> S[NP] = total */
            rowbase[t] = base;
            rowcnt[t]  = nxt - base;
            nb = (nxt - base + BSPAN - 1) / BSPAN;
        }
        int incl = nb;
        #pragma unroll
        for (int off = 1; off < 64; off <<= 1) {
            int u = __shfl_up(incl, off, 64);
            if (lane >= off) incl += u;
        }
        if (lane == 63) wsum[w] = incl;
        __syncthreads();
        int woff = 0;
        for (int k = 0; k < w; k++) woff += wsum[k];
        if (t < R_AUG) blkoffs[t] = woff + incl - nb;
        if (t == R_AUG) blkoffs[R_AUG] = woff + incl;   /* total blocks */
        return;
    }
    int e = (b - 1) * 256 + t;
    if (e >= E_AUG) return;
    int src, rel, dst;
    decode_edge(g, e, src, rel, dst);
    int pos = atomicAdd(&cursor[dst], 1);
    int dg = deg[rel * N_NODES + dst];          // >= 1 by construction
    uint2 rec;
    rec.x = (unsigned)S[rel * N_NODES + src];   // compact Z row
    rec.y = f2u(1.0f / (float)dg);
    sorted[pos] = rec;
}

// ---------------- compact GEMM: Zc[row][o] = xb[pair_src[row]][:] @ W[rel(row)][:][o] ----------------
// Fixed grid; block -> (rel, 512-row span) via binary search in blkoffs.
// Wave w: cols (w&1)*64..+64, tile parity w>>1 (16 tiles of 16 rows each).
// 16 tile indices preloaded; next-tile A prefetch; 4 A-loads : 16 MFMA.
// W rows permuted at load so lane (lr,lq) holds cols no+lq*8+{0..7} of its row.

__global__ __launch_bounds__(256, 4) void gemm_compact(const unsigned short* __restrict__ xb,
                                                       const unsigned short* __restrict__ Wt,
                                                       const int* __restrict__ pair_src,
                                                       const int* __restrict__ rowbase,
                                                       const int* __restrict__ rowcnt,
                                                       const int* __restrict__ blkoffs,
                                                       unsigned short* __restrict__ Zc) {
    int b = blockIdx.x;
    if (b >= blkoffs[R_AUG]) return;
    int lo = 0, hi = R_AUG;
    while (hi - lo > 1) {
        int mid = (lo + hi) >> 1;
        if (blkoffs[mid] <= b) lo = mid; else hi = mid;
    }
    int r = lo;
    int lb = b - blkoffs[r];
    int rbase = rowbase[r] + lb * BSPAN;
    int nrows = rowcnt[r] - lb * BSPAN; if (nrows > BSPAN) nrows = BSPAN;

    int t = threadIdx.x, wave = t >> 6, lane = t & 63;
    int lr = lane & 15, lq = lane >> 4;
    int no = (wave & 1) * 64;
    int tp = wave >> 1;
    const unsigned short* Wr = Wt + (size_t)r * D * D;

    // preload all 16 tile indices (independent loads)
    int srcs[16];
    #pragma unroll
    for (int i = 0; i < 16; i++) {
        int row = (tp + 2 * i) * 16 + lr;
        srcs[i] = pair_src[rbase + (row < nrows ? row : 0)];
    }

    int prow = ((lr >> 2) << 3) + (lr & 3);
    bf16x8 w0[4], w1[4], w2[4], w3[4];
    #pragma unroll
    for (int ks = 0; ks < 4; ks++) {
        size_t kb = ks * 32 + lq * 8;
        w0[ks] = *(const bf16x8*)(Wr + (size_t)(no + prow) * D + kb);
        w1[ks] = *(const bf16x8*)(Wr + (size_t)(no + prow + 4) * D + kb);
        w2[ks] = *(const bf16x8*)(Wr + (size_t)(no + 32 + prow) * D + kb);
        w3[ks] = *(const bf16x8*)(Wr + (size_t)(no + 32 + prow + 4) * D + kb);
    }

    bf16x8 a[4];
    {
        const unsigned short* x0 = xb + (size_t)srcs[0] * D + lq * 8;
        #pragma unroll
        for (int ks = 0; ks < 4; ks++) a[ks] = *(const bf16x8*)(x0 + ks * 32);
    }

    #pragma unroll
    for (int i = 0; i < 16; i++) {
        int tile = tp + 2 * i;
        if (tile * 16 >= nrows) break;                  // wave-uniform

        bf16x8 an[4];                                   // prefetch next tile's A
        {
            int ni = (i < 15) ? i + 1 : 15;
            const unsigned short* xn = xb + (size_t)srcs[ni] * D + lq * 8;
            #pragma unroll
            for (int ks = 0; ks < 4; ks++) an[ks] = *(const bf16x8*)(xn + ks * 32);
        }

        f32x4 c0 = {}, c1 = {}, c2 = {}, c3 = {};
        #pragma unroll
        for (int ks = 0; ks < 4; ks++) {
            c0 = __builtin_amdgcn_mfma_f32_16x16x32_bf16(w0[ks], a[ks], c0, 0, 0, 0);
            c1 = __builtin_amdgcn_mfma_f32_16x16x32_bf16(w1[ks], a[ks], c1, 0, 0, 0);
            c2 = __builtin_amdgcn_mfma_f32_16x16x32_bf16(w2[ks], a[ks], c2, 0, 0, 0);
            c3 = __builtin_amdgcn_mfma_f32_16x16x32_bf16(w3[ks], a[ks], c3, 0, 0, 0);
        }
        int row = tile * 16 + lr;
        if (row < nrows) {
            unsigned short* zrow = Zc + ((size_t)(rbase + row) << 7);
            uint4 p0, p1;
            p0.x = (unsigned)f2bf(c0[0]) | ((unsigned)f2bf(c0[1]) << 16);
            p0.y = (unsigned)f2bf(c0[2]) | ((unsigned)f2bf(c0[3]) << 16);
            p0.z = (unsigned)f2bf(c1[0]) | ((unsigned)f2bf(c1[1]) << 16);
            p0.w = (unsigned)f2bf(c1[2]) | ((unsigned)f2bf(c1[3]) << 16);
            p1.x = (unsigned)f2bf(c2[0]) | ((unsigned)f2bf(c2[1]) << 16);
            p1.y = (unsigned)f2bf(c2[2]) | ((unsigned)f2bf(c2[3]) << 16);
            p1.z = (unsigned)f2bf(c3[0]) | ((unsigned)f2bf(c3[1]) << 16);
            p1.w = (unsigned)f2bf(c3[2]) | ((unsigned)f2bf(c3[3]) << 16);
            *(uint4*)(zrow + no + lq * 8) = p0;
            *(uint4*)(zrow + no + 32 + lq * 8) = p1;
        }
        #pragma unroll
        for (int ks = 0; ks < 4; ks++) a[ks] = an[ks];
    }
}

// ---------------- aggregation: one wave per dst, 8 edges in flight ----------------

__global__ __launch_bounds__(256) void agg_pass(const uint2* __restrict__ sorted,
                                                const int* __restrict__ offs,
                                                const unsigned short* __restrict__ Zc,
                                                const float* __restrict__ bias,
                                                float* __restrict__ hf,
                                                unsigned short* __restrict__ hb,
                                                int dorelu) {
    int w = threadIdx.x >> 6, lane = threadIdx.x & 63;
    int dst = blockIdx.x * 4 + w;
    if (dst >= N_NODES) return;
    int e0 = offs[dst], e1 = offs[dst + 1];
    int g = lane >> 3, s = lane & 7;
    float acc[16] = {};

    for (int base = e0; base < e1; base += 64) {
        int n = e1 - base; if (n > 64) n = 64;
        uint2 rec = {0u, 0u};
        if (lane < n) rec = sorted[base + lane];
        int iters = (n + 7) >> 3;
        #pragma unroll 2
        for (int j = 0; j < iters; j++) {
            int ej = j * 8 + g;
            int ec = (ej < n) ? ej : (n - 1);
            unsigned zi = (unsigned)__shfl((int)rec.x, ec, 64);
            unsigned nb = (unsigned)__shfl((int)rec.y, ec, 64);
            float nrm = (ej < n) ? u2f(nb) : 0.0f;
            const unsigned short* zp = Zc + ((size_t)zi << 7) + s * 16;
            uint4 z0 = *(const uint4*)zp;
            uint4 z1 = *(const uint4*)(zp + 8);
            acc[0]  += nrm * bf2f((unsigned short)(z0.x & 0xFFFFu));
            acc[1]  += nrm * bf2f((unsigned short)(z0.x >> 16));
            acc[2]  += nrm * bf2f((unsigned short)(z0.y & 0xFFFFu));
            acc[3]  += nrm * bf2f((unsigned short)(z0.y >> 16));
            acc[4]  += nrm * bf2f((unsigned short)(z0.z & 0xFFFFu));
            acc[5]  += nrm * bf2f((unsigned short)(z0.z >> 16));
            acc[6]  += nrm * bf2f((unsigned short)(z0.w & 0xFFFFu));
            acc[7]  += nrm * bf2f((unsigned short)(z0.w >> 16));
            acc[8]  += nrm * bf2f((unsigned short)(z1.x & 0xFFFFu));
            acc[9]  += nrm * bf2f((unsigned short)(z1.x >> 16));
            acc[10] += nrm * bf2f((unsigned short)(z1.y & 0xFFFFu));
            acc[11] += nrm * bf2f((unsigned short)(z1.y >> 16));
            acc[12] += nrm * bf2f((unsigned short)(z1.z & 0xFFFFu));
            acc[13] += nrm * bf2f((unsigned short)(z1.z >> 16));
            acc[14] += nrm * bf2f((unsigned short)(z1.w & 0xFFFFu));
            acc[15] += nrm * bf2f((unsigned short)(z1.w >> 16));
        }
    }
    #pragma unroll
    for (int k = 0; k < 16; k++) {
        acc[k] += __shfl_down(acc[k], 8, 64);
        acc[k] += __shfl_down(acc[k], 16, 64);
        acc[k] += __shfl_down(acc[k], 32, 64);
    }
    if (g == 0) {
        const float* bp = bias + s * 16;
        float vv[16];
        #pragma unroll
        for (int k = 0; k < 16; k++) vv[k] = bp[k] + acc[k];
        if (dorelu) {
            unsigned short* hp = hb + ((size_t)dst << 7) + s * 16;
            uint4 p0, p1;
            p0.x = (unsigned)f2bf(fmaxf(vv[0], 0.0f))  | ((unsigned)f2bf(fmaxf(vv[1], 0.0f))  << 16);
            p0.y = (unsigned)f2bf(fmaxf(vv[2], 0.0f))  | ((unsigned)f2bf(fmaxf(vv[3], 0.0f))  << 16);
            p0.z = (unsigned)f2bf(fmaxf(vv[4], 0.0f))  | ((unsigned)f2bf(fmaxf(vv[5], 0.0f))  << 16);
            p0.w = (unsigned)f2bf(fmaxf(vv[6], 0.0f))  | ((unsigned)f2bf(fmaxf(vv[7], 0.0f))  << 16);
            p1.x = (unsigned)f2bf(fmaxf(vv[8], 0.0f))  | ((unsigned)f2bf(fmaxf(vv[9], 0.0f))  << 16);
            p1.y = (unsigned)f2bf(fmaxf(vv[10], 0.0f)) | ((unsigned)f2bf(fmaxf(vv[11], 0.0f)) << 16);
            p1.z = (unsigned)f2bf(fmaxf(vv[12], 0.0f)) | ((unsigned)f2bf(fmaxf(vv[13], 0.0f)) << 16);
            p1.w = (unsigned)f2bf(fmaxf(vv[14], 0.0f)) | ((unsigned)f2bf(fmaxf(vv[15], 0.0f)) << 16);
            *(uint4*)hp = p0;
            *(uint4*)(hp + 8) = p1;
        } else {
            float* hp = hf + ((size_t)dst << 7) + s * 16;
            #pragma unroll
            for (int q = 0; q < 4; q++) {
                float4 o = {vv[q * 4], vv[q * 4 + 1], vv[q * 4 + 2], vv[q * 4 + 3]};
                *(float4*)(hp + q * 4) = o;
            }
        }
    }
}

// ---------------- scoring: 4 items/wave (16 lanes x 2 float4 each) ----------------

__global__ __launch_bounds__(256) void score_kernel(const int* __restrict__ batch,
                                                    const float* __restrict__ h2,
                                                    const float* __restrict__ rels,
                                                    float* __restrict__ out) {
    int t = threadIdx.x;
    int wv = t >> 6, q = (t & 63) >> 4, sl = t & 15;
    int i = blockIdx.x * 16 + wv * 4 + q;     // grid 4096 covers 65536 exactly
    int bs = batch[3*i], bp = batch[3*i+1], bo = batch[3*i+2];
    const float* sp = h2   + (size_t)bs * D + sl * 8;
    const float* pp = rels + (size_t)bp * D + sl * 8;
    const float* op = h2   + (size_t)bo * D + sl * 8;
    float4 s0 = *(const float4*)sp,      s1 = *(const float4*)(sp + 4);
    float4 p0 = *(const float4*)pp,      p1 = *(const float4*)(pp + 4);
    float4 o0 = *(const float4*)op,      o1 = *(const float4*)(op + 4);
    float v = s0.x * p0.x * o0.x + s0.y * p0.y * o0.y + s0.z * p0.z * o0.z + s0.w * p0.w * o0.w
            + s1.x * p1.x * o1.x + s1.y * p1.y * o1.y + s1.z * p1.z * o1.z + s1.w * p1.w * o1.w;
    #pragma unroll
    for (int off = 8; off > 0; off >>= 1) v += __shfl_down(v, off, 16);
    if (sl == 0) out[i] = v;
}

// ---------------- host ----------------

extern "C" void kernel_launch(void* const* d_in, const int* in_sizes, int n_in,
                              void* d_out, int out_size, void* d_ws, size_t ws_size,
                              hipStream_t stream) {
    const int*   graph = (const int*)  d_in[0];
    const int*   batch = (const int*)  d_in[1];
    const float* emb   = (const float*)d_in[2];
    const float* W1    = (const float*)d_in[3];
    const float* b1    = (const float*)d_in[4];
    const float* W2    = (const float*)d_in[5];
    const float* b2    = (const float*)d_in[6];
    const float* rels  = (const float*)d_in[7];
    float* out = (float*)d_out;

    char* base = (char*)d_ws;
    size_t off = 0;
    auto take = [&](size_t bytes) -> char* {
        char* q = base + off;
        off += (bytes + 255) & ~(size_t)255;
        return q;
    };
    int*            deg     = (int*)           take((size_t)NP * 4);
    int*            S       = (int*)           take((size_t)(NP + 1) * 4);
    int*            pair_src= (int*)           take((size_t)E_AUG * 4);
    int*            ppart   = (int*)           take((size_t)NPB4 * 4);
    int*            rowbase = (int*)           take((size_t)(R_AUG + 1) * 4);
    int*            rowcnt  = (int*)           take((size_t)(R_AUG + 1) * 4);
    int*            blkoffs = (int*)           take((size_t)(R_AUG + 2) * 4);
    unsigned short* xb      = (unsigned short*)take((size_t)N_NODES * D * 2);
    float*          h2      = (float*)         take((size_t)N_NODES * D * 4);
    unsigned short* h1b     = (unsigned short*)take((size_t)N_NODES * D * 2);
    unsigned short* W1t     = (unsigned short*)take((size_t)R_AUG * D * D * 2);
    unsigned short* W2t     = (unsigned short*)take((size_t)R_AUG * D * D * 2);
    int*            offs    = (int*)           take((size_t)(NBINS + 1) * 4);
    int*            cursor  = (int*)           take((size_t)NBINS * 4);
    int*            part    = (int*)           take((size_t)NSB * 4);
    uint2*          sorted  = (uint2*)         take((size_t)E_AUG * 8);
    unsigned short* Zc      = (unsigned short*)take((size_t)E_AUG * D * 2);  // worst-case 166 MB

    hipMemsetAsync(deg, 0, (size_t)NP * 4, stream);
    prep_all<<<dim3(PREPX_BLOCKS + TW_BLOCKS + HIST_BLOCKS), 256, 0, stream>>>(
        emb, xb, W1, W2, W1t, W2t, graph, deg);
    scan_a<<<dim3(NSB + NPB4), 256, 0, stream>>>(deg, offs, part, S, ppart);
    scan_b<<<dim3(2), 256, 0, stream>>>(part, ppart, S);
    scan_c<<<dim3(NSB + NPB4), 256, 0, stream>>>(offs, part, cursor, deg, S, ppart, pair_src);
    scatter_blk<<<dim3(1 + SCAT_BLOCKS), 256, 0, stream>>>(
        graph, deg, S, cursor, sorted, rowbase, rowcnt, blkoffs);

    gemm_compact<<<dim3(GEMM_NBLK), 256, 0, stream>>>(xb, W1t, pair_src, rowbase, rowcnt, blkoffs, Zc);
    agg_pass<<<dim3((N_NODES + 3) / 4), 256, 0, stream>>>(sorted, offs, Zc, b1, (float*)0, h1b, 1);
    gemm_compact<<<dim3(GEMM_NBLK), 256, 0, stream>>>(h1b, W2t, pair_src, rowbase, rowcnt, blkoffs, Zc);
    agg_pass<<<dim3((N_NODES + 3) / 4), 256, 0, stream>>>(sorted, offs, Zc, b2, h2, (unsigned short*)0, 0);
    score_kernel<<<dim3(N_BATCH / 16), 256, 0, stream>>>(batch, h2, rels, out);
}

// Round 15
// 334.385 us; speedup vs baseline: 2.2380x; 1.0027x over previous
//
#include <hip/hip_runtime.h>

#define N_NODES 10000
#define N_RELS  50
#define R_AUG   101
#define D       128
#define N_EDGES 320000
#define E_AUG   650000   /* 2*N_EDGES + N_NODES */
#define N_BATCH 65536

#define NBINS   N_NODES
#define NSB     ((NBINS + 255) / 256)        /* 40 dst-bin scan blocks */
#define NP      (R_AUG * N_NODES)            /* 1,010,000 (rel,src) pairs */
#define NPB4    ((NP + 1023) / 1024)         /* 987 pair-scan blocks (4 elem/thread) */
#define BSPAN   512                          /* rows per gemm block */
#define GEMM_NBLK (101 + (E_AUG + BSPAN - 1) / BSPAN)  /* 1371 worst-case */
#define SCAT_BLOCKS ((E_AUG + 255) / 256)    /* 2540 */

/* fused prep kernel block ranges: hist FIRST (latency-bound atomics start at t=0,
   bandwidth work overlaps behind) */
#define HIST_BLOCKS  2540                    /* ceil(E_AUG/256) */
#define TW_BLOCKS    808                     /* 2*2*(2*R_AUG) */
#define PREPX_BLOCKS 1250                    /* N_NODES*D/(256*4) */

typedef short bf16x8 __attribute__((ext_vector_type(8)));
typedef float f32x4  __attribute__((ext_vector_type(4)));

__device__ __forceinline__ unsigned short f2bf(float f) {
    union { float f; unsigned int u; } v; v.f = f;
    unsigned int r = (v.u + 0x7FFFu + ((v.u >> 16) & 1u)) >> 16;
    return (unsigned short)r;
}
__device__ __forceinline__ float bf2f(unsigned short h) {
    union { unsigned int u; float f; } v; v.u = ((unsigned int)h) << 16;
    return v.f;
}
__device__ __forceinline__ float u2f(unsigned int u) {
    union { unsigned int u; float f; } v; v.u = u; return v.f;
}
__device__ __forceinline__ unsigned int f2u(float f) {
    union { float f; unsigned int u; } v; v.f = f; return v.u;
}

__device__ __forceinline__ void decode_edge(const int* __restrict__ g, int e,
                                            int& src, int& rel, int& dst) {
    if (e < N_EDGES)            { src = g[3*e];     rel = g[3*e+1];          dst = g[3*e+2]; }
    else if (e < 2*N_EDGES)     { int b = e - N_EDGES;
                                  src = g[3*b+2];   rel = g[3*b+1] + N_RELS; dst = g[3*b];   }
    else                        { int n = e - 2*N_EDGES; src = n; dst = n; rel = 2*N_RELS;   }
}

// paired relation: edge with rel=r,src=x exists  <=>  deg[pair(r)][x] > 0
__device__ __forceinline__ int pair_rel(int r) {
    return (r < N_RELS) ? r + N_RELS : (r < 2 * N_RELS ? r - N_RELS : r);
}

// ---------------- fused prep: deg_hist | transpose_w | x->bf16 ----------------

__global__ __launch_bounds__(256) void prep_all(const float* __restrict__ x,
                                                unsigned short* __restrict__ xb,
                                                const float* __restrict__ W1,
                                                const float* __restrict__ W2,
                                                unsigned short* __restrict__ W1t,
                                                unsigned short* __restrict__ W2t,
                                                const int* __restrict__ g,
                                                int* __restrict__ deg) {
    __shared__ float tile[64][65];
    int b = blockIdx.x, t = threadIdx.x;
    if (b < HIST_BLOCKS) {
        int e = b * 256 + t;
        if (e < E_AUG) {
            int src, rel, dst;
            decode_edge(g, e, src, rel, dst);
            atomicAdd(&deg[rel * N_NODES + dst], 1);
        }
    } else if (b < HIST_BLOCKS + TW_BLOCKS) {
        int q = b - HIST_BLOCKS;
        int d0 = (q & 1) * 64, o0 = ((q >> 1) & 1) * 64;
        int z = q >> 2;                                  /* 0..201 */
        const float* W = (z < R_AUG) ? W1 : W2;
        unsigned short* Wt = (z < R_AUG) ? W1t : W2t;
        int r = (z < R_AUG) ? z : (z - R_AUG);
        int tx = t & 63, ty = t >> 6;
        #pragma unroll
        for (int i = ty; i < 64; i += 4)
            tile[i][tx] = W[((size_t)r * D + (d0 + i)) * D + (o0 + tx)];
        __syncthreads();
        #pragma unroll
        for (int i = ty; i < 64; i += 4)
            Wt[((size_t)r * D + (o0 + i)) * D + (d0 + tx)] = f2bf(tile[tx][i]);
    } else {
        int i = (b - HIST_BLOCKS - TW_BLOCKS) * 1024 + t * 4;  // covers N_NODES*D exactly
        float4 xv = *(const float4*)(x + i);
        ushort4 o;
        o.x = f2bf(xv.x); o.y = f2bf(xv.y); o.z = f2bf(xv.z); o.w = f2bf(xv.w);
        *(ushort4*)(xb + i) = o;
    }
}

// ---- scan stage A: dst-bin block scan | pair block scan (flag = deg[pair]>0, 4/thread) ----

__global__ __launch_bounds__(256) void scan_a(const int* __restrict__ deg,
                                              int* __restrict__ offs,
                                              int* __restrict__ part,
                                              int* __restrict__ S,
                                              int* __restrict__ ppart) {
    __shared__ int wsum[4];
    int t = threadIdx.x, lane = t & 63, w = t >> 6;
    int b = blockIdx.x;
    if (b < NSB) {
        int i = b * 256 + t;
        int v = 0;
        if (i < NBINS) {
            for (int r = 0; r < R_AUG; r++) v += deg[r * N_NODES + i];
        }
        int incl = v;
        #pragma unroll
        for (int off = 1; off < 64; off <<= 1) {
            int u = __shfl_up(incl, off, 64);
            if (lane >= off) incl += u;
        }
        if (lane == 63) wsum[w] = incl;
        __syncthreads();
        int woff = 0;
        for (int k = 0; k < w; k++) woff += wsum[k];
        if (i < NBINS) offs[i] = woff + incl - v;
        if (t == 255) part[b] = woff + incl;
    } else {
        int pb = b - NSB;
        int i0 = pb * 1024 + t * 4;
        int4 f = {0, 0, 0, 0};
        if (i0 < NP) {
            int r = i0 / N_NODES;
            int xx = i0 - r * N_NODES;                  // 4-pack never crosses r (10000%4==0)
            const int* dp = deg + pair_rel(r) * N_NODES + xx;
            if (i0 + 3 < NP) {
                int4 d = *(const int4*)dp;
                f.x = d.x > 0; f.y = d.y > 0; f.z = d.z > 0; f.w = d.w > 0;
            } else {
                f.x = dp[0] > 0;
                if (i0 + 1 < NP) f.y = dp[1] > 0;
                if (i0 + 2 < NP) f.z = dp[2] > 0;
            }
        }
        int e1 = f.x, e2 = f.x + f.y, e3 = e2 + f.z, v = e3 + f.w;
        int incl = v;
        #pragma unroll
        for (int off = 1; off < 64; off <<= 1) {
            int u = __shfl_up(incl, off, 64);
            if (lane >= off) incl += u;
        }
        if (lane == 63) wsum[w] = incl;
        __syncthreads();
        int woff = 0;
        for (int k = 0; k < w; k++) woff += wsum[k];
        int texcl = woff + incl - v;
        if (i0 + 3 < NP) {
            int4 o = {texcl, texcl + e1, texcl + e2, texcl + e3};
            *(int4*)(S + i0) = o;
        } else if (i0 < NP) {
            S[i0] = texcl;
            if (i0 + 1 < NP) S[i0 + 1] = texcl + e1;
            if (i0 + 2 < NP) S[i0 + 2] = texcl + e2;
        }
        if (t == 255) ppart[pb] = woff + incl;
    }
}

// ---- scan stage B: block 0 scans part[NSB]; block 1 serial-carry scans ppart[NPB4] ----

__global__ __launch_bounds__(256) void scan_b(int* __restrict__ part,
                                              int* __restrict__ ppart,
                                              int* __restrict__ S) {
    __shared__ int wsum[4];
    int t = threadIdx.x, lane = t & 63, w = t >> 6;
    if (blockIdx.x == 0) {
        int v = (t < NSB) ? part[t] : 0;
        int incl = v;
        #pragma unroll
        for (int off = 1; off < 64; off <<= 1) {
            int u = __shfl_up(incl, off, 64);
            if (lane >= off) incl += u;
        }
        if (lane == 63) wsum[w] = incl;
        __syncthreads();
        int woff = 0;
        for (int k = 0; k < w; k++) woff += wsum[k];
        if (t < NSB) part[t] = woff + incl - v;
    } else {
        int carry = 0;
        for (int base = 0; base < NPB4; base += 256) {
            int i = base + t;
            int v = (i < NPB4) ? ppart[i] : 0;
            int incl = v;
            #pragma unroll
            for (int off = 1; off < 64; off <<= 1) {
                int u = __shfl_up(incl, off, 64);
                if (lane >= off) incl += u;
            }
            if (lane == 63) wsum[w] = incl;
            __syncthreads();
            int woff = 0;
            for (int k = 0; k < w; k++) woff += wsum[k];
            if (i < NPB4) ppart[i] = carry + woff + incl - v;
            carry += wsum[0] + wsum[1] + wsum[2] + wsum[3];
            __syncthreads();
        }
        if (t == 0) S[NP] = carry;
    }
}

// ---- scan stage C: dst-bin add+cursor | pair add+compact (4 elem/thread) ----

__global__ __launch_bounds__(256) void scan_c(int* __restrict__ offs,
                                              const int* __restrict__ part,
                                              int* __restrict__ cursor,
                                              const int* __restrict__ deg,
                                              int* __restrict__ S,
                                              const int* __restrict__ ppart,
                                              int* __restrict__ pair_src) {
    int b = blockIdx.x, t = threadIdx.x;
    if (b < NSB) {
        int i = b * 256 + t;
        if (i < NBINS) {
            int v = offs[i] + part[i >> 8];
            offs[i] = v;
            cursor[i] = v;
        }
        if (i == 0) offs[NBINS] = E_AUG;
    } else {
        int pb = b - NSB;
        int i0 = pb * 1024 + t * 4;
        if (i0 >= NP) return;
        int pp = ppart[pb];
        int r = i0 / N_NODES;
        int xx = i0 - r * N_NODES;
        const int* dp = deg + pair_rel(r) * N_NODES + xx;
        if (i0 + 3 < NP) {
            int4 sv = *(int4*)(S + i0);
            sv.x += pp; sv.y += pp; sv.z += pp; sv.w += pp;
            *(int4*)(S + i0) = sv;
            int4 d = *(const int4*)dp;
            if (d.x > 0) pair_src[sv.x] = xx;
            if (d.y > 0) pair_src[sv.y] = xx + 1;
            if (d.z > 0) pair_src[sv.z] = xx + 2;
            if (d.w > 0) pair_src[sv.w] = xx + 3;
        } else {
            for (int k = 0; k < 4; k++) {
                int i = i0 + k;
                if (i >= NP) break;
                int s = S[i] + pp;
                S[i] = s;
                if (dp[k] > 0) pair_src[s] = xx + k;
            }
        }
    }
}

// ---------------- fused [block-table | edge scatter] ----------------

__global__ __launch_bounds__(256) void scatter_blk(const int* __restrict__ g,
                                                   const int* __restrict__ deg,
                                                   const int* __restrict__ S,
                                                   int* __restrict__ cursor,
                                                   uint2* __restrict__ sorted,
                                                   int* __restrict__ rowbase,
                                                   int* __restrict__ rowcnt,
                                                   int* __restrict__ blkoffs) {
    int b = blockIdx.x, t = threadIdx.x;
    if (b == 0) {
        __shared__ int wsum[4];
        int lane = t & 63, w = t >> 6;
        int nb = 0;
        if (t < R_AUG) {
            int base = S[t * N_NODES];
            int nxt  = S[(t + 1) * N_NODES];     /* t==100 -> S[NP] = total */
            rowbase[t] = base;
            rowcnt[t]  = nxt - base;
            nb = (nxt - base + BSPAN - 1) / BSPAN;
        }
        int incl = nb;
        #pragma unroll
        for (int off = 1; off < 64; off <<= 1) {
            int u = __shfl_up(incl, off, 64);
            if (lane >= off) incl += u;
        }
        if (lane == 63) wsum[w] = incl;
        __syncthreads();
        int woff = 0;
        for (int k = 0; k < w; k++) woff += wsum[k];
        if (t < R_AUG) blkoffs[t] = woff + incl - nb;
        if (t == R_AUG) blkoffs[R_AUG] = woff + incl;   /* total blocks */
        return;
    }
    int e = (b - 1) * 256 + t;
    if (e >= E_AUG) return;
    int src, rel, dst;
    decode_edge(g, e, src, rel, dst);
    int pos = atomicAdd(&cursor[dst], 1);
    int dg = deg[rel * N_NODES + dst];          // >= 1 by construction
    uint2 rec;
    rec.x = (unsigned)S[rel * N_NODES + src];   // compact Z row
    rec.y = f2u(1.0f / (float)dg);
    sorted[pos] = rec;
}

// ---------------- compact GEMM: Zc[row][o] = xb[pair_src[row]][:] @ W[rel(row)][:][o] ----------------
// Fixed grid; block -> (rel, 512-row span) via binary search in blkoffs.
// Wave w: cols (w&1)*64..+64, tile parity w>>1 (16 tiles of 16 rows each).
// 16 tile indices preloaded; next-tile A prefetch; 4 A-loads : 16 MFMA.
// W rows permuted at load so lane (lr,lq) holds cols no+lq*8+{0..7} of its row.

__global__ __launch_bounds__(256, 4) void gemm_compact(const unsigned short* __restrict__ xb,
                                                       const unsigned short* __restrict__ Wt,
                                                       const int* __restrict__ pair_src,
                                                       const int* __restrict__ rowbase,
                                                       const int* __restrict__ rowcnt,
                                                       const int* __restrict__ blkoffs,
                                                       unsigned short* __restrict__ Zc) {
    int b = blockIdx.x;
    if (b >= blkoffs[R_AUG]) return;
    int lo = 0, hi = R_AUG;
    while (hi - lo > 1) {
        int mid = (lo + hi) >> 1;
        if (blkoffs[mid] <= b) lo = mid; else hi = mid;
    }
    int r = lo;
    int lb = b - blkoffs[r];
    int rbase = rowbase[r] + lb * BSPAN;
    int nrows = rowcnt[r] - lb * BSPAN; if (nrows > BSPAN) nrows = BSPAN;

    int t = threadIdx.x, wave = t >> 6, lane = t & 63;
    int lr = lane & 15, lq = lane >> 4;
    int no = (wave & 1) * 64;
    int tp = wave >> 1;
    const unsigned short* Wr = Wt + (size_t)r * D * D;

    // preload all 16 tile indices (independent loads)
    int srcs[16];
    #pragma unroll
    for (int i = 0; i < 16; i++) {
        int row = (tp + 2 * i) * 16 + lr;
        srcs[i] = pair_src[rbase + (row < nrows ? row : 0)];
    }

    int prow = ((lr >> 2) << 3) + (lr & 3);
    bf16x8 w0[4], w1[4], w2[4], w3[4];
    #pragma unroll
    for (int ks = 0; ks < 4; ks++) {
        size_t kb = ks * 32 + lq * 8;
        w0[ks] = *(const bf16x8*)(Wr + (size_t)(no + prow) * D + kb);
        w1[ks] = *(const bf16x8*)(Wr + (size_t)(no + prow + 4) * D + kb);
        w2[ks] = *(const bf16x8*)(Wr + (size_t)(no + 32 + prow) * D + kb);
        w3[ks] = *(const bf16x8*)(Wr + (size_t)(no + 32 + prow + 4) * D + kb);
    }

    bf16x8 a[4];
    {
        const unsigned short* x0 = xb + (size_t)srcs[0] * D + lq * 8;
        #pragma unroll
        for (int ks = 0; ks < 4; ks++) a[ks] = *(const bf16x8*)(x0 + ks * 32);
    }

    #pragma unroll
    for (int i = 0; i < 16; i++) {
        int tile = tp + 2 * i;
        if (tile * 16 >= nrows) break;                  // wave-uniform

        bf16x8 an[4];                                   // prefetch next tile's A
        {
            int ni = (i < 15) ? i + 1 : 15;
            const unsigned short* xn = xb + (size_t)srcs[ni] * D + lq * 8;
            #pragma unroll
            for (int ks = 0; ks < 4; ks++) an[ks] = *(const bf16x8*)(xn + ks * 32);
        }

        f32x4 c0 = {}, c1 = {}, c2 = {}, c3 = {};
        #pragma unroll
        for (int ks = 0; ks < 4; ks++) {
            c0 = __builtin_amdgcn_mfma_f32_16x16x32_bf16(w0[ks], a[ks], c0, 0, 0, 0);
            c1 = __builtin_amdgcn_mfma_f32_16x16x32_bf16(w1[ks], a[ks], c1, 0, 0, 0);
            c2 = __builtin_amdgcn_mfma_f32_16x16x32_bf16(w2[ks], a[ks], c2, 0, 0, 0);
            c3 = __builtin_amdgcn_mfma_f32_16x16x32_bf16(w3[ks], a[ks], c3, 0, 0, 0);
        }
        int row = tile * 16 + lr;
        if (row < nrows) {
            unsigned short* zrow = Zc + ((size_t)(rbase + row) << 7);
            uint4 p0, p1;
            p0.x = (unsigned)f2bf(c0[0]) | ((unsigned)f2bf(c0[1]) << 16);
            p0.y = (unsigned)f2bf(c0[2]) | ((unsigned)f2bf(c0[3]) << 16);
            p0.z = (unsigned)f2bf(c1[0]) | ((unsigned)f2bf(c1[1]) << 16);
            p0.w = (unsigned)f2bf(c1[2]) | ((unsigned)f2bf(c1[3]) << 16);
            p1.x = (unsigned)f2bf(c2[0]) | ((unsigned)f2bf(c2[1]) << 16);
            p1.y = (unsigned)f2bf(c2[2]) | ((unsigned)f2bf(c2[3]) << 16);
            p1.z = (unsigned)f2bf(c3[0]) | ((unsigned)f2bf(c3[1]) << 16);
            p1.w = (unsigned)f2bf(c3[2]) | ((unsigned)f2bf(c3[3]) << 16);
            *(uint4*)(zrow + no + lq * 8) = p0;
            *(uint4*)(zrow + no + 32 + lq * 8) = p1;
        }
        #pragma unroll
        for (int ks = 0; ks < 4; ks++) a[ks] = an[ks];
    }
}

// ---------------- aggregation: one wave per dst, 8 edges in flight ----------------

__global__ __launch_bounds__(256) void agg_pass(const uint2* __restrict__ sorted,
                                                const int* __restrict__ offs,
                                                const unsigned short* __restrict__ Zc,
                                                const float* __restrict__ bias,
                                                float* __restrict__ hf,
                                                unsigned short* __restrict__ hb,
                                                int dorelu) {
    int w = threadIdx.x >> 6, lane = threadIdx.x & 63;
    int dst = blockIdx.x * 4 + w;
    if (dst >= N_NODES) return;
    int e0 = offs[dst], e1 = offs[dst + 1];
    int g = lane >> 3, s = lane & 7;
    float acc[16] = {};

    for (int base = e0; base < e1; base += 64) {
        int n = e1 - base; if (n > 64) n = 64;
        uint2 rec = {0u, 0u};
        if (lane < n) rec = sorted[base + lane];
        int iters = (n + 7) >> 3;
        #pragma unroll 2
        for (int j = 0; j < iters; j++) {
            int ej = j * 8 + g;
            int ec = (ej < n) ? ej : (n - 1);
            unsigned zi = (unsigned)__shfl((int)rec.x, ec, 64);
            unsigned nb = (unsigned)__shfl((int)rec.y, ec, 64);
            float nrm = (ej < n) ? u2f(nb) : 0.0f;
            const unsigned short* zp = Zc + ((size_t)zi << 7) + s * 16;
            uint4 z0 = *(const uint4*)zp;
            uint4 z1 = *(const uint4*)(zp + 8);
            acc[0]  += nrm * bf2f((unsigned short)(z0.x & 0xFFFFu));
            acc[1]  += nrm * bf2f((unsigned short)(z0.x >> 16));
            acc[2]  += nrm * bf2f((unsigned short)(z0.y & 0xFFFFu));
            acc[3]  += nrm * bf2f((unsigned short)(z0.y >> 16));
            acc[4]  += nrm * bf2f((unsigned short)(z0.z & 0xFFFFu));
            acc[5]  += nrm * bf2f((unsigned short)(z0.z >> 16));
            acc[6]  += nrm * bf2f((unsigned short)(z0.w & 0xFFFFu));
            acc[7]  += nrm * bf2f((unsigned short)(z0.w >> 16));
            acc[8]  += nrm * bf2f((unsigned short)(z1.x & 0xFFFFu));
            acc[9]  += nrm * bf2f((unsigned short)(z1.x >> 16));
            acc[10] += nrm * bf2f((unsigned short)(z1.y & 0xFFFFu));
            acc[11] += nrm * bf2f((unsigned short)(z1.y >> 16));
            acc[12] += nrm * bf2f((unsigned short)(z1.z & 0xFFFFu));
            acc[13] += nrm * bf2f((unsigned short)(z1.z >> 16));
            acc[14] += nrm * bf2f((unsigned short)(z1.w & 0xFFFFu));
            acc[15] += nrm * bf2f((unsigned short)(z1.w >> 16));
        }
    }
    #pragma unroll
    for (int k = 0; k < 16; k++) {
        acc[k] += __shfl_down(acc[k], 8, 64);
        acc[k] += __shfl_down(acc[k], 16, 64);
        acc[k] += __shfl_down(acc[k], 32, 64);
    }
    if (g == 0) {
        const float* bp = bias + s * 16;
        float vv[16];
        #pragma unroll
        for (int k = 0; k < 16; k++) vv[k] = bp[k] + acc[k];
        if (dorelu) {
            unsigned short* hp = hb + ((size_t)dst << 7) + s * 16;
            uint4 p0, p1;
            p0.x = (unsigned)f2bf(fmaxf(vv[0], 0.0f))  | ((unsigned)f2bf(fmaxf(vv[1], 0.0f))  << 16);
            p0.y = (unsigned)f2bf(fmaxf(vv[2], 0.0f))  | ((unsigned)f2bf(fmaxf(vv[3], 0.0f))  << 16);
            p0.z = (unsigned)f2bf(fmaxf(vv[4], 0.0f))  | ((unsigned)f2bf(fmaxf(vv[5], 0.0f))  << 16);
            p0.w = (unsigned)f2bf(fmaxf(vv[6], 0.0f))  | ((unsigned)f2bf(fmaxf(vv[7], 0.0f))  << 16);
            p1.x = (unsigned)f2bf(fmaxf(vv[8], 0.0f))  | ((unsigned)f2bf(fmaxf(vv[9], 0.0f))  << 16);
            p1.y = (unsigned)f2bf(fmaxf(vv[10], 0.0f)) | ((unsigned)f2bf(fmaxf(vv[11], 0.0f)) << 16);
            p1.z = (unsigned)f2bf(fmaxf(vv[12], 0.0f)) | ((unsigned)f2bf(fmaxf(vv[13], 0.0f)) << 16);
            p1.w = (unsigned)f2bf(fmaxf(vv[14], 0.0f)) | ((unsigned)f2bf(fmaxf(vv[15], 0.0f)) << 16);
            *(uint4*)hp = p0;
            *(uint4*)(hp + 8) = p1;
        } else {
            float* hp = hf + ((size_t)dst << 7) + s * 16;
            #pragma unroll
            for (int q = 0; q < 4; q++) {
                float4 o = {vv[q * 4], vv[q * 4 + 1], vv[q * 4 + 2], vv[q * 4 + 3]};
                *(float4*)(hp + q * 4) = o;
            }
        }
    }
}

// ---------------- scoring: 4 items/wave (16 lanes x 2 float4 each) ----------------

__global__ __launch_bounds__(256) void score_kernel(const int* __restrict__ batch,
                                                    const float* __restrict__ h2,
                                                    const float* __restrict__ rels,
                                                    float* __restrict__ out) {
    int t = threadIdx.x;
    int wv = t >> 6, q = (t & 63) >> 4, sl = t & 15;
    int i = blockIdx.x * 16 + wv * 4 + q;     // grid 4096 covers 65536 exactly
    int bs = batch[3*i], bp = batch[3*i+1], bo = batch[3*i+2];
    const float* sp = h2   + (size_t)bs * D + sl * 8;
    const float* pp = rels + (size_t)bp * D + sl * 8;
    const float* op = h2   + (size_t)bo * D + sl * 8;
    float4 s0 = *(const float4*)sp,      s1 = *(const float4*)(sp + 4);
    float4 p0 = *(const float4*)pp,      p1 = *(const float4*)(pp + 4);
    float4 o0 = *(const float4*)op,      o1 = *(const float4*)(op + 4);
    float v = s0.x * p0.x * o0.x + s0.y * p0.y * o0.y + s0.z * p0.z * o0.z + s0.w * p0.w * o0.w
            + s1.x * p1.x * o1.x + s1.y * p1.y * o1.y + s1.z * p1.z * o1.z + s1.w * p1.w * o1.w;
    #pragma unroll
    for (int off = 8; off > 0; off >>= 1) v += __shfl_down(v, off, 16);
    if (sl == 0) out[i] = v;
}

// ---------------- host ----------------

extern "C" void kernel_launch(void* const* d_in, const int* in_sizes, int n_in,
                              void* d_out, int out_size, void* d_ws, size_t ws_size,
                              hipStream_t stream) {
    const int*   graph = (const int*)  d_in[0];
    const int*   batch = (const int*)  d_in[1];
    const float* emb   = (const float*)d_in[2];
    const float* W1    = (const float*)d_in[3];
    const float* b1    = (const float*)d_in[4];
    const float* W2    = (const float*)d_in[5];
    const float* b2    = (const float*)d_in[6];
    const float* rels  = (const float*)d_in[7];
    float* out = (float*)d_out;

    char* base = (char*)d_ws;
    size_t off = 0;
    auto take = [&](size_t bytes) -> char* {
        char* q = base + off;
        off += (bytes + 255) & ~(size_t)255;
        return q;
    };
    int*            deg     = (int*)           take((size_t)NP * 4);
    int*            S       = (int*)           take((size_t)(NP + 1) * 4);
    int*            pair_src= (int*)           take((size_t)E_AUG * 4);
    int*            ppart   = (int*)           take((size_t)NPB4 * 4);
    int*            rowbase = (int*)           take((size_t)(R_AUG + 1) * 4);
    int*            rowcnt  = (int*)           take((size_t)(R_AUG + 1) * 4);
    int*            blkoffs = (int*)           take((size_t)(R_AUG + 2) * 4);
    unsigned short* xb      = (unsigned short*)take((size_t)N_NODES * D * 2);
    float*          h2      = (float*)         take((size_t)N_NODES * D * 4);
    unsigned short* h1b     = (unsigned short*)take((size_t)N_NODES * D * 2);
    unsigned short* W1t     = (unsigned short*)take((size_t)R_AUG * D * D * 2);
    unsigned short* W2t     = (unsigned short*)take((size_t)R_AUG * D * D * 2);
    int*            offs    = (int*)           take((size_t)(NBINS + 1) * 4);
    int*            cursor  = (int*)           take((size_t)NBINS * 4);
    int*            part    = (int*)           take((size_t)NSB * 4);
    uint2*          sorted  = (uint2*)         take((size_t)E_AUG * 8);
    unsigned short* Zc      = (unsigned short*)take((size_t)E_AUG * D * 2);  // worst-case 166 MB

    hipMemsetAsync(deg, 0, (size_t)NP * 4, stream);
    prep_all<<<dim3(HIST_BLOCKS + TW_BLOCKS + PREPX_BLOCKS), 256, 0, stream>>>(
        emb, xb, W1, W2, W1t, W2t, graph, deg);
    scan_a<<<dim3(NSB + NPB4), 256, 0, stream>>>(deg, offs, part, S, ppart);
    scan_b<<<dim3(2), 256, 0, stream>>>(part, ppart, S);
    scan_c<<<dim3(NSB + NPB4), 256, 0, stream>>>(offs, part, cursor, deg, S, ppart, pair_src);
    scatter_blk<<<dim3(1 + SCAT_BLOCKS), 256, 0, stream>>>(
        graph, deg, S, cursor, sorted, rowbase, rowcnt, blkoffs);

    gemm_compact<<<dim3(GEMM_NBLK), 256, 0, stream>>>(xb, W1t, pair_src, rowbase, rowcnt, blkoffs, Zc);
    agg_pass<<<dim3((N_NODES + 3) / 4), 256, 0, stream>>>(sorted, offs, Zc, b1, (float*)0, h1b, 1);
    gemm_compact<<<dim3(GEMM_NBLK), 256, 0, stream>>>(h1b, W2t, pair_src, rowbase, rowcnt, blkoffs, Zc);
    agg_pass<<<dim3((N_NODES + 3) / 4), 256, 0, stream>>>(sorted, offs, Zc, b2, h2, (unsigned short*)0, 0);
    score_kernel<<<dim3(N_BATCH / 16), 256, 0, stream>>>(batch, h2, rels, out);
}